// Round 6
// baseline (338.866 us; speedup 1.0000x reference)
//
#include <hip/hip_runtime.h>
#include <hip/hip_bf16.h>
#include <math.h>

#define NN 100000
#define NE 1000000
#define DD 64
#define NG 128
#define NL 3

#define NBUK 196          // dst >> 9 buckets (512 nodes each)
#define EPB 2048          // edges per bin block
#define NBLK ((NE + EPB - 1) / EPB)   // 489
#define BCAP 6144         // per-bucket capacity (mean 5120, ~14 sigma margin)

typedef unsigned short ushort_t;
typedef unsigned int u32;
typedef __attribute__((ext_vector_type(8))) short short8v;
typedef __attribute__((ext_vector_type(4))) float f32x4;
typedef __attribute__((ext_vector_type(4))) unsigned int u32x4;

__device__ __forceinline__ ushort_t f2bf(float f) {
    __hip_bfloat16 h = __float2bfloat16(f);
    return *reinterpret_cast<ushort_t*>(&h);
}
__device__ __forceinline__ float bf2f(ushort_t u) {
    unsigned v = ((unsigned)u) << 16;
    return __builtin_bit_cast(float, v);
}
__device__ __forceinline__ unsigned cvtpk(float lo, float hi) {
    unsigned r;
    asm("v_cvt_pk_bf16_f32 %0, %1, %2" : "=v"(r) : "v"(lo), "v"(hi));
    return r;
}
// sum over each 8-lane group (lanes grouped by lane>>3)
__device__ __forceinline__ float sum8(float x) {
    int v = __builtin_bit_cast(int, x);
    int t1 = __builtin_amdgcn_update_dpp(0, v, 0xB1, 0xF, 0xF, true);   // quad_perm xor1
    x += __builtin_bit_cast(float, t1);
    v = __builtin_bit_cast(int, x);
    int t2 = __builtin_amdgcn_update_dpp(0, v, 0x4E, 0xF, 0xF, true);   // quad_perm xor2
    x += __builtin_bit_cast(float, t2);
    v = __builtin_bit_cast(int, x);
    int t3 = __builtin_amdgcn_ds_swizzle(v, 0x101F);                    // xor4
    x += __builtin_bit_cast(float, t3);
    return x;
}

// ---------------- misc ----------------

__global__ void zero2_k(float* a, int n1, int* g, int n2) {
    int i = blockIdx.x * blockDim.x + threadIdx.x;
    if (i < n1) a[i] = 0.f;
    if (i < n2) g[i] = 0;
}

__global__ void cvt_k(const float* __restrict__ x, ushort_t* __restrict__ o, int n) {
    int i = blockIdx.x * blockDim.x + threadIdx.x;
    int base = i * 4;
    if (base + 3 < n) {
        float4 v = *(const float4*)&x[base];
        uint2 pk;
        pk.x = cvtpk(v.x, v.y);
        pk.y = cvtpk(v.z, v.w);
        *(uint2*)&o[base] = pk;
    } else {
        for (int k = base; k < n; k++) o[k] = f2bf(x[k]);
    }
}

// ---------------- CSR build: bucket-major direct placement ----------------
// pack = (dst&511)<<17 | src   (src < 2^17)
// bin_k: LDS-sorts EPB edges by bucket, reserves global space per bucket via
// atomic cursors, scatter-WRITES chunks (stores don't stall). csr_k then reads
// its bucket fully coalesced.

__global__ __launch_bounds__(256) void bin_k(const int* __restrict__ src,
                                             const int* __restrict__ dst,
                                             u32* __restrict__ binbuf,
                                             int* __restrict__ gcur) {
    __shared__ int hist[NBUK];
    __shared__ int excl[NBUK];
    __shared__ int cur[NBUK];
    __shared__ int gbase[NBUK];
    __shared__ int tmp[256];
    __shared__ u32 pairs[EPB];
    __shared__ unsigned char bukid[EPB];
    int t = threadIdx.x;
    int blk = blockIdx.x;
    int e0 = blk * EPB;
    int totvalid = NE - e0; if (totvalid > EPB) totvalid = EPB;

    for (int i = t; i < NBUK; i += 256) hist[i] = 0;
    __syncthreads();

    int mysrc[8], mydst[8];
#pragma unroll
    for (int i = 0; i < 8; i++) {
        int e = e0 + i * 256 + t;
        bool v = e < NE;
        mysrc[i] = v ? src[e] : -1;
        mydst[i] = v ? dst[e] : -1;
        if (v) atomicAdd(&hist[mydst[i] >> 9], 1);
    }
    __syncthreads();

    int v = (t < NBUK) ? hist[t] : 0;
    tmp[t] = v;
    __syncthreads();
#pragma unroll
    for (int off = 1; off < 256; off <<= 1) {
        int a = (t >= off) ? tmp[t - off] : 0;
        __syncthreads();
        tmp[t] += a;
        __syncthreads();
    }
    if (t < NBUK) { excl[t] = tmp[t] - v; cur[t] = tmp[t] - v; }
    __syncthreads();

#pragma unroll
    for (int i = 0; i < 8; i++) {
        if (mydst[i] >= 0) {
            int b = mydst[i] >> 9;
            int p = atomicAdd(&cur[b], 1);
            pairs[p] = ((u32)(mydst[i] & 511) << 17) | (u32)mysrc[i];
            bukid[p] = (unsigned char)b;
        }
    }
    // reserve global chunk space per bucket
    if (t < NBUK && v > 0) gbase[t] = atomicAdd(&gcur[t], v);
    __syncthreads();

    for (int i = t; i < totvalid; i += 256) {
        int b = bukid[i];
        int idx = gbase[b] + (i - excl[b]);
        if (idx < BCAP) binbuf[(size_t)b * BCAP + idx] = pairs[i];
    }
}

// scan bucket totals -> bukbase; rowstart[NN] = total

__global__ __launch_bounds__(256) void scanB_k(const int* __restrict__ gcur,
                                               int* __restrict__ bukbase,
                                               int* __restrict__ rowstart) {
    __shared__ int tmp[256];
    int t = threadIdx.x;
    int v = 0;
    if (t < NBUK) { v = gcur[t]; if (v > BCAP) v = BCAP; }
    tmp[t] = v;
    __syncthreads();
#pragma unroll
    for (int off = 1; off < 256; off <<= 1) {
        int a = (t >= off) ? tmp[t - off] : 0;
        __syncthreads();
        tmp[t] += a;
        __syncthreads();
    }
    if (t < NBUK) bukbase[t] = tmp[t] - v;
    if (t == 255) rowstart[NN] = tmp[255];
}

__global__ __launch_bounds__(256) void csr_k(const u32* __restrict__ binbuf,
                                             const int* __restrict__ gcur,
                                             const int* __restrict__ bukbase,
                                             int* __restrict__ rowstart,
                                             int* __restrict__ csr_src) {
    __shared__ u32 pairs[BCAP];
    __shared__ int csrb[BCAP];
    __shared__ int deg[512];
    __shared__ int excl[512];
    __shared__ int cur[512];
    __shared__ int tmp[512];
    int b = blockIdx.x;
    int t = threadIdx.x;
    int base = bukbase[b];
    int nbase = b << 9;
    int T = gcur[b]; if (T > BCAP) T = BCAP;

    for (int i = t; i < 512; i += 256) deg[i] = 0;
    for (int i = t; i < T; i += 256) pairs[i] = binbuf[(size_t)b * BCAP + i];
    __syncthreads();
    for (int i = t; i < T; i += 256) atomicAdd(&deg[pairs[i] >> 17], 1);
    __syncthreads();

    int v0 = deg[t], v1 = deg[t + 256];
    tmp[t] = v0; tmp[t + 256] = v1;
    __syncthreads();
#pragma unroll
    for (int off = 1; off < 512; off <<= 1) {
        int a0 = (t >= off) ? tmp[t - off] : 0;
        int i1 = t + 256;
        int a1 = (i1 >= off) ? tmp[i1 - off] : 0;
        __syncthreads();
        tmp[t] += a0; tmp[i1] += a1;
        __syncthreads();
    }
    excl[t] = tmp[t] - v0; excl[t + 256] = tmp[t + 256] - v1;
    cur[t] = excl[t]; cur[t + 256] = excl[t + 256];
    __syncthreads();

    for (int i = t; i < 512; i += 256) {
        int n = nbase + i;
        if (n < NN) rowstart[n] = base + excl[i];
    }

    for (int i = t; i < T; i += 256) {
        u32 p = pairs[i];
        int pos = atomicAdd(&cur[p >> 17], 1);
        csrb[pos] = (int)(p & 0x1FFFFu);
    }
    __syncthreads();
    for (int i = t; i < T; i += 256) csr_src[base + i] = csrb[i];
}

// ---------------- W pre-pack (swapped-A MFMA fragments) ----------------

__global__ __launch_bounds__(64) void packw_k(const float* __restrict__ Wq,
                                              const float* __restrict__ Wk,
                                              const float* __restrict__ Wv,
                                              const float* __restrict__ Ws_,
                                              ushort_t* __restrict__ wpack) {
    int mat = blockIdx.x & 3, layer = blockIdx.x >> 2;
    const float* W = ((mat == 0) ? Wq : (mat == 1) ? Wk : (mat == 2) ? Wv : Ws_) + layer * DD * DD;
    int lane = threadIdx.x;
    int lq = lane >> 4, ln = lane & 15;
#pragma unroll
    for (int ct = 0; ct < 4; ct++) {
#pragma unroll
        for (int ks = 0; ks < 2; ks++) {
#pragma unroll
            for (int j = 0; j < 8; j++) {
                float v = W[(ks * 32 + lq * 8 + j) * DD + ct * 16 + ln];
                wpack[((size_t)(blockIdx.x * 8 + ct * 2 + ks)) * 512 + lane * 8 + j] = f2bf(v);
            }
        }
    }
}

// ---------------- fused 4-matrix MFMA GEMM, swapped operands ----------------

__global__ __launch_bounds__(256) void gemm4_k(const ushort_t* __restrict__ hbf,
                                               const ushort_t* __restrict__ wpl,
                                               const float* __restrict__ bq_, const float* __restrict__ bk_,
                                               const float* __restrict__ bv_, const float* __restrict__ bs_,
                                               ushort_t* __restrict__ qo, ushort_t* __restrict__ ko,
                                               ushort_t* __restrict__ vo, ushort_t* __restrict__ so) {
    int t = threadIdx.x;
    int lane = t & 63, wv = t >> 6;
    int ln = lane & 15, lq = lane >> 4;
    int rowbase = blockIdx.x * 64;

    const float* bsel = (wv == 0) ? bq_ : (wv == 1) ? bk_ : (wv == 2) ? bv_ : bs_;
    ushort_t* osel    = (wv == 0) ? qo : (wv == 1) ? ko : (wv == 2) ? vo : so;

    short8v wfrag[4][2];
#pragma unroll
    for (int ct = 0; ct < 4; ct++)
#pragma unroll
        for (int ks = 0; ks < 2; ks++)
            wfrag[ct][ks] = *(const short8v*)&wpl[((size_t)(wv * 8 + ct * 2 + ks)) * 512 + lane * 8];

    float4 bias[4];
#pragma unroll
    for (int ct = 0; ct < 4; ct++) bias[ct] = *(const float4*)&bsel[ct * 16 + lq * 4];

#pragma unroll
    for (int rt = 0; rt < 4; rt++) {
        int grow = rowbase + rt * 16 + ln;
        bool rv = grow < NN;
        int gr = rv ? grow : NN - 1;
        short8v h0 = *(const short8v*)&hbf[(size_t)gr * DD + lq * 8];
        short8v h1 = *(const short8v*)&hbf[(size_t)gr * DD + 32 + lq * 8];
#pragma unroll
        for (int ct = 0; ct < 4; ct++) {
            f32x4 acc;
            acc[0] = bias[ct].x; acc[1] = bias[ct].y; acc[2] = bias[ct].z; acc[3] = bias[ct].w;
            acc = __builtin_amdgcn_mfma_f32_16x16x32_bf16(wfrag[ct][0], h0, acc, 0, 0, 0);
            acc = __builtin_amdgcn_mfma_f32_16x16x32_bf16(wfrag[ct][1], h1, acc, 0, 0, 0);
            if (rv) {
                uint2 pk;
                pk.x = cvtpk(acc[0], acc[1]);
                pk.y = cvtpk(acc[2], acc[3]);
                *(uint2*)&osel[(size_t)grow * DD + ct * 16 + lq * 4] = pk;
            }
        }
    }
}

// ---------------- single-pass online-softmax aggregate + skip + relu ----------------
// 4 nodes/wave; node = 2 groups of 8 lanes; lane&7 holds dims 8j..8j+7.
// 3-stage register pipeline: kv loads issued ~2 sections before use.

#define SCLOG2E 0.18033688011112042f  // 0.125 * log2(e)

#define PROC(KX, VX, ACT)                                                    \
  {                                                                          \
    float dp = q0 * bf2f((ushort_t)KX[0]) + q1 * bf2f((ushort_t)KX[1])       \
             + q2 * bf2f((ushort_t)KX[2]) + q3 * bf2f((ushort_t)KX[3])       \
             + q4 * bf2f((ushort_t)KX[4]) + q5 * bf2f((ushort_t)KX[5])       \
             + q6 * bf2f((ushort_t)KX[6]) + q7 * bf2f((ushort_t)KX[7]);      \
    dp = sum8(dp);                                                           \
    float w = 0.f;                                                           \
    if (ACT) {                                                               \
      float sc = dp * SCLOG2E;                                               \
      if (sc <= m + 11.5f) { w = exp2f(sc - m); }                            \
      else { float cc = exp2f(m - sc);                                       \
             se *= cc; a0 *= cc; a1 *= cc; a2 *= cc; a3 *= cc;               \
             a4 *= cc; a5 *= cc; a6 *= cc; a7 *= cc;                         \
             m = sc; w = 1.f; }                                              \
    }                                                                        \
    se += w;                                                                 \
    a0 += w * bf2f((ushort_t)VX[0]); a1 += w * bf2f((ushort_t)VX[1]);        \
    a2 += w * bf2f((ushort_t)VX[2]); a3 += w * bf2f((ushort_t)VX[3]);        \
    a4 += w * bf2f((ushort_t)VX[4]); a5 += w * bf2f((ushort_t)VX[5]);        \
    a6 += w * bf2f((ushort_t)VX[6]); a7 += w * bf2f((ushort_t)VX[7]);        \
  }

__global__ __launch_bounds__(256) void agg_k(const ushort_t* __restrict__ qb,
                                             const ushort_t* __restrict__ kb,
                                             const ushort_t* __restrict__ vb,
                                             const ushort_t* __restrict__ skb,
                                             const int* __restrict__ rowstart,
                                             const int* __restrict__ csr_src,
                                             ushort_t* __restrict__ hout) {
    int wv = threadIdx.x >> 6, lane = threadIdx.x & 63;
    int g = lane >> 3, j = lane & 7, sub = g & 1;
    int nid = blockIdx.x * 16 + wv * 4 + (g >> 1);
    bool nv = nid < NN;
    int nc = nv ? nid : NN - 1;
    int r0 = rowstart[nc];
    int r1 = nv ? rowstart[nc + 1] : r0;

    short8v q8 = *(const short8v*)&qb[(size_t)nc * DD + 8 * j];
    float q0 = bf2f((ushort_t)q8[0]), q1 = bf2f((ushort_t)q8[1]);
    float q2 = bf2f((ushort_t)q8[2]), q3 = bf2f((ushort_t)q8[3]);
    float q4 = bf2f((ushort_t)q8[4]), q5 = bf2f((ushort_t)q8[5]);
    float q6 = bf2f((ushort_t)q8[6]), q7 = bf2f((ushort_t)q8[7]);

    float m = -1.0e38f, se = 0.f;
    float a0 = 0.f, a1 = 0.f, a2 = 0.f, a3 = 0.f, a4 = 0.f, a5 = 0.f, a6 = 0.f, a7 = 0.f;

    int eA = r0 + sub, eB = eA + 2, eC = eA + 4;
    int sA = csr_src[eA < NE ? eA : NE - 1];
    int sB = csr_src[eB < NE ? eB : NE - 1];
    int sC = csr_src[eC < NE ? eC : NE - 1];
    short8v kA = *(const short8v*)&kb[(size_t)sA * DD + 8 * j];
    short8v vA = *(const short8v*)&vb[(size_t)sA * DD + 8 * j];
    short8v kB = *(const short8v*)&kb[(size_t)sB * DD + 8 * j];
    short8v vB = *(const short8v*)&vb[(size_t)sB * DD + 8 * j];
    short8v kC = *(const short8v*)&kb[(size_t)sC * DD + 8 * j];
    short8v vC = *(const short8v*)&vb[(size_t)sC * DD + 8 * j];

    while (__ballot(eA < r1)) {
        int en = eA + 6; int sn = csr_src[en < NE ? en : NE - 1];
        PROC(kA, vA, eA < r1);
        kA = *(const short8v*)&kb[(size_t)sn * DD + 8 * j];
        vA = *(const short8v*)&vb[(size_t)sn * DD + 8 * j];
        eA = en;

        en = eB + 6; sn = csr_src[en < NE ? en : NE - 1];
        PROC(kB, vB, eB < r1);
        kB = *(const short8v*)&kb[(size_t)sn * DD + 8 * j];
        vB = *(const short8v*)&vb[(size_t)sn * DD + 8 * j];
        eB = en;

        en = eC + 6; sn = csr_src[en < NE ? en : NE - 1];
        PROC(kC, vC, eC < r1);
        kC = *(const short8v*)&kb[(size_t)sn * DD + 8 * j];
        vC = *(const short8v*)&vb[(size_t)sn * DD + 8 * j];
        eC = en;
    }

    // combine the node's two groups (xor8)
    float M = fmaxf(m, __shfl_xor(m, 8));
    float cc = exp2f(m - M);
    se *= cc; a0 *= cc; a1 *= cc; a2 *= cc; a3 *= cc;
    a4 *= cc; a5 *= cc; a6 *= cc; a7 *= cc;
    se += __shfl_xor(se, 8);
    a0 += __shfl_xor(a0, 8); a1 += __shfl_xor(a1, 8);
    a2 += __shfl_xor(a2, 8); a3 += __shfl_xor(a3, 8);
    a4 += __shfl_xor(a4, 8); a5 += __shfl_xor(a5, 8);
    a6 += __shfl_xor(a6, 8); a7 += __shfl_xor(a7, 8);

    if (sub == 0 && nv) {
        float inv = 1.0f / (se + 1e-16f);
        short8v sk8 = *(const short8v*)&skb[(size_t)nc * DD + 8 * j];
        float o0 = fmaxf(a0 * inv + bf2f((ushort_t)sk8[0]), 0.f);
        float o1 = fmaxf(a1 * inv + bf2f((ushort_t)sk8[1]), 0.f);
        float o2 = fmaxf(a2 * inv + bf2f((ushort_t)sk8[2]), 0.f);
        float o3 = fmaxf(a3 * inv + bf2f((ushort_t)sk8[3]), 0.f);
        float o4 = fmaxf(a4 * inv + bf2f((ushort_t)sk8[4]), 0.f);
        float o5 = fmaxf(a5 * inv + bf2f((ushort_t)sk8[5]), 0.f);
        float o6 = fmaxf(a6 * inv + bf2f((ushort_t)sk8[6]), 0.f);
        float o7 = fmaxf(a7 * inv + bf2f((ushort_t)sk8[7]), 0.f);
        u32x4 pk;
        pk[0] = cvtpk(o0, o1); pk[1] = cvtpk(o2, o3);
        pk[2] = cvtpk(o4, o5); pk[3] = cvtpk(o6, o7);
        *(u32x4*)&hout[(size_t)nid * DD + 8 * j] = pk;
    }
}

// ---------------- global add pool ----------------

#define POOL_ROWS 128

__global__ __launch_bounds__(256) void pool_k(const ushort_t* __restrict__ h,
                                              const int* __restrict__ batch,
                                              float* __restrict__ pooled) {
    int i0 = blockIdx.x * POOL_ROWS;
    int i1 = i0 + POOL_ROWS; if (i1 > NN) i1 = NN;
    int lane = threadIdx.x & 63;
    int wv = threadIdx.x >> 6;
    float acc = 0.f;
    int gcur = -1;
    for (int i = i0 + wv; i < i1; i += 4) {
        int gi = batch[i];
        if (gi != gcur) {
            if (gcur >= 0) atomicAdd(&pooled[gcur * DD + lane], acc);
            gcur = gi; acc = 0.f;
        }
        acc += bf2f(h[(size_t)i * DD + lane]);
    }
    if (gcur >= 0) atomicAdd(&pooled[gcur * DD + lane], acc);
}

// ---------------- head ----------------

__global__ __launch_bounds__(64) void head_k(const float* __restrict__ pooled2,
                                             const float* __restrict__ W1,
                                             const float* __restrict__ b1,
                                             const float* __restrict__ W2,
                                             const float* __restrict__ b2,
                                             float* __restrict__ out) {
    int g = blockIdx.x;
    int c = threadIdx.x;
    __shared__ float pg[64], p[64];
    pg[c] = pooled2[g * DD + c];
    __syncthreads();
    float a = b1[c];
#pragma unroll 8
    for (int kk = 0; kk < 64; kk++) a += pg[kk] * W1[kk * DD + c];
    p[c] = fmaxf(a, 0.f);
    __syncthreads();
    if (c < 10) {
        float o = b2[c];
#pragma unroll 8
        for (int kk = 0; kk < 64; kk++) o += p[kk] * W2[kk * 10 + c];
        out[g * 10 + c] = o;
    }
}

// ---------------- launch ----------------

extern "C" void kernel_launch(void* const* d_in, const int* in_sizes, int n_in,
                              void* d_out, int out_size, void* d_ws, size_t ws_size,
                              hipStream_t stream) {
    const float* x    = (const float*)d_in[0];
    const int*   ei   = (const int*)d_in[1];
    const int*   batch= (const int*)d_in[2];
    const float* Wq   = (const float*)d_in[3];
    const float* bq   = (const float*)d_in[4];
    const float* Wk   = (const float*)d_in[5];
    const float* bk   = (const float*)d_in[6];
    const float* Wv   = (const float*)d_in[7];
    const float* bv   = (const float*)d_in[8];
    const float* Wsp  = (const float*)d_in[9];
    const float* bsp  = (const float*)d_in[10];
    const float* W1   = (const float*)d_in[11];
    const float* b1   = (const float*)d_in[12];
    const float* W2   = (const float*)d_in[13];
    const float* b2   = (const float*)d_in[14];
    float* out = (float*)d_out;
    float* pooled = out + NG * 10;

    const int* srcv = ei;
    const int* dstv = ei + NE;

    const size_t NEL = (size_t)NN * DD;
    ushort_t* hbf = (ushort_t*)d_ws;                 // [NN][64]
    ushort_t* qb  = hbf + NEL;
    ushort_t* kb  = qb  + NEL;
    ushort_t* vb  = kb  + NEL;
    ushort_t* skb = vb  + NEL;
    u32* binbuf   = (u32*)(skb + NEL);               // [NBUK*BCAP]
    int* gcur     = (int*)(binbuf + (size_t)NBUK * BCAP);  // [NBUK]
    int* bukbase  = gcur + NBUK;                     // [NBUK]
    int* rowstart = bukbase + NBUK;                  // [NN+1]
    int* csr_src  = rowstart + (NN + 1);             // [NE]
    ushort_t* wpack = (ushort_t*)(csr_src + NE);     // 12*4096 bf16

    int totOut = NG * 10 + NL * NG * DD;

    zero2_k<<<(totOut + 255) / 256, 256, 0, stream>>>(out, totOut, gcur, NBUK);
    cvt_k<<<((int)NEL / 4 + 255) / 256, 256, 0, stream>>>(x, hbf, (int)NEL);
    packw_k<<<NL * 4, 64, 0, stream>>>(Wq, Wk, Wv, Wsp, wpack);

    bin_k<<<NBLK, 256, 0, stream>>>(srcv, dstv, binbuf, gcur);
    scanB_k<<<1, 256, 0, stream>>>(gcur, bukbase, rowstart);
    csr_k<<<NBUK, 256, 0, stream>>>(binbuf, gcur, bukbase, rowstart, csr_src);

    int gtiles = (NN + 63) / 64;
    int poolblocks = (NN + POOL_ROWS - 1) / POOL_ROWS;
    for (int l = 0; l < NL; l++) {
        gemm4_k<<<gtiles, 256, 0, stream>>>(hbf, wpack + (size_t)l * 4 * 8 * 512,
                                            bq + l * DD, bk + l * DD, bv + l * DD, bsp + l * DD,
                                            qb, kb, vb, skb);
        agg_k<<<(NN + 15) / 16, 256, 0, stream>>>(qb, kb, vb, skb, rowstart, csr_src, hbf);
        pool_k<<<poolblocks, 256, 0, stream>>>(hbf, batch, pooled + l * NG * DD);
    }
    head_k<<<NG, 64, 0, stream>>>(pooled + 2 * NG * DD, W1, b1, W2, b2, out);
}

// Round 7
// 281.130 us; speedup vs baseline: 1.2054x; 1.2054x over previous
//
#include <hip/hip_runtime.h>
#include <hip/hip_bf16.h>
#include <math.h>

#define NN 100000
#define NE 1000000
#define DD 64
#define NG 128
#define NL 3

#define NBUK 196          // dst >> 9 buckets (512 nodes each)
#define EPB 2048          // edges per bin block
#define NBLK ((NE + EPB - 1) / EPB)   // 489
#define BCAP 6144         // per-bucket capacity (mean 5120, ~14 sigma margin)

typedef unsigned short ushort_t;
typedef unsigned int u32;
typedef __attribute__((ext_vector_type(8))) short short8v;
typedef __attribute__((ext_vector_type(2))) float f32x2;
typedef __attribute__((ext_vector_type(4))) float f32x4;
typedef __attribute__((ext_vector_type(4))) unsigned int u32x4;

__device__ __forceinline__ ushort_t f2bf(float f) {
    __hip_bfloat16 h = __float2bfloat16(f);
    return *reinterpret_cast<ushort_t*>(&h);
}
__device__ __forceinline__ unsigned cvtpk(float lo, float hi) {
    unsigned r;
    asm("v_cvt_pk_bf16_f32 %0, %1, %2" : "=v"(r) : "v"(lo), "v"(hi));
    return r;
}
// unpack 2 bf16 (packed in u32) -> f32x2
__device__ __forceinline__ f32x2 bfpair(u32 u) {
    f32x2 r;
    r.x = __builtin_bit_cast(float, u << 16);
    r.y = __builtin_bit_cast(float, u & 0xffff0000u);
    return r;
}
// sum over each 8-lane group (lanes grouped by lane>>3)
__device__ __forceinline__ float sum8(float x) {
    int v = __builtin_bit_cast(int, x);
    int t1 = __builtin_amdgcn_update_dpp(0, v, 0xB1, 0xF, 0xF, true);   // quad_perm xor1
    x += __builtin_bit_cast(float, t1);
    v = __builtin_bit_cast(int, x);
    int t2 = __builtin_amdgcn_update_dpp(0, v, 0x4E, 0xF, 0xF, true);   // quad_perm xor2
    x += __builtin_bit_cast(float, t2);
    v = __builtin_bit_cast(int, x);
    int t3 = __builtin_amdgcn_ds_swizzle(v, 0x101F);                    // xor4
    x += __builtin_bit_cast(float, t3);
    return x;
}
// 16B row fragment pointer: row s, 8-dim chunk j
__device__ __forceinline__ const u32x4* rowp(const ushort_t* base, int s, int j) {
    return (const u32x4*)(base + (((u32)s << 6) + ((u32)j << 3)));
}

// ---------------- fused setup: cvt + zero + packw ----------------

__global__ __launch_bounds__(256) void setup_k(const float* __restrict__ x, ushort_t* __restrict__ hbf,
                                               float* __restrict__ out, int totOut,
                                               int* __restrict__ gcur,
                                               const float* __restrict__ Wq, const float* __restrict__ Wk,
                                               const float* __restrict__ Wv, const float* __restrict__ Ws_,
                                               ushort_t* __restrict__ wpack,
                                               int cvtBlocks, int zeroBlocks) {
    int b = blockIdx.x, t = threadIdx.x;
    if (b < cvtBlocks) {        // bf16 convert of x (NEL divisible by 1024)
        int base = (b * 256 + t) * 4;
        float4 v = *(const float4*)&x[base];
        uint2 pk;
        pk.x = cvtpk(v.x, v.y);
        pk.y = cvtpk(v.z, v.w);
        *(uint2*)&hbf[base] = pk;
        return;
    }
    b -= cvtBlocks;
    if (b < zeroBlocks) {       // zero d_out (pooled accumulators) + gcur
        int i = b * 256 + t;
        if (i < totOut) out[i] = 0.f;
        if (b == 0 && t < NBUK) gcur[t] = 0;
        return;
    }
    b -= zeroBlocks;            // packw: b in [0, NL*4)
    if (t < 64) {
        int mat = b & 3, layer = b >> 2;
        const float* W = ((mat == 0) ? Wq : (mat == 1) ? Wk : (mat == 2) ? Wv : Ws_) + layer * DD * DD;
        int lq = t >> 4, ln = t & 15;
#pragma unroll
        for (int ct = 0; ct < 4; ct++)
#pragma unroll
            for (int ks = 0; ks < 2; ks++)
#pragma unroll
                for (int j = 0; j < 8; j++) {
                    float v = W[(ks * 32 + lq * 8 + j) * DD + ct * 16 + ln];
                    wpack[((size_t)(b * 8 + ct * 2 + ks)) * 512 + t * 8 + j] = f2bf(v);
                }
    }
}

// ---------------- CSR build: bucket-major direct placement ----------------
// pack = (dst&511)<<17 | src   (src < 2^17)

__global__ __launch_bounds__(256) void bin_k(const int* __restrict__ src,
                                             const int* __restrict__ dst,
                                             u32* __restrict__ binbuf,
                                             int* __restrict__ gcur) {
    __shared__ int hist[NBUK];
    __shared__ int excl[NBUK];
    __shared__ int cur[NBUK];
    __shared__ int gbase[NBUK];
    __shared__ int tmp[256];
    __shared__ u32 pairs[EPB];
    __shared__ unsigned char bukid[EPB];
    int t = threadIdx.x;
    int blk = blockIdx.x;
    int e0 = blk * EPB;
    int totvalid = NE - e0; if (totvalid > EPB) totvalid = EPB;

    for (int i = t; i < NBUK; i += 256) hist[i] = 0;
    __syncthreads();

    int mysrc[8], mydst[8];
#pragma unroll
    for (int i = 0; i < 8; i++) {
        int e = e0 + i * 256 + t;
        bool v = e < NE;
        mysrc[i] = v ? src[e] : -1;
        mydst[i] = v ? dst[e] : -1;
        if (v) atomicAdd(&hist[mydst[i] >> 9], 1);
    }
    __syncthreads();

    int v = (t < NBUK) ? hist[t] : 0;
    tmp[t] = v;
    __syncthreads();
#pragma unroll
    for (int off = 1; off < 256; off <<= 1) {
        int a = (t >= off) ? tmp[t - off] : 0;
        __syncthreads();
        tmp[t] += a;
        __syncthreads();
    }
    if (t < NBUK) { excl[t] = tmp[t] - v; cur[t] = tmp[t] - v; }
    __syncthreads();

#pragma unroll
    for (int i = 0; i < 8; i++) {
        if (mydst[i] >= 0) {
            int b = mydst[i] >> 9;
            int p = atomicAdd(&cur[b], 1);
            pairs[p] = ((u32)(mydst[i] & 511) << 17) | (u32)mysrc[i];
            bukid[p] = (unsigned char)b;
        }
    }
    if (t < NBUK && v > 0) gbase[t] = atomicAdd(&gcur[t], v);
    __syncthreads();

    for (int i = t; i < totvalid; i += 256) {
        int b = bukid[i];
        int idx = gbase[b] + (i - excl[b]);
        if (idx < BCAP) binbuf[(size_t)b * BCAP + idx] = pairs[i];
    }
}

__global__ __launch_bounds__(256) void csr_k(const u32* __restrict__ binbuf,
                                             const int* __restrict__ gcur,
                                             int* __restrict__ rowstart,
                                             int* __restrict__ csr_src) {
    __shared__ u32 pairs[BCAP];
    __shared__ int csrb[BCAP];
    __shared__ int deg[512];
    __shared__ int excl[512];
    __shared__ int cur[512];
    __shared__ int tmp[512];
    __shared__ int bt[256];
    int b = blockIdx.x;
    int t = threadIdx.x;

    // in-block scan of bucket totals -> base for this bucket
    int bv = 0;
    if (t < NBUK) { bv = gcur[t]; if (bv > BCAP) bv = BCAP; }
    bt[t] = bv;
    __syncthreads();
#pragma unroll
    for (int off = 1; off < 256; off <<= 1) {
        int a = (t >= off) ? bt[t - off] : 0;
        __syncthreads();
        bt[t] += a;
        __syncthreads();
    }
    int base = (b == 0) ? 0 : bt[b - 1];
    int T = bt[b] - base;
    if (b == 0 && t == 0) rowstart[NN] = bt[NBUK - 1];
    int nbase = b << 9;

    for (int i = t; i < 512; i += 256) deg[i] = 0;
    for (int i = t; i < T; i += 256) pairs[i] = binbuf[(size_t)b * BCAP + i];
    __syncthreads();
    for (int i = t; i < T; i += 256) atomicAdd(&deg[pairs[i] >> 17], 1);
    __syncthreads();

    int v0 = deg[t], v1 = deg[t + 256];
    tmp[t] = v0; tmp[t + 256] = v1;
    __syncthreads();
#pragma unroll
    for (int off = 1; off < 512; off <<= 1) {
        int a0 = (t >= off) ? tmp[t - off] : 0;
        int i1 = t + 256;
        int a1 = (i1 >= off) ? tmp[i1 - off] : 0;
        __syncthreads();
        tmp[t] += a0; tmp[i1] += a1;
        __syncthreads();
    }
    excl[t] = tmp[t] - v0; excl[t + 256] = tmp[t + 256] - v1;
    cur[t] = excl[t]; cur[t + 256] = excl[t + 256];
    __syncthreads();

    for (int i = t; i < 512; i += 256) {
        int n = nbase + i;
        if (n < NN) rowstart[n] = base + excl[i];
    }

    for (int i = t; i < T; i += 256) {
        u32 p = pairs[i];
        int pos = atomicAdd(&cur[p >> 17], 1);
        csrb[pos] = (int)(p & 0x1FFFFu);
    }
    __syncthreads();
    for (int i = t; i < T; i += 256) csr_src[base + i] = csrb[i];
}

// ---------------- fused 4-matrix MFMA GEMM, swapped operands ----------------

__global__ __launch_bounds__(256) void gemm4_k(const ushort_t* __restrict__ hbf,
                                               const ushort_t* __restrict__ wpl,
                                               const float* __restrict__ bq_, const float* __restrict__ bk_,
                                               const float* __restrict__ bv_, const float* __restrict__ bs_,
                                               ushort_t* __restrict__ qo, ushort_t* __restrict__ ko,
                                               ushort_t* __restrict__ vo, ushort_t* __restrict__ so) {
    int t = threadIdx.x;
    int lane = t & 63, wv = t >> 6;
    int ln = lane & 15, lq = lane >> 4;
    int rowbase = blockIdx.x * 64;

    const float* bsel = (wv == 0) ? bq_ : (wv == 1) ? bk_ : (wv == 2) ? bv_ : bs_;
    ushort_t* osel    = (wv == 0) ? qo : (wv == 1) ? ko : (wv == 2) ? vo : so;

    short8v wfrag[4][2];
#pragma unroll
    for (int ct = 0; ct < 4; ct++)
#pragma unroll
        for (int ks = 0; ks < 2; ks++)
            wfrag[ct][ks] = *(const short8v*)&wpl[((size_t)(wv * 8 + ct * 2 + ks)) * 512 + lane * 8];

    float4 bias[4];
#pragma unroll
    for (int ct = 0; ct < 4; ct++) bias[ct] = *(const float4*)&bsel[ct * 16 + lq * 4];

#pragma unroll
    for (int rt = 0; rt < 4; rt++) {
        int grow = rowbase + rt * 16 + ln;
        bool rv = grow < NN;
        int gr = rv ? grow : NN - 1;
        short8v h0 = *(const short8v*)&hbf[(size_t)gr * DD + lq * 8];
        short8v h1 = *(const short8v*)&hbf[(size_t)gr * DD + 32 + lq * 8];
#pragma unroll
        for (int ct = 0; ct < 4; ct++) {
            f32x4 acc;
            acc[0] = bias[ct].x; acc[1] = bias[ct].y; acc[2] = bias[ct].z; acc[3] = bias[ct].w;
            acc = __builtin_amdgcn_mfma_f32_16x16x32_bf16(wfrag[ct][0], h0, acc, 0, 0, 0);
            acc = __builtin_amdgcn_mfma_f32_16x16x32_bf16(wfrag[ct][1], h1, acc, 0, 0, 0);
            if (rv) {
                uint2 pk;
                pk.x = cvtpk(acc[0], acc[1]);
                pk.y = cvtpk(acc[2], acc[3]);
                *(uint2*)&osel[(size_t)grow * DD + ct * 16 + lq * 4] = pk;
            }
        }
    }
}

// ---------------- single-pass online-softmax aggregate + skip + relu ----------------
// 4 nodes/wave; node = 2 groups of 8 lanes (sub=0/1); lane&7 holds dims 8j..8j+7.
// 3-stage register pipeline, prefetch clamped to the node's LAST edge (cache-hot,
// no junk HBM traffic). Packed-f32 math (v_pk_fma_f32).

#define SCLOG2E 0.18033688011112042f  // 0.125 * log2(e)

#define PROC(KX, VX, ACT)                                              \
  {                                                                    \
    f32x2 dp2 = q01 * bfpair(KX.x);                                    \
    dp2 += q23 * bfpair(KX.y);                                         \
    dp2 += q45 * bfpair(KX.z);                                         \
    dp2 += q67 * bfpair(KX.w);                                         \
    float dp = dp2.x + dp2.y;                                          \
    dp = sum8(dp);                                                     \
    float w = 0.f;                                                     \
    if (ACT) {                                                         \
      float sc = dp * SCLOG2E;                                         \
      if (sc <= m + 11.5f) { w = exp2f(sc - m); }                      \
      else { float cc = exp2f(m - sc);                                 \
             se *= cc; a01 *= cc; a23 *= cc; a45 *= cc; a67 *= cc;     \
             m = sc; w = 1.f; }                                        \
    }                                                                  \
    se += w;                                                           \
    a01 += bfpair(VX.x) * w;                                           \
    a23 += bfpair(VX.y) * w;                                           \
    a45 += bfpair(VX.z) * w;                                           \
    a67 += bfpair(VX.w) * w;                                           \
  }

__global__ __launch_bounds__(256) void agg_k(const ushort_t* __restrict__ qb,
                                             const ushort_t* __restrict__ kb,
                                             const ushort_t* __restrict__ vb,
                                             const ushort_t* __restrict__ skb,
                                             const int* __restrict__ rowstart,
                                             const int* __restrict__ csr_src,
                                             ushort_t* __restrict__ hout) {
    int wv = threadIdx.x >> 6, lane = threadIdx.x & 63;
    int g = lane >> 3, j = lane & 7, sub = g & 1;
    int nid = blockIdx.x * 16 + wv * 4 + (g >> 1);
    if (nid >= NN) return;
    int r0 = rowstart[nid];
    int r1 = rowstart[nid + 1];

    u32x4 q8 = *rowp(qb, nid, j);
    f32x2 q01 = bfpair(q8.x), q23 = bfpair(q8.y), q45 = bfpair(q8.z), q67 = bfpair(q8.w);

    float m = -1.0e38f, se = 0.f;
    f32x2 a01 = {0.f, 0.f}, a23 = {0.f, 0.f}, a45 = {0.f, 0.f}, a67 = {0.f, 0.f};

    int clampE = r1 - 1; if (clampE < 0) clampE = 0;   // node's own last edge: cache-hot
    int eA = r0 + sub, eB = eA + 2, eC = eA + 4;
    int sA = csr_src[eA < clampE ? eA : clampE];
    int sB = csr_src[eB < clampE ? eB : clampE];
    int sC = csr_src[eC < clampE ? eC : clampE];
    u32x4 kA = *rowp(kb, sA, j), vA = *rowp(vb, sA, j);
    u32x4 kB = *rowp(kb, sB, j), vB = *rowp(vb, sB, j);
    u32x4 kC = *rowp(kb, sC, j), vC = *rowp(vb, sC, j);

    while (__ballot(eA < r1)) {
        int en = eA + 6; int sn = csr_src[en < clampE ? en : clampE];
        PROC(kA, vA, eA < r1);
        kA = *rowp(kb, sn, j); vA = *rowp(vb, sn, j);
        eA = en;

        en = eB + 6; sn = csr_src[en < clampE ? en : clampE];
        PROC(kB, vB, eB < r1);
        kB = *rowp(kb, sn, j); vB = *rowp(vb, sn, j);
        eB = en;

        en = eC + 6; sn = csr_src[en < clampE ? en : clampE];
        PROC(kC, vC, eC < r1);
        kC = *rowp(kb, sn, j); vC = *rowp(vb, sn, j);
        eC = en;
    }

    // combine the node's two groups (xor8)
    float M = fmaxf(m, __shfl_xor(m, 8));
    float cc = exp2f(m - M);
    se *= cc; a01 *= cc; a23 *= cc; a45 *= cc; a67 *= cc;
    se += __shfl_xor(se, 8);
    a01.x += __shfl_xor(a01.x, 8); a01.y += __shfl_xor(a01.y, 8);
    a23.x += __shfl_xor(a23.x, 8); a23.y += __shfl_xor(a23.y, 8);
    a45.x += __shfl_xor(a45.x, 8); a45.y += __shfl_xor(a45.y, 8);
    a67.x += __shfl_xor(a67.x, 8); a67.y += __shfl_xor(a67.y, 8);

    if (sub == 0) {
        float inv = 1.0f / (se + 1e-16f);
        u32x4 sk = *rowp(skb, nid, j);
        f32x2 o01 = a01 * inv + bfpair(sk.x);
        f32x2 o23 = a23 * inv + bfpair(sk.y);
        f32x2 o45 = a45 * inv + bfpair(sk.z);
        f32x2 o67 = a67 * inv + bfpair(sk.w);
        u32x4 pk;
        pk.x = cvtpk(fmaxf(o01.x, 0.f), fmaxf(o01.y, 0.f));
        pk.y = cvtpk(fmaxf(o23.x, 0.f), fmaxf(o23.y, 0.f));
        pk.z = cvtpk(fmaxf(o45.x, 0.f), fmaxf(o45.y, 0.f));
        pk.w = cvtpk(fmaxf(o67.x, 0.f), fmaxf(o67.y, 0.f));
        *(u32x4*)(hout + (((u32)nid << 6) + ((u32)j << 3))) = pk;
    }
}

// ---------------- global add pool ----------------

#define POOL_ROWS 128

__global__ __launch_bounds__(256) void pool_k(const ushort_t* __restrict__ h,
                                              const int* __restrict__ batch,
                                              float* __restrict__ pooled) {
    int i0 = blockIdx.x * POOL_ROWS;
    int i1 = i0 + POOL_ROWS; if (i1 > NN) i1 = NN;
    int lane = threadIdx.x & 63;
    int wv = threadIdx.x >> 6;
    float acc = 0.f;
    int gcur = -1;
    for (int i = i0 + wv; i < i1; i += 4) {
        int gi = batch[i];
        if (gi != gcur) {
            if (gcur >= 0) atomicAdd(&pooled[gcur * DD + lane], acc);
            gcur = gi; acc = 0.f;
        }
        unsigned u = ((unsigned)h[(size_t)i * DD + lane]) << 16;
        acc += __builtin_bit_cast(float, u);
    }
    if (gcur >= 0) atomicAdd(&pooled[gcur * DD + lane], acc);
}

// ---------------- head ----------------

__global__ __launch_bounds__(64) void head_k(const float* __restrict__ pooled2,
                                             const float* __restrict__ W1,
                                             const float* __restrict__ b1,
                                             const float* __restrict__ W2,
                                             const float* __restrict__ b2,
                                             float* __restrict__ out) {
    int g = blockIdx.x;
    int c = threadIdx.x;
    __shared__ float pg[64], p[64];
    pg[c] = pooled2[g * DD + c];
    __syncthreads();
    float a = b1[c];
#pragma unroll 8
    for (int kk = 0; kk < 64; kk++) a += pg[kk] * W1[kk * DD + c];
    p[c] = fmaxf(a, 0.f);
    __syncthreads();
    if (c < 10) {
        float o = b2[c];
#pragma unroll 8
        for (int kk = 0; kk < 64; kk++) o += p[kk] * W2[kk * 10 + c];
        out[g * 10 + c] = o;
    }
}

// ---------------- launch ----------------

extern "C" void kernel_launch(void* const* d_in, const int* in_sizes, int n_in,
                              void* d_out, int out_size, void* d_ws, size_t ws_size,
                              hipStream_t stream) {
    const float* x    = (const float*)d_in[0];
    const int*   ei   = (const int*)d_in[1];
    const int*   batch= (const int*)d_in[2];
    const float* Wq   = (const float*)d_in[3];
    const float* bq   = (const float*)d_in[4];
    const float* Wk   = (const float*)d_in[5];
    const float* bk   = (const float*)d_in[6];
    const float* Wv   = (const float*)d_in[7];
    const float* bv   = (const float*)d_in[8];
    const float* Wsp  = (const float*)d_in[9];
    const float* bsp  = (const float*)d_in[10];
    const float* W1   = (const float*)d_in[11];
    const float* b1   = (const float*)d_in[12];
    const float* W2   = (const float*)d_in[13];
    const float* b2   = (const float*)d_in[14];
    float* out = (float*)d_out;
    float* pooled = out + NG * 10;

    const int* srcv = ei;
    const int* dstv = ei + NE;

    const size_t NEL = (size_t)NN * DD;
    ushort_t* hbf = (ushort_t*)d_ws;                 // [NN][64]
    ushort_t* qb  = hbf + NEL;
    ushort_t* kb  = qb  + NEL;
    ushort_t* vb  = kb  + NEL;
    ushort_t* skb = vb  + NEL;
    u32* binbuf   = (u32*)(skb + NEL);               // [NBUK*BCAP]
    int* gcur     = (int*)(binbuf + (size_t)NBUK * BCAP);  // [NBUK]
    int* rowstart = gcur + NBUK;                     // [NN+1]
    int* csr_src  = rowstart + (NN + 1);             // [NE]
    ushort_t* wpack = (ushort_t*)(csr_src + NE);     // 12*4096 bf16

    int totOut = NG * 10 + NL * NG * DD;
    int cvtBlocks = (int)(NEL / 4 / 256);            // 6250 (exact)
    int zeroBlocks = (totOut + 255) / 256;           // 102

    setup_k<<<cvtBlocks + zeroBlocks + NL * 4, 256, 0, stream>>>(
        x, hbf, out, totOut, gcur, Wq, Wk, Wv, Wsp, wpack, cvtBlocks, zeroBlocks);

    bin_k<<<NBLK, 256, 0, stream>>>(srcv, dstv, binbuf, gcur);
    csr_k<<<NBUK, 256, 0, stream>>>(binbuf, gcur, rowstart, csr_src);

    int gtiles = (NN + 63) / 64;
    int poolblocks = (NN + POOL_ROWS - 1) / POOL_ROWS;
    for (int l = 0; l < NL; l++) {
        gemm4_k<<<gtiles, 256, 0, stream>>>(hbf, wpack + (size_t)l * 4 * 8 * 512,
                                            bq + l * DD, bk + l * DD, bv + l * DD, bsp + l * DD,
                                            qb, kb, vb, skb);
        agg_k<<<(NN + 15) / 16, 256, 0, stream>>>(qb, kb, vb, skb, rowstart, csr_src, hbf);
        pool_k<<<poolblocks, 256, 0, stream>>>(hbf, batch, pooled + l * NG * DD);
    }
    head_k<<<NG, 64, 0, stream>>>(pooled + 2 * NG * DD, W1, b1, W2, b2, out);
}

// Round 9
// 279.632 us; speedup vs baseline: 1.2118x; 1.0054x over previous
//
#include <hip/hip_runtime.h>
#include <hip/hip_bf16.h>
#include <math.h>

#define NN 100000
#define NE 1000000
#define DD 64
#define NG 128
#define NL 3

#define NBUK 196          // dst >> 9 buckets (512 nodes each)
#define EPB 2048          // edges per bin block
#define NBLK ((NE + EPB - 1) / EPB)   // 489
#define BCAP 6144         // per-bucket capacity (mean 5120, ~14 sigma margin)

typedef unsigned short ushort_t;
typedef unsigned int u32;
typedef __attribute__((ext_vector_type(8))) short short8v;
typedef __attribute__((ext_vector_type(2))) float f32x2;
typedef __attribute__((ext_vector_type(4))) float f32x4;
typedef __attribute__((ext_vector_type(4))) unsigned int u32x4;

__device__ __forceinline__ ushort_t f2bf(float f) {
    __hip_bfloat16 h = __float2bfloat16(f);
    return *reinterpret_cast<ushort_t*>(&h);
}
__device__ __forceinline__ unsigned cvtpk(float lo, float hi) {
    unsigned r;
    asm("v_cvt_pk_bf16_f32 %0, %1, %2" : "=v"(r) : "v"(lo), "v"(hi));
    return r;
}
// unpack 2 bf16 (packed in u32) -> f32x2
__device__ __forceinline__ f32x2 bfpair(u32 u) {
    f32x2 r;
    r.x = __builtin_bit_cast(float, u << 16);
    r.y = __builtin_bit_cast(float, u & 0xffff0000u);
    return r;
}
// unpack 2 fp8 e4m3 (word half HI of u) -> f32x2 (HW convert; HI must be ICE)
template <bool HI>
__device__ __forceinline__ f32x2 f8pair(u32 u) {
    return __builtin_amdgcn_cvt_pk_f32_fp8(u, HI);
}
// sum over each 8-lane group: xor1, xor2 quad_perm + row_half_mirror (all VALU DPP)
__device__ __forceinline__ float sum8(float x) {
    int v = __builtin_bit_cast(int, x);
    x += __builtin_bit_cast(float, __builtin_amdgcn_update_dpp(0, v, 0xB1, 0xF, 0xF, true));
    v = __builtin_bit_cast(int, x);
    x += __builtin_bit_cast(float, __builtin_amdgcn_update_dpp(0, v, 0x4E, 0xF, 0xF, true));
    v = __builtin_bit_cast(int, x);
    x += __builtin_bit_cast(float, __builtin_amdgcn_update_dpp(0, v, 0x141, 0xF, 0xF, true));
    return x;
}
// 16B row fragment pointer: row s, 8-dim chunk j
__device__ __forceinline__ const u32x4* rowp(const ushort_t* base, int s, int j) {
    return (const u32x4*)(base + (((u32)s << 6) + ((u32)j << 3)));
}

// ---------------- fused setup: cvt + zero + packw ----------------

__global__ __launch_bounds__(256) void setup_k(const float* __restrict__ x, ushort_t* __restrict__ hbf,
                                               float* __restrict__ out, int totOut,
                                               int* __restrict__ gcur,
                                               const float* __restrict__ Wq, const float* __restrict__ Wk,
                                               const float* __restrict__ Wv, const float* __restrict__ Ws_,
                                               ushort_t* __restrict__ wpack,
                                               int cvtBlocks, int zeroBlocks) {
    int b = blockIdx.x, t = threadIdx.x;
    if (b < cvtBlocks) {        // bf16 convert of x (NEL divisible by 1024)
        int base = (b * 256 + t) * 4;
        float4 v = *(const float4*)&x[base];
        uint2 pk;
        pk.x = cvtpk(v.x, v.y);
        pk.y = cvtpk(v.z, v.w);
        *(uint2*)&hbf[base] = pk;
        return;
    }
    b -= cvtBlocks;
    if (b < zeroBlocks) {       // zero d_out (pooled accumulators) + gcur
        int i = b * 256 + t;
        if (i < totOut) out[i] = 0.f;
        if (b == 0 && t < NBUK) gcur[t] = 0;
        return;
    }
    b -= zeroBlocks;            // packw: b in [0, NL*4)
    if (t < 64) {
        int mat = b & 3, layer = b >> 2;
        const float* W = ((mat == 0) ? Wq : (mat == 1) ? Wk : (mat == 2) ? Wv : Ws_) + layer * DD * DD;
        int lq = t >> 4, ln = t & 15;
#pragma unroll
        for (int ct = 0; ct < 4; ct++)
#pragma unroll
            for (int ks = 0; ks < 2; ks++)
#pragma unroll
                for (int j = 0; j < 8; j++) {
                    float v = W[(ks * 32 + lq * 8 + j) * DD + ct * 16 + ln];
                    wpack[((size_t)(b * 8 + ct * 2 + ks)) * 512 + t * 8 + j] = f2bf(v);
                }
    }
}

// ---------------- CSR build: bucket-major direct placement ----------------
// pack = (dst&511)<<17 | src   (src < 2^17)

__global__ __launch_bounds__(256) void bin_k(const int* __restrict__ src,
                                             const int* __restrict__ dst,
                                             u32* __restrict__ binbuf,
                                             int* __restrict__ gcur) {
    __shared__ int hist[NBUK];
    __shared__ int excl[NBUK];
    __shared__ int cur[NBUK];
    __shared__ int gbase[NBUK];
    __shared__ int tmp[256];
    __shared__ u32 pairs[EPB];
    __shared__ unsigned char bukid[EPB];
    int t = threadIdx.x;
    int blk = blockIdx.x;
    int e0 = blk * EPB;
    int totvalid = NE - e0; if (totvalid > EPB) totvalid = EPB;

    for (int i = t; i < NBUK; i += 256) hist[i] = 0;
    __syncthreads();

    int mysrc[8], mydst[8];
#pragma unroll
    for (int i = 0; i < 8; i++) {
        int e = e0 + i * 256 + t;
        bool v = e < NE;
        mysrc[i] = v ? src[e] : -1;
        mydst[i] = v ? dst[e] : -1;
        if (v) atomicAdd(&hist[mydst[i] >> 9], 1);
    }
    __syncthreads();

    int v = (t < NBUK) ? hist[t] : 0;
    tmp[t] = v;
    __syncthreads();
#pragma unroll
    for (int off = 1; off < 256; off <<= 1) {
        int a = (t >= off) ? tmp[t - off] : 0;
        __syncthreads();
        tmp[t] += a;
        __syncthreads();
    }
    if (t < NBUK) { excl[t] = tmp[t] - v; cur[t] = tmp[t] - v; }
    __syncthreads();

#pragma unroll
    for (int i = 0; i < 8; i++) {
        if (mydst[i] >= 0) {
            int b = mydst[i] >> 9;
            int p = atomicAdd(&cur[b], 1);
            pairs[p] = ((u32)(mydst[i] & 511) << 17) | (u32)mysrc[i];
            bukid[p] = (unsigned char)b;
        }
    }
    if (t < NBUK && v > 0) gbase[t] = atomicAdd(&gcur[t], v);
    __syncthreads();

    for (int i = t; i < totvalid; i += 256) {
        int b = bukid[i];
        int idx = gbase[b] + (i - excl[b]);
        if (idx < BCAP) binbuf[(size_t)b * BCAP + idx] = pairs[i];
    }
}

__global__ __launch_bounds__(256) void csr_k(const u32* __restrict__ binbuf,
                                             const int* __restrict__ gcur,
                                             int* __restrict__ rowstart,
                                             int* __restrict__ csr_src) {
    __shared__ u32 pairs[BCAP];
    __shared__ int csrb[BCAP];
    __shared__ int deg[512];
    __shared__ int excl[512];
    __shared__ int cur[512];
    __shared__ int tmp[512];
    __shared__ int bt[256];
    int b = blockIdx.x;
    int t = threadIdx.x;

    // in-block scan of bucket totals -> base for this bucket
    int bv = 0;
    if (t < NBUK) { bv = gcur[t]; if (bv > BCAP) bv = BCAP; }
    bt[t] = bv;
    __syncthreads();
#pragma unroll
    for (int off = 1; off < 256; off <<= 1) {
        int a = (t >= off) ? bt[t - off] : 0;
        __syncthreads();
        bt[t] += a;
        __syncthreads();
    }
    int base = (b == 0) ? 0 : bt[b - 1];
    int T = bt[b] - base;
    if (b == 0 && t == 0) rowstart[NN] = bt[NBUK - 1];
    int nbase = b << 9;

    for (int i = t; i < 512; i += 256) deg[i] = 0;
    for (int i = t; i < T; i += 256) pairs[i] = binbuf[(size_t)b * BCAP + i];
    __syncthreads();
    for (int i = t; i < T; i += 256) atomicAdd(&deg[pairs[i] >> 17], 1);
    __syncthreads();

    int v0 = deg[t], v1 = deg[t + 256];
    tmp[t] = v0; tmp[t + 256] = v1;
    __syncthreads();
#pragma unroll
    for (int off = 1; off < 512; off <<= 1) {
        int a0 = (t >= off) ? tmp[t - off] : 0;
        int i1 = t + 256;
        int a1 = (i1 >= off) ? tmp[i1 - off] : 0;
        __syncthreads();
        tmp[t] += a0; tmp[i1] += a1;
        __syncthreads();
    }
    excl[t] = tmp[t] - v0; excl[t + 256] = tmp[t + 256] - v1;
    cur[t] = excl[t]; cur[t + 256] = excl[t + 256];
    __syncthreads();

    for (int i = t; i < 512; i += 256) {
        int n = nbase + i;
        if (n < NN) rowstart[n] = base + excl[i];
    }

    for (int i = t; i < T; i += 256) {
        u32 p = pairs[i];
        int pos = atomicAdd(&cur[p >> 17], 1);
        csrb[pos] = (int)(p & 0x1FFFFu);
    }
    __syncthreads();
    for (int i = t; i < T; i += 256) csr_src[base + i] = csrb[i];
}

// ---------------- fused 4-matrix MFMA GEMM, swapped operands ----------------
// k-wave (wv==1) emits fp8 e4m3 (64B rows); q/v/skip emit bf16.

__global__ __launch_bounds__(256) void gemm4_k(const ushort_t* __restrict__ hbf,
                                               const ushort_t* __restrict__ wpl,
                                               const float* __restrict__ bq_, const float* __restrict__ bk_,
                                               const float* __restrict__ bv_, const float* __restrict__ bs_,
                                               ushort_t* __restrict__ qo, unsigned char* __restrict__ kf8,
                                               ushort_t* __restrict__ vo, ushort_t* __restrict__ so) {
    int t = threadIdx.x;
    int lane = t & 63, wv = t >> 6;
    int ln = lane & 15, lq = lane >> 4;
    int rowbase = blockIdx.x * 64;

    const float* bsel = (wv == 0) ? bq_ : (wv == 1) ? bk_ : (wv == 2) ? bv_ : bs_;
    ushort_t* osel    = (wv == 0) ? qo : (wv == 2) ? vo : so;   // wv==1 uses kf8 path

    short8v wfrag[4][2];
#pragma unroll
    for (int ct = 0; ct < 4; ct++)
#pragma unroll
        for (int ks = 0; ks < 2; ks++)
            wfrag[ct][ks] = *(const short8v*)&wpl[((size_t)(wv * 8 + ct * 2 + ks)) * 512 + lane * 8];

    float4 bias[4];
#pragma unroll
    for (int ct = 0; ct < 4; ct++) bias[ct] = *(const float4*)&bsel[ct * 16 + lq * 4];

#pragma unroll
    for (int rt = 0; rt < 4; rt++) {
        int grow = rowbase + rt * 16 + ln;
        bool rv = grow < NN;
        int gr = rv ? grow : NN - 1;
        short8v h0 = *(const short8v*)&hbf[(size_t)gr * DD + lq * 8];
        short8v h1 = *(const short8v*)&hbf[(size_t)gr * DD + 32 + lq * 8];
#pragma unroll
        for (int ct = 0; ct < 4; ct++) {
            f32x4 acc;
            acc[0] = bias[ct].x; acc[1] = bias[ct].y; acc[2] = bias[ct].z; acc[3] = bias[ct].w;
            acc = __builtin_amdgcn_mfma_f32_16x16x32_bf16(wfrag[ct][0], h0, acc, 0, 0, 0);
            acc = __builtin_amdgcn_mfma_f32_16x16x32_bf16(wfrag[ct][1], h1, acc, 0, 0, 0);
            if (rv) {
                if (wv == 1) {
                    int pk8 = __builtin_amdgcn_cvt_pk_fp8_f32(acc[0], acc[1], 0, false);
                    pk8 = __builtin_amdgcn_cvt_pk_fp8_f32(acc[2], acc[3], pk8, true);
                    *(u32*)&kf8[(size_t)grow * 64 + ct * 16 + lq * 4] = (u32)pk8;
                } else {
                    uint2 pk;
                    pk.x = cvtpk(acc[0], acc[1]);
                    pk.y = cvtpk(acc[2], acc[3]);
                    *(uint2*)&osel[(size_t)grow * DD + ct * 16 + lq * 4] = pk;
                }
            }
        }
    }
}

// ---------------- single-pass online-softmax aggregate + skip + relu ----------------
// 4 nodes/wave; node = 2 groups of 8 lanes (sub=0/1); lane&7 holds dims 8j..8j+7.
// k gathered as fp8 (8B/lane), v bf16 (16B/lane). 1-deep prefetch clamped to the
// node's own last edge (cache-hot). log2-domain deferred-max softmax.

#define SCLOG2E 0.18033688011112042f  // 0.125 * log2(e)

#define PROC(KX, VX, ACT)                                              \
  {                                                                    \
    f32x2 dp2 = q01 * f8pair<false>(KX.x);                             \
    dp2 += q23 * f8pair<true>(KX.x);                                   \
    dp2 += q45 * f8pair<false>(KX.y);                                  \
    dp2 += q67 * f8pair<true>(KX.y);                                   \
    float dp = dp2.x + dp2.y;                                          \
    dp = sum8(dp);                                                     \
    float w = 0.f;                                                     \
    if (ACT) {                                                         \
      float sc = dp * SCLOG2E;                                         \
      if (sc <= m + 11.5f) { w = exp2f(sc - m); }                      \
      else { float cc = exp2f(m - sc);                                 \
             se *= cc; a01 *= cc; a23 *= cc; a45 *= cc; a67 *= cc;     \
             m = sc; w = 1.f; }                                        \
    }                                                                  \
    se += w;                                                           \
    a01 += bfpair(VX.x) * w;                                           \
    a23 += bfpair(VX.y) * w;                                           \
    a45 += bfpair(VX.z) * w;                                           \
    a67 += bfpair(VX.w) * w;                                           \
  }

__global__ __launch_bounds__(256) void agg_k(const ushort_t* __restrict__ qb,
                                             const uint2* __restrict__ kf8,
                                             const ushort_t* __restrict__ vb,
                                             const ushort_t* __restrict__ skb,
                                             const int* __restrict__ rowstart,
                                             const int* __restrict__ csr_src,
                                             ushort_t* __restrict__ hout) {
    int wv = threadIdx.x >> 6, lane = threadIdx.x & 63;
    int g = lane >> 3, j = lane & 7, sub = g & 1;
    int nid = blockIdx.x * 16 + wv * 4 + (g >> 1);
    if (nid >= NN) return;
    int r0 = rowstart[nid];
    int r1 = rowstart[nid + 1];

    u32x4 q8 = *rowp(qb, nid, j);
    f32x2 q01 = bfpair(q8.x), q23 = bfpair(q8.y), q45 = bfpair(q8.z), q67 = bfpair(q8.w);

    float m = -1.0e38f, se = 0.f;
    f32x2 a01 = {0.f, 0.f}, a23 = {0.f, 0.f}, a45 = {0.f, 0.f}, a67 = {0.f, 0.f};

    int clampE = r1 - 1; if (clampE < 0) clampE = 0;   // node's own last edge: cache-hot
    int e0 = r0 + sub;
    int s0 = csr_src[e0 < clampE ? e0 : clampE];
    uint2 k0 = kf8[(u32)s0 * 8 + j];
    u32x4 v0 = *rowp(vb, s0, j);

    while (__ballot(e0 < r1)) {
        int e1 = e0 + 2;
        int s1 = csr_src[e1 < clampE ? e1 : clampE];
        uint2 k1 = kf8[(u32)s1 * 8 + j];
        u32x4 v1 = *rowp(vb, s1, j);
        PROC(k0, v0, e0 < r1);
        e0 = e1; k0 = k1; v0 = v1;
    }

    // combine the node's two groups (xor8)
    float M = fmaxf(m, __shfl_xor(m, 8));
    float cc = exp2f(m - M);
    se *= cc; a01 *= cc; a23 *= cc; a45 *= cc; a67 *= cc;
    se += __shfl_xor(se, 8);
    a01.x += __shfl_xor(a01.x, 8); a01.y += __shfl_xor(a01.y, 8);
    a23.x += __shfl_xor(a23.x, 8); a23.y += __shfl_xor(a23.y, 8);
    a45.x += __shfl_xor(a45.x, 8); a45.y += __shfl_xor(a45.y, 8);
    a67.x += __shfl_xor(a67.x, 8); a67.y += __shfl_xor(a67.y, 8);

    if (sub == 0) {
        float inv = 1.0f / (se + 1e-16f);
        u32x4 sk = *rowp(skb, nid, j);
        f32x2 o01 = a01 * inv + bfpair(sk.x);
        f32x2 o23 = a23 * inv + bfpair(sk.y);
        f32x2 o45 = a45 * inv + bfpair(sk.z);
        f32x2 o67 = a67 * inv + bfpair(sk.w);
        u32x4 pk;
        pk.x = cvtpk(fmaxf(o01.x, 0.f), fmaxf(o01.y, 0.f));
        pk.y = cvtpk(fmaxf(o23.x, 0.f), fmaxf(o23.y, 0.f));
        pk.z = cvtpk(fmaxf(o45.x, 0.f), fmaxf(o45.y, 0.f));
        pk.w = cvtpk(fmaxf(o67.x, 0.f), fmaxf(o67.y, 0.f));
        *(u32x4*)(hout + (((u32)nid << 6) + ((u32)j << 3))) = pk;
    }
}

// ---------------- global add pool ----------------

#define POOL_ROWS 128

__global__ __launch_bounds__(256) void pool_k(const ushort_t* __restrict__ h,
                                              const int* __restrict__ batch,
                                              float* __restrict__ pooled) {
    int i0 = blockIdx.x * POOL_ROWS;
    int i1 = i0 + POOL_ROWS; if (i1 > NN) i1 = NN;
    int lane = threadIdx.x & 63;
    int wv = threadIdx.x >> 6;
    float acc = 0.f;
    int gcur = -1;
    for (int i = i0 + wv; i < i1; i += 4) {
        int gi = batch[i];
        if (gi != gcur) {
            if (gcur >= 0) atomicAdd(&pooled[gcur * DD + lane], acc);
            gcur = gi; acc = 0.f;
        }
        unsigned u = ((unsigned)h[(size_t)i * DD + lane]) << 16;
        acc += __builtin_bit_cast(float, u);
    }
    if (gcur >= 0) atomicAdd(&pooled[gcur * DD + lane], acc);
}

// ---------------- head ----------------

__global__ __launch_bounds__(64) void head_k(const float* __restrict__ pooled2,
                                             const float* __restrict__ W1,
                                             const float* __restrict__ b1,
                                             const float* __restrict__ W2,
                                             const float* __restrict__ b2,
                                             float* __restrict__ out) {
    int g = blockIdx.x;
    int c = threadIdx.x;
    __shared__ float pg[64], p[64];
    pg[c] = pooled2[g * DD + c];
    __syncthreads();
    float a = b1[c];
#pragma unroll 8
    for (int kk = 0; kk < 64; kk++) a += pg[kk] * W1[kk * DD + c];
    p[c] = fmaxf(a, 0.f);
    __syncthreads();
    if (c < 10) {
        float o = b2[c];
#pragma unroll 8
        for (int kk = 0; kk < 64; kk++) o += p[kk] * W2[kk * 10 + c];
        out[g * 10 + c] = o;
    }
}

// ---------------- launch ----------------

extern "C" void kernel_launch(void* const* d_in, const int* in_sizes, int n_in,
                              void* d_out, int out_size, void* d_ws, size_t ws_size,
                              hipStream_t stream) {
    const float* x    = (const float*)d_in[0];
    const int*   ei   = (const int*)d_in[1];
    const int*   batch= (const int*)d_in[2];
    const float* Wq   = (const float*)d_in[3];
    const float* bq   = (const float*)d_in[4];
    const float* Wk   = (const float*)d_in[5];
    const float* bk   = (const float*)d_in[6];
    const float* Wv   = (const float*)d_in[7];
    const float* bv   = (const float*)d_in[8];
    const float* Wsp  = (const float*)d_in[9];
    const float* bsp  = (const float*)d_in[10];
    const float* W1   = (const float*)d_in[11];
    const float* b1   = (const float*)d_in[12];
    const float* W2   = (const float*)d_in[13];
    const float* b2   = (const float*)d_in[14];
    float* out = (float*)d_out;
    float* pooled = out + NG * 10;

    const int* srcv = ei;
    const int* dstv = ei + NE;

    const size_t NEL = (size_t)NN * DD;
    ushort_t* hbf = (ushort_t*)d_ws;                 // [NN][64] bf16
    ushort_t* qb  = hbf + NEL;                       // bf16
    ushort_t* vb  = qb  + NEL;                       // bf16
    ushort_t* skb = vb  + NEL;                       // bf16
    unsigned char* kf8 = (unsigned char*)(skb + NEL); // [NN][64] fp8
    u32* binbuf   = (u32*)(kf8 + (size_t)NN * 64);   // [NBUK*BCAP]
    int* gcur     = (int*)(binbuf + (size_t)NBUK * BCAP);  // [NBUK]
    int* rowstart = gcur + NBUK;                     // [NN+1]
    int* csr_src  = rowstart + (NN + 1);             // [NE]
    ushort_t* wpack = (ushort_t*)(csr_src + NE);     // 12*4096 bf16

    int totOut = NG * 10 + NL * NG * DD;
    int cvtBlocks = (int)(NEL / 4 / 256);            // 6250 (exact)
    int zeroBlocks = (totOut + 255) / 256;           // 102

    setup_k<<<cvtBlocks + zeroBlocks + NL * 4, 256, 0, stream>>>(
        x, hbf, out, totOut, gcur, Wq, Wk, Wv, Wsp, wpack, cvtBlocks, zeroBlocks);

    bin_k<<<NBLK, 256, 0, stream>>>(srcv, dstv, binbuf, gcur);
    csr_k<<<NBUK, 256, 0, stream>>>(binbuf, gcur, rowstart, csr_src);

    int gtiles = (NN + 63) / 64;
    int poolblocks = (NN + POOL_ROWS - 1) / POOL_ROWS;
    for (int l = 0; l < NL; l++) {
        gemm4_k<<<gtiles, 256, 0, stream>>>(hbf, wpack + (size_t)l * 4 * 8 * 512,
                                            bq + l * DD, bk + l * DD, bv + l * DD, bsp + l * DD,
                                            qb, kf8, vb, skb);
        agg_k<<<(NN + 15) / 16, 256, 0, stream>>>(qb, (const uint2*)kf8, vb, skb,
                                                  rowstart, csr_src, hbf);
        pool_k<<<poolblocks, 256, 0, stream>>>(hbf, batch, pooled + l * NG * DD);
    }
    head_k<<<NG, 64, 0, stream>>>(pooled + 2 * NG * DD, W1, b1, W2, b2, out);
}

// Round 10
// 268.090 us; speedup vs baseline: 1.2640x; 1.0431x over previous
//
#include <hip/hip_runtime.h>
#include <hip/hip_bf16.h>
#include <math.h>

#define NN 100000
#define NE 1000000
#define DD 64
#define NG 128
#define NL 3

#define NBUK 196          // dst >> 9 buckets (512 nodes each)
#define EPB 2048          // edges per bin block
#define NBLK ((NE + EPB - 1) / EPB)   // 489
#define BCAP 6144         // per-bucket capacity (mean 5120, ~14 sigma margin)

typedef unsigned short ushort_t;
typedef unsigned int u32;
typedef __attribute__((ext_vector_type(8))) short short8v;
typedef __attribute__((ext_vector_type(2))) float f32x2;
typedef __attribute__((ext_vector_type(4))) float f32x4;
typedef __attribute__((ext_vector_type(4))) unsigned int u32x4;

__device__ __forceinline__ ushort_t f2bf(float f) {
    __hip_bfloat16 h = __float2bfloat16(f);
    return *reinterpret_cast<ushort_t*>(&h);
}
__device__ __forceinline__ unsigned cvtpk(float lo, float hi) {
    unsigned r;
    asm("v_cvt_pk_bf16_f32 %0, %1, %2" : "=v"(r) : "v"(lo), "v"(hi));
    return r;
}
// unpack 2 bf16 (packed in u32) -> f32x2
__device__ __forceinline__ f32x2 bfpair(u32 u) {
    f32x2 r;
    r.x = __builtin_bit_cast(float, u << 16);
    r.y = __builtin_bit_cast(float, u & 0xffff0000u);
    return r;
}
// unpack 2 fp8 e4m3 (word half HI of u) -> f32x2 (HW convert; HI must be ICE)
template <bool HI>
__device__ __forceinline__ f32x2 f8pair(u32 u) {
    return __builtin_amdgcn_cvt_pk_f32_fp8(u, HI);
}
// sum over each 8-lane group: xor1, xor2 quad_perm + row_half_mirror (all VALU DPP)
__device__ __forceinline__ float sum8(float x) {
    int v = __builtin_bit_cast(int, x);
    x += __builtin_bit_cast(float, __builtin_amdgcn_update_dpp(0, v, 0xB1, 0xF, 0xF, true));
    v = __builtin_bit_cast(int, x);
    x += __builtin_bit_cast(float, __builtin_amdgcn_update_dpp(0, v, 0x4E, 0xF, 0xF, true));
    v = __builtin_bit_cast(int, x);
    x += __builtin_bit_cast(float, __builtin_amdgcn_update_dpp(0, v, 0x141, 0xF, 0xF, true));
    return x;
}

// ---------------- fused setup: cvt + zero + packw ----------------

__global__ __launch_bounds__(256) void setup_k(const float* __restrict__ x, ushort_t* __restrict__ hbf,
                                               float* __restrict__ out, int totOut,
                                               int* __restrict__ gcur,
                                               const float* __restrict__ Wq, const float* __restrict__ Wk,
                                               const float* __restrict__ Wv, const float* __restrict__ Ws_,
                                               ushort_t* __restrict__ wpack,
                                               int cvtBlocks, int zeroBlocks) {
    int b = blockIdx.x, t = threadIdx.x;
    if (b < cvtBlocks) {        // bf16 convert of x (NEL divisible by 1024)
        int base = (b * 256 + t) * 4;
        float4 v = *(const float4*)&x[base];
        uint2 pk;
        pk.x = cvtpk(v.x, v.y);
        pk.y = cvtpk(v.z, v.w);
        *(uint2*)&hbf[base] = pk;
        return;
    }
    b -= cvtBlocks;
    if (b < zeroBlocks) {       // zero d_out (pooled accumulators) + gcur
        int i = b * 256 + t;
        if (i < totOut) out[i] = 0.f;
        if (b == 0 && t < NBUK) gcur[t] = 0;
        return;
    }
    b -= zeroBlocks;            // packw: b in [0, NL*4)
    if (t < 64) {
        int mat = b & 3, layer = b >> 2;
        const float* W = ((mat == 0) ? Wq : (mat == 1) ? Wk : (mat == 2) ? Wv : Ws_) + layer * DD * DD;
        int lq = t >> 4, ln = t & 15;
#pragma unroll
        for (int ct = 0; ct < 4; ct++)
#pragma unroll
            for (int ks = 0; ks < 2; ks++)
#pragma unroll
                for (int j = 0; j < 8; j++) {
                    float v = W[(ks * 32 + lq * 8 + j) * DD + ct * 16 + ln];
                    wpack[((size_t)(b * 8 + ct * 2 + ks)) * 512 + t * 8 + j] = f2bf(v);
                }
    }
}

// ---------------- CSR build: bucket-major direct placement ----------------
// pack = (dst&511)<<17 | src   (src < 2^17)

__global__ __launch_bounds__(256) void bin_k(const int* __restrict__ src,
                                             const int* __restrict__ dst,
                                             u32* __restrict__ binbuf,
                                             int* __restrict__ gcur) {
    __shared__ int hist[NBUK];
    __shared__ int excl[NBUK];
    __shared__ int cur[NBUK];
    __shared__ int gbase[NBUK];
    __shared__ int tmp[256];
    __shared__ u32 pairs[EPB];
    __shared__ unsigned char bukid[EPB];
    int t = threadIdx.x;
    int blk = blockIdx.x;
    int e0 = blk * EPB;
    int totvalid = NE - e0; if (totvalid > EPB) totvalid = EPB;

    for (int i = t; i < NBUK; i += 256) hist[i] = 0;
    __syncthreads();

    int mysrc[8], mydst[8];
#pragma unroll
    for (int i = 0; i < 8; i++) {
        int e = e0 + i * 256 + t;
        bool v = e < NE;
        mysrc[i] = v ? src[e] : -1;
        mydst[i] = v ? dst[e] : -1;
        if (v) atomicAdd(&hist[mydst[i] >> 9], 1);
    }
    __syncthreads();

    int v = (t < NBUK) ? hist[t] : 0;
    tmp[t] = v;
    __syncthreads();
#pragma unroll
    for (int off = 1; off < 256; off <<= 1) {
        int a = (t >= off) ? tmp[t - off] : 0;
        __syncthreads();
        tmp[t] += a;
        __syncthreads();
    }
    if (t < NBUK) { excl[t] = tmp[t] - v; cur[t] = tmp[t] - v; }
    __syncthreads();

#pragma unroll
    for (int i = 0; i < 8; i++) {
        if (mydst[i] >= 0) {
            int b = mydst[i] >> 9;
            int p = atomicAdd(&cur[b], 1);
            pairs[p] = ((u32)(mydst[i] & 511) << 17) | (u32)mysrc[i];
            bukid[p] = (unsigned char)b;
        }
    }
    if (t < NBUK && v > 0) gbase[t] = atomicAdd(&gcur[t], v);
    __syncthreads();

    for (int i = t; i < totvalid; i += 256) {
        int b = bukid[i];
        int idx = gbase[b] + (i - excl[b]);
        if (idx < BCAP) binbuf[(size_t)b * BCAP + idx] = pairs[i];
    }
}

__global__ __launch_bounds__(256) void csr_k(const u32* __restrict__ binbuf,
                                             const int* __restrict__ gcur,
                                             int* __restrict__ rowstart,
                                             int* __restrict__ csr_src) {
    __shared__ u32 pairs[BCAP];
    __shared__ int csrb[BCAP];
    __shared__ int deg[512];
    __shared__ int excl[512];
    __shared__ int cur[512];
    __shared__ int tmp[512];
    __shared__ int bt[256];
    int b = blockIdx.x;
    int t = threadIdx.x;

    // in-block scan of bucket totals -> base for this bucket
    int bv = 0;
    if (t < NBUK) { bv = gcur[t]; if (bv > BCAP) bv = BCAP; }
    bt[t] = bv;
    __syncthreads();
#pragma unroll
    for (int off = 1; off < 256; off <<= 1) {
        int a = (t >= off) ? bt[t - off] : 0;
        __syncthreads();
        bt[t] += a;
        __syncthreads();
    }
    int base = (b == 0) ? 0 : bt[b - 1];
    int T = bt[b] - base;
    if (b == 0 && t == 0) rowstart[NN] = bt[NBUK - 1];
    int nbase = b << 9;

    for (int i = t; i < 512; i += 256) deg[i] = 0;
    for (int i = t; i < T; i += 256) pairs[i] = binbuf[(size_t)b * BCAP + i];
    __syncthreads();
    for (int i = t; i < T; i += 256) atomicAdd(&deg[pairs[i] >> 17], 1);
    __syncthreads();

    int v0 = deg[t], v1 = deg[t + 256];
    tmp[t] = v0; tmp[t + 256] = v1;
    __syncthreads();
#pragma unroll
    for (int off = 1; off < 512; off <<= 1) {
        int a0 = (t >= off) ? tmp[t - off] : 0;
        int i1 = t + 256;
        int a1 = (i1 >= off) ? tmp[i1 - off] : 0;
        __syncthreads();
        tmp[t] += a0; tmp[i1] += a1;
        __syncthreads();
    }
    excl[t] = tmp[t] - v0; excl[t + 256] = tmp[t + 256] - v1;
    cur[t] = excl[t]; cur[t + 256] = excl[t + 256];
    __syncthreads();

    for (int i = t; i < 512; i += 256) {
        int n = nbase + i;
        if (n < NN) rowstart[n] = base + excl[i];
    }

    for (int i = t; i < T; i += 256) {
        u32 p = pairs[i];
        int pos = atomicAdd(&cur[p >> 17], 1);
        csrb[pos] = (int)(p & 0x1FFFFu);
    }
    __syncthreads();
    for (int i = t; i < T; i += 256) csr_src[base + i] = csrb[i];
}

// ---------------- fused 4-matrix MFMA GEMM, swapped operands ----------------
// k-wave (wv==1) and v-wave (wv==2) emit fp8 e4m3 into one [NN][128B] kv row
// (k = bytes 0..63, v = bytes 64..127); q/skip emit bf16.

__global__ __launch_bounds__(256) void gemm4_k(const ushort_t* __restrict__ hbf,
                                               const ushort_t* __restrict__ wpl,
                                               const float* __restrict__ bq_, const float* __restrict__ bk_,
                                               const float* __restrict__ bv_, const float* __restrict__ bs_,
                                               ushort_t* __restrict__ qo, unsigned char* __restrict__ kv8,
                                               ushort_t* __restrict__ so) {
    int t = threadIdx.x;
    int lane = t & 63, wv = t >> 6;
    int ln = lane & 15, lq = lane >> 4;
    int rowbase = blockIdx.x * 64;

    const float* bsel = (wv == 0) ? bq_ : (wv == 1) ? bk_ : (wv == 2) ? bv_ : bs_;
    ushort_t* osel    = (wv == 0) ? qo : so;   // wv 1/2 use kv8 path
    int kvoff = (wv == 1) ? 0 : 64;

    short8v wfrag[4][2];
#pragma unroll
    for (int ct = 0; ct < 4; ct++)
#pragma unroll
        for (int ks = 0; ks < 2; ks++)
            wfrag[ct][ks] = *(const short8v*)&wpl[((size_t)(wv * 8 + ct * 2 + ks)) * 512 + lane * 8];

    float4 bias[4];
#pragma unroll
    for (int ct = 0; ct < 4; ct++) bias[ct] = *(const float4*)&bsel[ct * 16 + lq * 4];

#pragma unroll
    for (int rt = 0; rt < 4; rt++) {
        int grow = rowbase + rt * 16 + ln;
        bool rv = grow < NN;
        int gr = rv ? grow : NN - 1;
        short8v h0 = *(const short8v*)&hbf[(size_t)gr * DD + lq * 8];
        short8v h1 = *(const short8v*)&hbf[(size_t)gr * DD + 32 + lq * 8];
#pragma unroll
        for (int ct = 0; ct < 4; ct++) {
            f32x4 acc;
            acc[0] = bias[ct].x; acc[1] = bias[ct].y; acc[2] = bias[ct].z; acc[3] = bias[ct].w;
            acc = __builtin_amdgcn_mfma_f32_16x16x32_bf16(wfrag[ct][0], h0, acc, 0, 0, 0);
            acc = __builtin_amdgcn_mfma_f32_16x16x32_bf16(wfrag[ct][1], h1, acc, 0, 0, 0);
            if (rv) {
                if (wv == 1 || wv == 2) {
                    int pk8 = __builtin_amdgcn_cvt_pk_fp8_f32(acc[0], acc[1], 0, false);
                    pk8 = __builtin_amdgcn_cvt_pk_fp8_f32(acc[2], acc[3], pk8, true);
                    *(u32*)&kv8[(size_t)grow * 128 + kvoff + ct * 16 + lq * 4] = (u32)pk8;
                } else {
                    uint2 pk;
                    pk.x = cvtpk(acc[0], acc[1]);
                    pk.y = cvtpk(acc[2], acc[3]);
                    *(uint2*)&osel[(size_t)grow * DD + ct * 16 + lq * 4] = pk;
                }
            }
        }
    }
}

// ---------------- single-pass online-softmax aggregate + skip + relu ----------------
// 4 nodes/wave; node = 2 groups of 8 lanes (sub); ONE 128B kv line per edge:
// lane j loads kv bytes [16j..16j+16). Lanes 0-3 hold k (dot phase), lanes 4-7
// hold v (accumulate phase). blk[] registers alias q (lanes<4) / v-acc (lanes>=4).

#define SCLOG2E 0.18033688011112042f  // 0.125 * log2(e)

__global__ __launch_bounds__(256) void agg_k(const ushort_t* __restrict__ qb,
                                             const u32x4* __restrict__ kv8,
                                             const ushort_t* __restrict__ skb,
                                             const int* __restrict__ rowstart,
                                             const int* __restrict__ csr_src,
                                             ushort_t* __restrict__ hout) {
    int wv = threadIdx.x >> 6, lane = threadIdx.x & 63;
    int g = lane >> 3, j = lane & 7, sub = g & 1;
    int nid = blockIdx.x * 16 + wv * 4 + (g >> 1);
    if (nid >= NN) return;
    int r0 = rowstart[nid];
    int r1 = rowstart[nid + 1];

    // blk: lanes j<4 = q dims [16j..16j+16) (8 bf16-pairs); lanes j>=4 = v accumulator
    f32x2 blk[8];
    {
        const u32x4* qp = (const u32x4*)(qb + ((u32)nid << 6) + ((u32)(j & 3) << 4));
        u32x4 qa = qp[0], qc = qp[1];
        f32x2 z = {0.f, 0.f};
        bool isq = j < 4;
        blk[0] = isq ? bfpair(qa.x) : z;  blk[1] = isq ? bfpair(qa.y) : z;
        blk[2] = isq ? bfpair(qa.z) : z;  blk[3] = isq ? bfpair(qa.w) : z;
        blk[4] = isq ? bfpair(qc.x) : z;  blk[5] = isq ? bfpair(qc.y) : z;
        blk[6] = isq ? bfpair(qc.z) : z;  blk[7] = isq ? bfpair(qc.w) : z;
    }

    float m = -1.0e38f, se = 0.f;
    int clampE = r1 - 1; if (clampE < 0) clampE = 0;   // node's own last edge: cache-hot
    int e0 = r0 + sub;
    int s0 = csr_src[e0 < clampE ? e0 : clampE];
    u32x4 kv0 = kv8[(u32)s0 * 8 + j];

    while (__ballot(e0 < r1)) {
        int e1 = e0 + 2;
        int s1 = csr_src[e1 < clampE ? e1 : clampE];
        u32x4 kv1 = kv8[(u32)s1 * 8 + j];

        f32x2 dp2 = {0.f, 0.f};
        if (j < 4) {   // k half of the line
            dp2  = blk[0] * f8pair<false>(kv0.x);
            dp2 += blk[1] * f8pair<true >(kv0.x);
            dp2 += blk[2] * f8pair<false>(kv0.y);
            dp2 += blk[3] * f8pair<true >(kv0.y);
            dp2 += blk[4] * f8pair<false>(kv0.z);
            dp2 += blk[5] * f8pair<true >(kv0.z);
            dp2 += blk[6] * f8pair<false>(kv0.w);
            dp2 += blk[7] * f8pair<true >(kv0.w);
        }
        float dp = sum8(dp2.x + dp2.y);

        float w = 0.f;
        if (e0 < r1) {
            float sc = dp * SCLOG2E;
            if (sc <= m + 11.5f) { w = exp2f(sc - m); }
            else {
                float cc = exp2f(m - sc);
                se *= cc;
                if (j >= 4) {
#pragma unroll
                    for (int p = 0; p < 8; p++) blk[p] *= cc;
                }
                m = sc; w = 1.f;
            }
        }
        se += w;
        if (j >= 4) {  // v half of the line
            blk[0] += f8pair<false>(kv0.x) * w;
            blk[1] += f8pair<true >(kv0.x) * w;
            blk[2] += f8pair<false>(kv0.y) * w;
            blk[3] += f8pair<true >(kv0.y) * w;
            blk[4] += f8pair<false>(kv0.z) * w;
            blk[5] += f8pair<true >(kv0.z) * w;
            blk[6] += f8pair<false>(kv0.w) * w;
            blk[7] += f8pair<true >(kv0.w) * w;
        }
        e0 = e1; kv0 = kv1;
    }

    // combine the node's two groups (xor8); q in blk is dead now, scale freely
    float M = fmaxf(m, __shfl_xor(m, 8));
    float cc = exp2f(m - M);
    se *= cc;
    se += __shfl_xor(se, 8);
#pragma unroll
    for (int p = 0; p < 8; p++) {
        blk[p] *= cc;
        blk[p].x += __shfl_xor(blk[p].x, 8);
        blk[p].y += __shfl_xor(blk[p].y, 8);
    }

    if (sub == 0 && j >= 4) {
        float inv = 1.0f / (se + 1e-16f);
        int d0 = j - 4;  // 16-dim slice index
        const u32x4* sp = (const u32x4*)(skb + ((u32)nid << 6) + ((u32)d0 << 4));
        u32x4 s0v = sp[0], s1v = sp[1];
        f32x2 o0 = blk[0] * inv + bfpair(s0v.x);
        f32x2 o1 = blk[1] * inv + bfpair(s0v.y);
        f32x2 o2 = blk[2] * inv + bfpair(s0v.z);
        f32x2 o3 = blk[3] * inv + bfpair(s0v.w);
        f32x2 o4 = blk[4] * inv + bfpair(s1v.x);
        f32x2 o5 = blk[5] * inv + bfpair(s1v.y);
        f32x2 o6 = blk[6] * inv + bfpair(s1v.z);
        f32x2 o7 = blk[7] * inv + bfpair(s1v.w);
        u32x4 pkA, pkB;
        pkA.x = cvtpk(fmaxf(o0.x, 0.f), fmaxf(o0.y, 0.f));
        pkA.y = cvtpk(fmaxf(o1.x, 0.f), fmaxf(o1.y, 0.f));
        pkA.z = cvtpk(fmaxf(o2.x, 0.f), fmaxf(o2.y, 0.f));
        pkA.w = cvtpk(fmaxf(o3.x, 0.f), fmaxf(o3.y, 0.f));
        pkB.x = cvtpk(fmaxf(o4.x, 0.f), fmaxf(o4.y, 0.f));
        pkB.y = cvtpk(fmaxf(o5.x, 0.f), fmaxf(o5.y, 0.f));
        pkB.z = cvtpk(fmaxf(o6.x, 0.f), fmaxf(o6.y, 0.f));
        pkB.w = cvtpk(fmaxf(o7.x, 0.f), fmaxf(o7.y, 0.f));
        u32x4* op = (u32x4*)(hout + ((u32)nid << 6) + ((u32)d0 << 4));
        op[0] = pkA;
        op[1] = pkB;
    }
}

// ---------------- global add pool ----------------

#define POOL_ROWS 128

__global__ __launch_bounds__(256) void pool_k(const ushort_t* __restrict__ h,
                                              const int* __restrict__ batch,
                                              float* __restrict__ pooled) {
    int i0 = blockIdx.x * POOL_ROWS;
    int i1 = i0 + POOL_ROWS; if (i1 > NN) i1 = NN;
    int lane = threadIdx.x & 63;
    int wv = threadIdx.x >> 6;
    float acc = 0.f;
    int gcur = -1;
    for (int i = i0 + wv; i < i1; i += 4) {
        int gi = batch[i];
        if (gi != gcur) {
            if (gcur >= 0) atomicAdd(&pooled[gcur * DD + lane], acc);
            gcur = gi; acc = 0.f;
        }
        unsigned u = ((unsigned)h[(size_t)i * DD + lane]) << 16;
        acc += __builtin_bit_cast(float, u);
    }
    if (gcur >= 0) atomicAdd(&pooled[gcur * DD + lane], acc);
}

// ---------------- head ----------------

__global__ __launch_bounds__(64) void head_k(const float* __restrict__ pooled2,
                                             const float* __restrict__ W1,
                                             const float* __restrict__ b1,
                                             const float* __restrict__ W2,
                                             const float* __restrict__ b2,
                                             float* __restrict__ out) {
    int g = blockIdx.x;
    int c = threadIdx.x;
    __shared__ float pg[64], p[64];
    pg[c] = pooled2[g * DD + c];
    __syncthreads();
    float a = b1[c];
#pragma unroll 8
    for (int kk = 0; kk < 64; kk++) a += pg[kk] * W1[kk * DD + c];
    p[c] = fmaxf(a, 0.f);
    __syncthreads();
    if (c < 10) {
        float o = b2[c];
#pragma unroll 8
        for (int kk = 0; kk < 64; kk++) o += p[kk] * W2[kk * 10 + c];
        out[g * 10 + c] = o;
    }
}

// ---------------- launch ----------------

extern "C" void kernel_launch(void* const* d_in, const int* in_sizes, int n_in,
                              void* d_out, int out_size, void* d_ws, size_t ws_size,
                              hipStream_t stream) {
    const float* x    = (const float*)d_in[0];
    const int*   ei   = (const int*)d_in[1];
    const int*   batch= (const int*)d_in[2];
    const float* Wq   = (const float*)d_in[3];
    const float* bq   = (const float*)d_in[4];
    const float* Wk   = (const float*)d_in[5];
    const float* bk   = (const float*)d_in[6];
    const float* Wv   = (const float*)d_in[7];
    const float* bv   = (const float*)d_in[8];
    const float* Wsp  = (const float*)d_in[9];
    const float* bsp  = (const float*)d_in[10];
    const float* W1   = (const float*)d_in[11];
    const float* b1   = (const float*)d_in[12];
    const float* W2   = (const float*)d_in[13];
    const float* b2   = (const float*)d_in[14];
    float* out = (float*)d_out;
    float* pooled = out + NG * 10;

    const int* srcv = ei;
    const int* dstv = ei + NE;

    const size_t NEL = (size_t)NN * DD;
    ushort_t* hbf = (ushort_t*)d_ws;                 // [NN][64] bf16
    ushort_t* qb  = hbf + NEL;                       // bf16
    ushort_t* skb = qb  + NEL;                       // bf16
    unsigned char* kv8 = (unsigned char*)(skb + NEL); // [NN][128] fp8 k|v
    u32* binbuf   = (u32*)(kv8 + (size_t)NN * 128);  // [NBUK*BCAP]
    int* gcur     = (int*)(binbuf + (size_t)NBUK * BCAP);  // [NBUK]
    int* rowstart = gcur + NBUK;                     // [NN+1]
    int* csr_src  = rowstart + (NN + 1);             // [NE]
    ushort_t* wpack = (ushort_t*)(csr_src + NE);     // 12*4096 bf16

    int totOut = NG * 10 + NL * NG * DD;
    int cvtBlocks = (int)(NEL / 4 / 256);            // 6250 (exact)
    int zeroBlocks = (totOut + 255) / 256;           // 102

    setup_k<<<cvtBlocks + zeroBlocks + NL * 4, 256, 0, stream>>>(
        x, hbf, out, totOut, gcur, Wq, Wk, Wv, Wsp, wpack, cvtBlocks, zeroBlocks);

    bin_k<<<NBLK, 256, 0, stream>>>(srcv, dstv, binbuf, gcur);
    csr_k<<<NBUK, 256, 0, stream>>>(binbuf, gcur, rowstart, csr_src);

    int gtiles = (NN + 63) / 64;
    int poolblocks = (NN + POOL_ROWS - 1) / POOL_ROWS;
    for (int l = 0; l < NL; l++) {
        gemm4_k<<<gtiles, 256, 0, stream>>>(hbf, wpack + (size_t)l * 4 * 8 * 512,
                                            bq + l * DD, bk + l * DD, bv + l * DD, bsp + l * DD,
                                            qb, kv8, skb);
        agg_k<<<(NN + 15) / 16, 256, 0, stream>>>(qb, (const u32x4*)kv8, skb,
                                                  rowstart, csr_src, hbf);
        pool_k<<<poolblocks, 256, 0, stream>>>(hbf, batch, pooled + l * NG * DD);
    }
    head_k<<<NG, 64, 0, stream>>>(pooled + 2 * NG * DD, W1, b1, W2, b2, out);
}

// Round 11
// 255.676 us; speedup vs baseline: 1.3254x; 1.0486x over previous
//
#include <hip/hip_runtime.h>
#include <hip/hip_bf16.h>
#include <math.h>

#define NN 100000
#define NE 1000000
#define DD 64
#define NG 128
#define NL 3

#define NBUK 196          // dst >> 9 buckets (512 nodes each)
#define EPB 2048          // edges per bin block
#define NBLK ((NE + EPB - 1) / EPB)   // 489
#define BCAP 6144         // per-bucket capacity (mean 5120, ~14 sigma margin)
#define NDC 64            // degree classes for node sort

typedef unsigned short ushort_t;
typedef unsigned int u32;
typedef __attribute__((ext_vector_type(8))) short short8v;
typedef __attribute__((ext_vector_type(2))) float f32x2;
typedef __attribute__((ext_vector_type(4))) float f32x4;
typedef __attribute__((ext_vector_type(4))) unsigned int u32x4;

__device__ __forceinline__ ushort_t f2bf(float f) {
    __hip_bfloat16 h = __float2bfloat16(f);
    return *reinterpret_cast<ushort_t*>(&h);
}
__device__ __forceinline__ unsigned cvtpk(float lo, float hi) {
    unsigned r;
    asm("v_cvt_pk_bf16_f32 %0, %1, %2" : "=v"(r) : "v"(lo), "v"(hi));
    return r;
}
// unpack 2 bf16 (packed in u32) -> f32x2
__device__ __forceinline__ f32x2 bfpair(u32 u) {
    f32x2 r;
    r.x = __builtin_bit_cast(float, u << 16);
    r.y = __builtin_bit_cast(float, u & 0xffff0000u);
    return r;
}
// unpack 2 fp8 e4m3 (word half HI of u) -> f32x2 (HW convert; HI must be ICE)
template <bool HI>
__device__ __forceinline__ f32x2 f8pair(u32 u) {
    return __builtin_amdgcn_cvt_pk_f32_fp8(u, HI);
}
// sum over each 8-lane group: xor1, xor2 quad_perm + row_half_mirror (all VALU DPP)
__device__ __forceinline__ float sum8(float x) {
    int v = __builtin_bit_cast(int, x);
    x += __builtin_bit_cast(float, __builtin_amdgcn_update_dpp(0, v, 0xB1, 0xF, 0xF, true));
    v = __builtin_bit_cast(int, x);
    x += __builtin_bit_cast(float, __builtin_amdgcn_update_dpp(0, v, 0x4E, 0xF, 0xF, true));
    v = __builtin_bit_cast(int, x);
    x += __builtin_bit_cast(float, __builtin_amdgcn_update_dpp(0, v, 0x141, 0xF, 0xF, true));
    return x;
}

// ---------------- fused setup: cvt + zero + packw ----------------

__global__ __launch_bounds__(256) void setup_k(const float* __restrict__ x, ushort_t* __restrict__ hbf,
                                               float* __restrict__ out, int totOut,
                                               int* __restrict__ gcur, int* __restrict__ gdh,
                                               const float* __restrict__ Wq, const float* __restrict__ Wk,
                                               const float* __restrict__ Wv, const float* __restrict__ Ws_,
                                               ushort_t* __restrict__ wpack,
                                               int cvtBlocks, int zeroBlocks) {
    int b = blockIdx.x, t = threadIdx.x;
    if (b < cvtBlocks) {        // bf16 convert of x (NEL divisible by 1024)
        int base = (b * 256 + t) * 4;
        float4 v = *(const float4*)&x[base];
        uint2 pk;
        pk.x = cvtpk(v.x, v.y);
        pk.y = cvtpk(v.z, v.w);
        *(uint2*)&hbf[base] = pk;
        return;
    }
    b -= cvtBlocks;
    if (b < zeroBlocks) {       // zero d_out + gcur + degree hist
        int i = b * 256 + t;
        if (i < totOut) out[i] = 0.f;
        if (b == 0 && t < NBUK) gcur[t] = 0;
        if (b == 1 && t < NDC) gdh[t] = 0;
        return;
    }
    b -= zeroBlocks;            // packw: b in [0, NL*4)
    if (t < 64) {
        int mat = b & 3, layer = b >> 2;
        const float* W = ((mat == 0) ? Wq : (mat == 1) ? Wk : (mat == 2) ? Wv : Ws_) + layer * DD * DD;
        int lq = t >> 4, ln = t & 15;
#pragma unroll
        for (int ct = 0; ct < 4; ct++)
#pragma unroll
            for (int ks = 0; ks < 2; ks++)
#pragma unroll
                for (int j = 0; j < 8; j++) {
                    float v = W[(ks * 32 + lq * 8 + j) * DD + ct * 16 + ln];
                    wpack[((size_t)(b * 8 + ct * 2 + ks)) * 512 + t * 8 + j] = f2bf(v);
                }
    }
}

// ---------------- CSR build: bucket-major direct placement ----------------
// pack = (dst&511)<<17 | src   (src < 2^17)

__global__ __launch_bounds__(256) void bin_k(const int* __restrict__ src,
                                             const int* __restrict__ dst,
                                             u32* __restrict__ binbuf,
                                             int* __restrict__ gcur) {
    __shared__ int hist[NBUK];
    __shared__ int excl[NBUK];
    __shared__ int cur[NBUK];
    __shared__ int gbase[NBUK];
    __shared__ int tmp[256];
    __shared__ u32 pairs[EPB];
    __shared__ unsigned char bukid[EPB];
    int t = threadIdx.x;
    int blk = blockIdx.x;
    int e0 = blk * EPB;
    int totvalid = NE - e0; if (totvalid > EPB) totvalid = EPB;

    for (int i = t; i < NBUK; i += 256) hist[i] = 0;
    __syncthreads();

    int mysrc[8], mydst[8];
#pragma unroll
    for (int i = 0; i < 8; i++) {
        int e = e0 + i * 256 + t;
        bool v = e < NE;
        mysrc[i] = v ? src[e] : -1;
        mydst[i] = v ? dst[e] : -1;
        if (v) atomicAdd(&hist[mydst[i] >> 9], 1);
    }
    __syncthreads();

    int v = (t < NBUK) ? hist[t] : 0;
    tmp[t] = v;
    __syncthreads();
#pragma unroll
    for (int off = 1; off < 256; off <<= 1) {
        int a = (t >= off) ? tmp[t - off] : 0;
        __syncthreads();
        tmp[t] += a;
        __syncthreads();
    }
    if (t < NBUK) { excl[t] = tmp[t] - v; cur[t] = tmp[t] - v; }
    __syncthreads();

#pragma unroll
    for (int i = 0; i < 8; i++) {
        if (mydst[i] >= 0) {
            int b = mydst[i] >> 9;
            int p = atomicAdd(&cur[b], 1);
            pairs[p] = ((u32)(mydst[i] & 511) << 17) | (u32)mysrc[i];
            bukid[p] = (unsigned char)b;
        }
    }
    if (t < NBUK && v > 0) gbase[t] = atomicAdd(&gcur[t], v);
    __syncthreads();

    for (int i = t; i < totvalid; i += 256) {
        int b = bukid[i];
        int idx = gbase[b] + (i - excl[b]);
        if (idx < BCAP) binbuf[(size_t)b * BCAP + idx] = pairs[i];
    }
}

__global__ __launch_bounds__(256) void csr_k(const u32* __restrict__ binbuf,
                                             const int* __restrict__ gcur,
                                             int* __restrict__ rowstart,
                                             int* __restrict__ csr_src) {
    __shared__ u32 pairs[BCAP];
    __shared__ int csrb[BCAP];
    __shared__ int deg[512];
    __shared__ int excl[512];
    __shared__ int cur[512];
    __shared__ int tmp[512];
    __shared__ int bt[256];
    int b = blockIdx.x;
    int t = threadIdx.x;

    // in-block scan of bucket totals -> base for this bucket
    int bv = 0;
    if (t < NBUK) { bv = gcur[t]; if (bv > BCAP) bv = BCAP; }
    bt[t] = bv;
    __syncthreads();
#pragma unroll
    for (int off = 1; off < 256; off <<= 1) {
        int a = (t >= off) ? bt[t - off] : 0;
        __syncthreads();
        bt[t] += a;
        __syncthreads();
    }
    int base = (b == 0) ? 0 : bt[b - 1];
    int T = bt[b] - base;
    if (b == 0 && t == 0) rowstart[NN] = bt[NBUK - 1];
    int nbase = b << 9;

    for (int i = t; i < 512; i += 256) deg[i] = 0;
    for (int i = t; i < T; i += 256) pairs[i] = binbuf[(size_t)b * BCAP + i];
    __syncthreads();
    for (int i = t; i < T; i += 256) atomicAdd(&deg[pairs[i] >> 17], 1);
    __syncthreads();

    int v0 = deg[t], v1 = deg[t + 256];
    tmp[t] = v0; tmp[t + 256] = v1;
    __syncthreads();
#pragma unroll
    for (int off = 1; off < 512; off <<= 1) {
        int a0 = (t >= off) ? tmp[t - off] : 0;
        int i1 = t + 256;
        int a1 = (i1 >= off) ? tmp[i1 - off] : 0;
        __syncthreads();
        tmp[t] += a0; tmp[i1] += a1;
        __syncthreads();
    }
    excl[t] = tmp[t] - v0; excl[t + 256] = tmp[t + 256] - v1;
    cur[t] = excl[t]; cur[t + 256] = excl[t + 256];
    __syncthreads();

    for (int i = t; i < 512; i += 256) {
        int n = nbase + i;
        if (n < NN) rowstart[n] = base + excl[i];
    }

    for (int i = t; i < T; i += 256) {
        u32 p = pairs[i];
        int pos = atomicAdd(&cur[p >> 17], 1);
        csrb[pos] = (int)(p & 0x1FFFFu);
    }
    __syncthreads();
    for (int i = t; i < T; i += 256) csr_src[base + i] = csrb[i];
}

// ---------------- degree sort: hist -> scan -> perm ----------------

__global__ __launch_bounds__(256) void dhist_k(const int* __restrict__ rowstart,
                                               int* __restrict__ gdh) {
    __shared__ int h[NDC];
    int t = threadIdx.x;
    if (t < NDC) h[t] = 0;
    __syncthreads();
    int n0 = blockIdx.x * 1024;
#pragma unroll
    for (int i = 0; i < 4; i++) {
        int n = n0 + i * 256 + t;
        if (n < NN) {
            int d = rowstart[n + 1] - rowstart[n];
            if (d > NDC - 1) d = NDC - 1;
            atomicAdd(&h[d], 1);
        }
    }
    __syncthreads();
    if (t < NDC && h[t]) atomicAdd(&gdh[t], h[t]);
}

__global__ __launch_bounds__(64) void dscan_k(const int* __restrict__ gdh,
                                              int* __restrict__ gdcur) {
    int t = threadIdx.x;
    int v = gdh[t];
    int inc = v;
#pragma unroll
    for (int off = 1; off < NDC; off <<= 1) {
        int u = __shfl_up(inc, off);
        if (t >= off) inc += u;
    }
    gdcur[t] = inc - v;
}

__global__ __launch_bounds__(256) void dperm_k(const int* __restrict__ rowstart,
                                               int* __restrict__ gdcur,
                                               int* __restrict__ perm) {
    __shared__ int h[NDC];
    __shared__ int cur[NDC];
    int t = threadIdx.x;
    if (t < NDC) h[t] = 0;
    __syncthreads();
    int n0 = blockIdx.x * 1024;
    int myd[4];
#pragma unroll
    for (int i = 0; i < 4; i++) {
        int n = n0 + i * 256 + t;
        myd[i] = -1;
        if (n < NN) {
            int d = rowstart[n + 1] - rowstart[n];
            if (d > NDC - 1) d = NDC - 1;
            myd[i] = d;
            atomicAdd(&h[d], 1);
        }
    }
    __syncthreads();
    if (t < NDC) cur[t] = h[t] ? atomicAdd(&gdcur[t], h[t]) : 0;
    __syncthreads();
#pragma unroll
    for (int i = 0; i < 4; i++) {
        if (myd[i] >= 0) {
            int pos = atomicAdd(&cur[myd[i]], 1);
            perm[pos] = n0 + i * 256 + t;
        }
    }
}

// ---------------- fused 4-matrix MFMA GEMM, swapped operands ----------------
// k-wave (wv==1) and v-wave (wv==2) emit fp8 e4m3 into one [NN][128B] kv row
// (k = bytes 0..63, v = bytes 64..127); q/skip emit bf16.

__global__ __launch_bounds__(256) void gemm4_k(const ushort_t* __restrict__ hbf,
                                               const ushort_t* __restrict__ wpl,
                                               const float* __restrict__ bq_, const float* __restrict__ bk_,
                                               const float* __restrict__ bv_, const float* __restrict__ bs_,
                                               ushort_t* __restrict__ qo, unsigned char* __restrict__ kv8,
                                               ushort_t* __restrict__ so) {
    int t = threadIdx.x;
    int lane = t & 63, wv = t >> 6;
    int ln = lane & 15, lq = lane >> 4;
    int rowbase = blockIdx.x * 64;

    const float* bsel = (wv == 0) ? bq_ : (wv == 1) ? bk_ : (wv == 2) ? bv_ : bs_;
    ushort_t* osel    = (wv == 0) ? qo : so;   // wv 1/2 use kv8 path
    int kvoff = (wv == 1) ? 0 : 64;

    short8v wfrag[4][2];
#pragma unroll
    for (int ct = 0; ct < 4; ct++)
#pragma unroll
        for (int ks = 0; ks < 2; ks++)
            wfrag[ct][ks] = *(const short8v*)&wpl[((size_t)(wv * 8 + ct * 2 + ks)) * 512 + lane * 8];

    float4 bias[4];
#pragma unroll
    for (int ct = 0; ct < 4; ct++) bias[ct] = *(const float4*)&bsel[ct * 16 + lq * 4];

#pragma unroll
    for (int rt = 0; rt < 4; rt++) {
        int grow = rowbase + rt * 16 + ln;
        bool rv = grow < NN;
        int gr = rv ? grow : NN - 1;
        short8v h0 = *(const short8v*)&hbf[(size_t)gr * DD + lq * 8];
        short8v h1 = *(const short8v*)&hbf[(size_t)gr * DD + 32 + lq * 8];
#pragma unroll
        for (int ct = 0; ct < 4; ct++) {
            f32x4 acc;
            acc[0] = bias[ct].x; acc[1] = bias[ct].y; acc[2] = bias[ct].z; acc[3] = bias[ct].w;
            acc = __builtin_amdgcn_mfma_f32_16x16x32_bf16(wfrag[ct][0], h0, acc, 0, 0, 0);
            acc = __builtin_amdgcn_mfma_f32_16x16x32_bf16(wfrag[ct][1], h1, acc, 0, 0, 0);
            if (rv) {
                if (wv == 1 || wv == 2) {
                    int pk8 = __builtin_amdgcn_cvt_pk_fp8_f32(acc[0], acc[1], 0, false);
                    pk8 = __builtin_amdgcn_cvt_pk_fp8_f32(acc[2], acc[3], pk8, true);
                    *(u32*)&kv8[(size_t)grow * 128 + kvoff + ct * 16 + lq * 4] = (u32)pk8;
                } else {
                    uint2 pk;
                    pk.x = cvtpk(acc[0], acc[1]);
                    pk.y = cvtpk(acc[2], acc[3]);
                    *(uint2*)&osel[(size_t)grow * DD + ct * 16 + lq * 4] = pk;
                }
            }
        }
    }
}

// ---------------- single-pass online-softmax aggregate + skip + relu ----------------
// Degree-sorted: slot -> perm[slot] = node; 4 nodes/wave (uniform degree).
// Node = 2 groups of 8 lanes (sub = even/odd edges); lane j owns dims 8j..8j+7.
// One 128B kv line per edge; lane j loads k bytes [8j..8j+8) and v bytes
// [64+8j..64+8j+8) of the SAME line. All lanes active in both phases.

#define SCLOG2E 0.18033688011112042f  // 0.125 * log2(e)

__global__ __launch_bounds__(256) void agg_k(const ushort_t* __restrict__ qb,
                                             const unsigned char* __restrict__ kv8,
                                             const ushort_t* __restrict__ skb,
                                             const int* __restrict__ rowstart,
                                             const int* __restrict__ csr_src,
                                             const int* __restrict__ perm,
                                             ushort_t* __restrict__ hout) {
    int wv = threadIdx.x >> 6, lane = threadIdx.x & 63;
    int g = lane >> 3, j = lane & 7, sub = g & 1;
    int slot = blockIdx.x * 16 + wv * 4 + (g >> 1);
    if (slot >= NN) return;
    int nid = perm[slot];
    int r0 = rowstart[nid];
    int r1 = rowstart[nid + 1];

    // q dims [8j..8j+8)
    u32x4 qa = *(const u32x4*)(qb + ((u32)nid << 6) + ((u32)j << 3));
    f32x2 q0 = bfpair(qa.x), q1 = bfpair(qa.y), q2 = bfpair(qa.z), q3 = bfpair(qa.w);

    float m = -1.0e38f, se = 0.f;
    f32x2 a0 = {0.f, 0.f}, a1 = {0.f, 0.f}, a2 = {0.f, 0.f}, a3 = {0.f, 0.f};

    int clampE = r1 - 1; if (clampE < 0) clampE = 0;   // node's own last edge: cache-hot
    int e0 = r0 + sub;
    int s0 = csr_src[e0 < clampE ? e0 : clampE];
    uint2 k0 = *(const uint2*)(kv8 + (size_t)s0 * 128 + 8 * j);
    uint2 v0 = *(const uint2*)(kv8 + (size_t)s0 * 128 + 64 + 8 * j);

    while (__ballot(e0 < r1)) {
        int e1 = e0 + 2;
        int s1 = csr_src[e1 < clampE ? e1 : clampE];
        uint2 k1 = *(const uint2*)(kv8 + (size_t)s1 * 128 + 8 * j);
        uint2 v1 = *(const uint2*)(kv8 + (size_t)s1 * 128 + 64 + 8 * j);

        f32x2 dp2 = q0 * f8pair<false>(k0.x);
        dp2 += q1 * f8pair<true >(k0.x);
        dp2 += q2 * f8pair<false>(k0.y);
        dp2 += q3 * f8pair<true >(k0.y);
        float dp = sum8(dp2.x + dp2.y);

        float w = 0.f;
        if (e0 < r1) {
            float sc = dp * SCLOG2E;
            if (sc <= m + 11.5f) { w = exp2f(sc - m); }
            else {
                float cc = exp2f(m - sc);
                se *= cc; a0 *= cc; a1 *= cc; a2 *= cc; a3 *= cc;
                m = sc; w = 1.f;
            }
        }
        se += w;
        a0 += f8pair<false>(v0.x) * w;
        a1 += f8pair<true >(v0.x) * w;
        a2 += f8pair<false>(v0.y) * w;
        a3 += f8pair<true >(v0.y) * w;

        e0 = e1; k0 = k1; v0 = v1;
    }

    // combine the node's two groups (xor8)
    float M = fmaxf(m, __shfl_xor(m, 8));
    float cc = exp2f(m - M);
    se *= cc; a0 *= cc; a1 *= cc; a2 *= cc; a3 *= cc;
    se += __shfl_xor(se, 8);
    a0.x += __shfl_xor(a0.x, 8); a0.y += __shfl_xor(a0.y, 8);
    a1.x += __shfl_xor(a1.x, 8); a1.y += __shfl_xor(a1.y, 8);
    a2.x += __shfl_xor(a2.x, 8); a2.y += __shfl_xor(a2.y, 8);
    a3.x += __shfl_xor(a3.x, 8); a3.y += __shfl_xor(a3.y, 8);

    if (sub == 0) {
        float inv = 1.0f / (se + 1e-16f);
        u32x4 sk = *(const u32x4*)(skb + ((u32)nid << 6) + ((u32)j << 3));
        f32x2 o0 = a0 * inv + bfpair(sk.x);
        f32x2 o1 = a1 * inv + bfpair(sk.y);
        f32x2 o2 = a2 * inv + bfpair(sk.z);
        f32x2 o3 = a3 * inv + bfpair(sk.w);
        u32x4 pk;
        pk.x = cvtpk(fmaxf(o0.x, 0.f), fmaxf(o0.y, 0.f));
        pk.y = cvtpk(fmaxf(o1.x, 0.f), fmaxf(o1.y, 0.f));
        pk.z = cvtpk(fmaxf(o2.x, 0.f), fmaxf(o2.y, 0.f));
        pk.w = cvtpk(fmaxf(o3.x, 0.f), fmaxf(o3.y, 0.f));
        *(u32x4*)(hout + ((u32)nid << 6) + ((u32)j << 3)) = pk;
    }
}

// ---------------- global add pool ----------------

#define POOL_ROWS 128

__global__ __launch_bounds__(256) void pool_k(const ushort_t* __restrict__ h,
                                              const int* __restrict__ batch,
                                              float* __restrict__ pooled) {
    int i0 = blockIdx.x * POOL_ROWS;
    int i1 = i0 + POOL_ROWS; if (i1 > NN) i1 = NN;
    int lane = threadIdx.x & 63;
    int wv = threadIdx.x >> 6;
    float acc = 0.f;
    int gcur = -1;
    for (int i = i0 + wv; i < i1; i += 4) {
        int gi = batch[i];
        if (gi != gcur) {
            if (gcur >= 0) atomicAdd(&pooled[gcur * DD + lane], acc);
            gcur = gi; acc = 0.f;
        }
        unsigned u = ((unsigned)h[(size_t)i * DD + lane]) << 16;
        acc += __builtin_bit_cast(float, u);
    }
    if (gcur >= 0) atomicAdd(&pooled[gcur * DD + lane], acc);
}

// ---------------- head ----------------

__global__ __launch_bounds__(64) void head_k(const float* __restrict__ pooled2,
                                             const float* __restrict__ W1,
                                             const float* __restrict__ b1,
                                             const float* __restrict__ W2,
                                             const float* __restrict__ b2,
                                             float* __restrict__ out) {
    int g = blockIdx.x;
    int c = threadIdx.x;
    __shared__ float pg[64], p[64];
    pg[c] = pooled2[g * DD + c];
    __syncthreads();
    float a = b1[c];
#pragma unroll 8
    for (int kk = 0; kk < 64; kk++) a += pg[kk] * W1[kk * DD + c];
    p[c] = fmaxf(a, 0.f);
    __syncthreads();
    if (c < 10) {
        float o = b2[c];
#pragma unroll 8
        for (int kk = 0; kk < 64; kk++) o += p[kk] * W2[kk * 10 + c];
        out[g * 10 + c] = o;
    }
}

// ---------------- launch ----------------

extern "C" void kernel_launch(void* const* d_in, const int* in_sizes, int n_in,
                              void* d_out, int out_size, void* d_ws, size_t ws_size,
                              hipStream_t stream) {
    const float* x    = (const float*)d_in[0];
    const int*   ei   = (const int*)d_in[1];
    const int*   batch= (const int*)d_in[2];
    const float* Wq   = (const float*)d_in[3];
    const float* bq   = (const float*)d_in[4];
    const float* Wk   = (const float*)d_in[5];
    const float* bk   = (const float*)d_in[6];
    const float* Wv   = (const float*)d_in[7];
    const float* bv   = (const float*)d_in[8];
    const float* Wsp  = (const float*)d_in[9];
    const float* bsp  = (const float*)d_in[10];
    const float* W1   = (const float*)d_in[11];
    const float* b1   = (const float*)d_in[12];
    const float* W2   = (const float*)d_in[13];
    const float* b2   = (const float*)d_in[14];
    float* out = (float*)d_out;
    float* pooled = out + NG * 10;

    const int* srcv = ei;
    const int* dstv = ei + NE;

    const size_t NEL = (size_t)NN * DD;
    ushort_t* hbf = (ushort_t*)d_ws;                 // [NN][64] bf16
    ushort_t* qb  = hbf + NEL;                       // bf16
    ushort_t* skb = qb  + NEL;                       // bf16
    unsigned char* kv8 = (unsigned char*)(skb + NEL); // [NN][128] fp8 k|v
    u32* binbuf   = (u32*)(kv8 + (size_t)NN * 128);  // [NBUK*BCAP]
    int* gcur     = (int*)(binbuf + (size_t)NBUK * BCAP);  // [NBUK]
    int* gdh      = gcur + NBUK;                     // [NDC]
    int* gdcur    = gdh + NDC;                       // [NDC]
    int* rowstart = gdcur + NDC;                     // [NN+1]
    int* csr_src  = rowstart + (NN + 1);             // [NE]
    int* perm     = csr_src + NE;                    // [NN]
    ushort_t* wpack = (ushort_t*)(perm + NN);        // 12*4096 bf16

    int totOut = NG * 10 + NL * NG * DD;
    int cvtBlocks = (int)(NEL / 4 / 256);            // 6250 (exact)
    int zeroBlocks = (totOut + 255) / 256;           // 102

    setup_k<<<cvtBlocks + zeroBlocks + NL * 4, 256, 0, stream>>>(
        x, hbf, out, totOut, gcur, gdh, Wq, Wk, Wv, Wsp, wpack, cvtBlocks, zeroBlocks);

    bin_k<<<NBLK, 256, 0, stream>>>(srcv, dstv, binbuf, gcur);
    csr_k<<<NBUK, 256, 0, stream>>>(binbuf, gcur, rowstart, csr_src);

    int dblocks = (NN + 1023) / 1024;
    dhist_k<<<dblocks, 256, 0, stream>>>(rowstart, gdh);
    dscan_k<<<1, 64, 0, stream>>>(gdh, gdcur);
    dperm_k<<<dblocks, 256, 0, stream>>>(rowstart, gdcur, perm);

    int gtiles = (NN + 63) / 64;
    int poolblocks = (NN + POOL_ROWS - 1) / POOL_ROWS;
    for (int l = 0; l < NL; l++) {
        gemm4_k<<<gtiles, 256, 0, stream>>>(hbf, wpack + (size_t)l * 4 * 8 * 512,
                                            bq + l * DD, bk + l * DD, bv + l * DD, bsp + l * DD,
                                            qb, kv8, skb);
        agg_k<<<(NN + 15) / 16, 256, 0, stream>>>(qb, kv8, skb, rowstart, csr_src, perm, hbf);
        pool_k<<<poolblocks, 256, 0, stream>>>(hbf, batch, pooled + l * NG * DD);
    }
    head_k<<<NG, 64, 0, stream>>>(pooled + 2 * NG * DD, W1, b1, W2, b2, out);
}

// Round 12
// 253.047 us; speedup vs baseline: 1.3391x; 1.0104x over previous
//
#include <hip/hip_runtime.h>
#include <hip/hip_bf16.h>
#include <math.h>

#define NN 100000
#define NE 1000000
#define DD 64
#define NG 128
#define NL 3

#define NBUK 196          // dst >> 9 buckets (512 nodes each)
#define EPB 2048          // edges per bin block
#define NBLK ((NE + EPB - 1) / EPB)   // 489
#define BCAP 6144         // per-bucket capacity (mean 5120, ~14 sigma margin)
#define NDC 64            // degree classes for node sort

typedef unsigned short ushort_t;
typedef unsigned int u32;
typedef __attribute__((ext_vector_type(8))) short short8v;
typedef __attribute__((ext_vector_type(2))) float f32x2;
typedef __attribute__((ext_vector_type(4))) float f32x4;
typedef __attribute__((ext_vector_type(4))) unsigned int u32x4;

__device__ __forceinline__ ushort_t f2bf(float f) {
    __hip_bfloat16 h = __float2bfloat16(f);
    return *reinterpret_cast<ushort_t*>(&h);
}
__device__ __forceinline__ unsigned cvtpk(float lo, float hi) {
    unsigned r;
    asm("v_cvt_pk_bf16_f32 %0, %1, %2" : "=v"(r) : "v"(lo), "v"(hi));
    return r;
}
__device__ __forceinline__ f32x2 bfpair(u32 u) {
    f32x2 r;
    r.x = __builtin_bit_cast(float, u << 16);
    r.y = __builtin_bit_cast(float, u & 0xffff0000u);
    return r;
}
template <bool HI>
__device__ __forceinline__ f32x2 f8pair(u32 u) {
    return __builtin_amdgcn_cvt_pk_f32_fp8(u, HI);
}
// sum over each 8-lane group
__device__ __forceinline__ float sum8(float x) {
    int v = __builtin_bit_cast(int, x);
    x += __builtin_bit_cast(float, __builtin_amdgcn_update_dpp(0, v, 0xB1, 0xF, 0xF, true));
    v = __builtin_bit_cast(int, x);
    x += __builtin_bit_cast(float, __builtin_amdgcn_update_dpp(0, v, 0x4E, 0xF, 0xF, true));
    v = __builtin_bit_cast(int, x);
    x += __builtin_bit_cast(float, __builtin_amdgcn_update_dpp(0, v, 0x141, 0xF, 0xF, true));
    return x;
}

// ---------------- zero: out + gcur + gdh ----------------

__global__ __launch_bounds__(256) void zero_k(float* __restrict__ out, int totOut,
                                              int* __restrict__ gcur, int* __restrict__ gdh) {
    int i = blockIdx.x * 256 + threadIdx.x;
    if (i < totOut) out[i] = 0.f;
    if (blockIdx.x == 0 && threadIdx.x < NBUK) gcur[threadIdx.x] = 0;
    if (blockIdx.x == 1 && threadIdx.x < NDC) gdh[threadIdx.x] = 0;
}

// ---------------- fused: cvt + packw + bin ----------------
// blocks [0,cvtBlocks): f32->bf16 convert of x
// blocks [cvtBlocks, +NL*4): W pre-pack
// blocks [cvtBlocks+NL*4, +NBLK): edge bucket binning

__global__ __launch_bounds__(256) void fused_k(const float* __restrict__ x, ushort_t* __restrict__ hbf,
                                               const float* __restrict__ Wq, const float* __restrict__ Wk,
                                               const float* __restrict__ Wv, const float* __restrict__ Ws_,
                                               ushort_t* __restrict__ wpack,
                                               const int* __restrict__ src, const int* __restrict__ dst,
                                               u32* __restrict__ binbuf, int* __restrict__ gcur,
                                               int cvtBlocks) {
    __shared__ int hist[NBUK];
    __shared__ int excl[NBUK];
    __shared__ int cur[NBUK];
    __shared__ int gbase[NBUK];
    __shared__ int tmp[256];
    __shared__ u32 pairs[EPB];
    __shared__ unsigned char bukid[EPB];

    int b = blockIdx.x, t = threadIdx.x;
    if (b < cvtBlocks) {
        int base = (b * 256 + t) * 4;
        float4 v = *(const float4*)&x[base];
        uint2 pk;
        pk.x = cvtpk(v.x, v.y);
        pk.y = cvtpk(v.z, v.w);
        *(uint2*)&hbf[base] = pk;
        return;
    }
    b -= cvtBlocks;
    if (b < NL * 4) {
        if (t < 64) {
            int mat = b & 3, layer = b >> 2;
            const float* W = ((mat == 0) ? Wq : (mat == 1) ? Wk : (mat == 2) ? Wv : Ws_) + layer * DD * DD;
#pragma unroll
            for (int ct = 0; ct < 4; ct++)
#pragma unroll
                for (int ks = 0; ks < 2; ks++)
#pragma unroll
                    for (int j = 0; j < 8; j++) {
                        float v = W[(ks * 32 + (t >> 4) * 8 + j) * DD + ct * 16 + (t & 15)];
                        wpack[((size_t)(b * 8 + ct * 2 + ks)) * 512 + t * 8 + j] = f2bf(v);
                    }
        }
        return;
    }
    b -= NL * 4;   // bin block index
    int e0 = b * EPB;
    int totvalid = NE - e0; if (totvalid > EPB) totvalid = EPB;

    for (int i = t; i < NBUK; i += 256) hist[i] = 0;
    __syncthreads();

    int mysrc[8], mydst[8];
#pragma unroll
    for (int i = 0; i < 8; i++) {
        int e = e0 + i * 256 + t;
        bool v = e < NE;
        mysrc[i] = v ? src[e] : -1;
        mydst[i] = v ? dst[e] : -1;
        if (v) atomicAdd(&hist[mydst[i] >> 9], 1);
    }
    __syncthreads();

    int v = (t < NBUK) ? hist[t] : 0;
    tmp[t] = v;
    __syncthreads();
#pragma unroll
    for (int off = 1; off < 256; off <<= 1) {
        int a = (t >= off) ? tmp[t - off] : 0;
        __syncthreads();
        tmp[t] += a;
        __syncthreads();
    }
    if (t < NBUK) { excl[t] = tmp[t] - v; cur[t] = tmp[t] - v; }
    __syncthreads();

#pragma unroll
    for (int i = 0; i < 8; i++) {
        if (mydst[i] >= 0) {
            int bb = mydst[i] >> 9;
            int p = atomicAdd(&cur[bb], 1);
            pairs[p] = ((u32)(mydst[i] & 511) << 17) | (u32)mysrc[i];
            bukid[p] = (unsigned char)bb;
        }
    }
    if (t < NBUK && v > 0) gbase[t] = atomicAdd(&gcur[t], v);
    __syncthreads();

    for (int i = t; i < totvalid; i += 256) {
        int bb = bukid[i];
        int idx = gbase[bb] + (i - excl[bb]);
        if (idx < BCAP) binbuf[(size_t)bb * BCAP + idx] = pairs[i];
    }
}

// ---------------- csr_k: CSR finalize + degree-class histogram ----------------

__global__ __launch_bounds__(256) void csr_k(const u32* __restrict__ binbuf,
                                             const int* __restrict__ gcur,
                                             int* __restrict__ rowstart,
                                             int* __restrict__ csr_src,
                                             int* __restrict__ gdh) {
    __shared__ u32 pairs[BCAP];
    __shared__ int csrb[BCAP];
    __shared__ int deg[512];
    __shared__ int excl[512];
    __shared__ int cur[512];
    __shared__ int tmp[512];
    __shared__ int bt[256];
    __shared__ int ch[NDC];
    int b = blockIdx.x;
    int t = threadIdx.x;

    int bv = 0;
    if (t < NBUK) { bv = gcur[t]; if (bv > BCAP) bv = BCAP; }
    bt[t] = bv;
    __syncthreads();
#pragma unroll
    for (int off = 1; off < 256; off <<= 1) {
        int a = (t >= off) ? bt[t - off] : 0;
        __syncthreads();
        bt[t] += a;
        __syncthreads();
    }
    int base = (b == 0) ? 0 : bt[b - 1];
    int T = bt[b] - base;
    if (b == 0 && t == 0) rowstart[NN] = bt[NBUK - 1];
    int nbase = b << 9;

    for (int i = t; i < 512; i += 256) deg[i] = 0;
    if (t < NDC) ch[t] = 0;
    for (int i = t; i < T; i += 256) pairs[i] = binbuf[(size_t)b * BCAP + i];
    __syncthreads();
    for (int i = t; i < T; i += 256) atomicAdd(&deg[pairs[i] >> 17], 1);
    __syncthreads();

    // degree-class histogram (real nodes only)
    for (int i = t; i < 512; i += 256) {
        if (nbase + i < NN) {
            int d = deg[i]; if (d > NDC - 1) d = NDC - 1;
            atomicAdd(&ch[d], 1);
        }
    }

    int v0 = deg[t], v1 = deg[t + 256];
    tmp[t] = v0; tmp[t + 256] = v1;
    __syncthreads();
#pragma unroll
    for (int off = 1; off < 512; off <<= 1) {
        int a0 = (t >= off) ? tmp[t - off] : 0;
        int i1 = t + 256;
        int a1 = (i1 >= off) ? tmp[i1 - off] : 0;
        __syncthreads();
        tmp[t] += a0; tmp[i1] += a1;
        __syncthreads();
    }
    excl[t] = tmp[t] - v0; excl[t + 256] = tmp[t + 256] - v1;
    cur[t] = excl[t]; cur[t + 256] = excl[t + 256];
    if (t < NDC && ch[t]) atomicAdd(&gdh[t], ch[t]);
    __syncthreads();

    for (int i = t; i < 512; i += 256) {
        int n = nbase + i;
        if (n < NN) rowstart[n] = base + excl[i];
    }

    for (int i = t; i < T; i += 256) {
        u32 p = pairs[i];
        int pos = atomicAdd(&cur[p >> 17], 1);
        csrb[pos] = (int)(p & 0x1FFFFu);
    }
    __syncthreads();
    for (int i = t; i < T; i += 256) csr_src[base + i] = csrb[i];
}

// ---------------- degree sort: scan -> perm ----------------

__global__ __launch_bounds__(64) void dscan_k(const int* __restrict__ gdh,
                                              int* __restrict__ gdcur) {
    int t = threadIdx.x;
    int v = gdh[t];
    int inc = v;
#pragma unroll
    for (int off = 1; off < NDC; off <<= 1) {
        int u = __shfl_up(inc, off);
        if (t >= off) inc += u;
    }
    gdcur[t] = inc - v;
}

__global__ __launch_bounds__(256) void dperm_k(const int* __restrict__ rowstart,
                                               int* __restrict__ gdcur,
                                               int* __restrict__ perm) {
    __shared__ int h[NDC];
    __shared__ int cur[NDC];
    int t = threadIdx.x;
    if (t < NDC) h[t] = 0;
    __syncthreads();
    int n0 = blockIdx.x * 1024;
    int myd[4];
#pragma unroll
    for (int i = 0; i < 4; i++) {
        int n = n0 + i * 256 + t;
        myd[i] = -1;
        if (n < NN) {
            int d = rowstart[n + 1] - rowstart[n];
            if (d > NDC - 1) d = NDC - 1;
            myd[i] = d;
            atomicAdd(&h[d], 1);
        }
    }
    __syncthreads();
    if (t < NDC) cur[t] = h[t] ? atomicAdd(&gdcur[t], h[t]) : 0;
    __syncthreads();
#pragma unroll
    for (int i = 0; i < 4; i++) {
        if (myd[i] >= 0) {
            int pos = atomicAdd(&cur[myd[i]], 1);
            perm[pos] = n0 + i * 256 + t;
        }
    }
}

// ---------------- fused 4-matrix MFMA GEMM, swapped operands ----------------

__global__ __launch_bounds__(256) void gemm4_k(const ushort_t* __restrict__ hbf,
                                               const ushort_t* __restrict__ wpl,
                                               const float* __restrict__ bq_, const float* __restrict__ bk_,
                                               const float* __restrict__ bv_, const float* __restrict__ bs_,
                                               ushort_t* __restrict__ qo, unsigned char* __restrict__ kv8,
                                               ushort_t* __restrict__ so) {
    int t = threadIdx.x;
    int lane = t & 63, wv = t >> 6;
    int ln = lane & 15, lq = lane >> 4;
    int rowbase = blockIdx.x * 64;

    const float* bsel = (wv == 0) ? bq_ : (wv == 1) ? bk_ : (wv == 2) ? bv_ : bs_;
    ushort_t* osel    = (wv == 0) ? qo : so;
    int kvoff = (wv == 1) ? 0 : 64;

    short8v wfrag[4][2];
#pragma unroll
    for (int ct = 0; ct < 4; ct++)
#pragma unroll
        for (int ks = 0; ks < 2; ks++)
            wfrag[ct][ks] = *(const short8v*)&wpl[((size_t)(wv * 8 + ct * 2 + ks)) * 512 + lane * 8];

    float4 bias[4];
#pragma unroll
    for (int ct = 0; ct < 4; ct++) bias[ct] = *(const float4*)&bsel[ct * 16 + lq * 4];

#pragma unroll
    for (int rt = 0; rt < 4; rt++) {
        int grow = rowbase + rt * 16 + ln;
        bool rv = grow < NN;
        int gr = rv ? grow : NN - 1;
        short8v h0 = *(const short8v*)&hbf[(size_t)gr * DD + lq * 8];
        short8v h1 = *(const short8v*)&hbf[(size_t)gr * DD + 32 + lq * 8];
#pragma unroll
        for (int ct = 0; ct < 4; ct++) {
            f32x4 acc;
            acc[0] = bias[ct].x; acc[1] = bias[ct].y; acc[2] = bias[ct].z; acc[3] = bias[ct].w;
            acc = __builtin_amdgcn_mfma_f32_16x16x32_bf16(wfrag[ct][0], h0, acc, 0, 0, 0);
            acc = __builtin_amdgcn_mfma_f32_16x16x32_bf16(wfrag[ct][1], h1, acc, 0, 0, 0);
            if (rv) {
                if (wv == 1 || wv == 2) {
                    int pk8 = __builtin_amdgcn_cvt_pk_fp8_f32(acc[0], acc[1], 0, false);
                    pk8 = __builtin_amdgcn_cvt_pk_fp8_f32(acc[2], acc[3], pk8, true);
                    *(u32*)&kv8[(size_t)grow * 128 + kvoff + ct * 16 + lq * 4] = (u32)pk8;
                } else {
                    uint2 pk;
                    pk.x = cvtpk(acc[0], acc[1]);
                    pk.y = cvtpk(acc[2], acc[3]);
                    *(uint2*)&osel[(size_t)grow * DD + ct * 16 + lq * 4] = pk;
                }
            }
        }
    }
}

// ---------------- aggregate: degree-DESCENDING, depth-2 prefetch ----------------

#define SCLOG2E 0.18033688011112042f  // 0.125 * log2(e)

__global__ __launch_bounds__(256) void agg_k(const ushort_t* __restrict__ qb,
                                             const unsigned char* __restrict__ kv8,
                                             const ushort_t* __restrict__ skb,
                                             const int* __restrict__ rowstart,
                                             const int* __restrict__ csr_src,
                                             const int* __restrict__ perm,
                                             ushort_t* __restrict__ hout) {
    int wv = threadIdx.x >> 6, lane = threadIdx.x & 63;
    int g = lane >> 3, j = lane & 7, sub = g & 1;
    int slot = blockIdx.x * 16 + wv * 4 + (g >> 1);
    if (slot >= NN) return;
    int nid = perm[(NN - 1) - slot];     // longest-first scheduling
    int r0 = rowstart[nid];
    int r1 = rowstart[nid + 1];

    u32x4 qa = *(const u32x4*)(qb + ((u32)nid << 6) + ((u32)j << 3));
    f32x2 q0 = bfpair(qa.x), q1 = bfpair(qa.y), q2 = bfpair(qa.z), q3 = bfpair(qa.w);

    float m = -1.0e38f, se = 0.f;
    f32x2 a0 = {0.f, 0.f}, a1 = {0.f, 0.f}, a2 = {0.f, 0.f}, a3 = {0.f, 0.f};

    int clampE = r1 - 1; if (clampE < 0) clampE = 0;
    int e0 = r0 + sub, e1 = e0 + 2;
    int s0 = csr_src[e0 < clampE ? e0 : clampE];
    int s1 = csr_src[e1 < clampE ? e1 : clampE];
    uint2 k0 = *(const uint2*)(kv8 + (size_t)s0 * 128 + 8 * j);
    uint2 v0 = *(const uint2*)(kv8 + (size_t)s0 * 128 + 64 + 8 * j);
    uint2 k1 = *(const uint2*)(kv8 + (size_t)s1 * 128 + 8 * j);
    uint2 v1 = *(const uint2*)(kv8 + (size_t)s1 * 128 + 64 + 8 * j);

    while (__ballot(e0 < r1)) {
        int e2 = e1 + 2;
        int s2 = csr_src[e2 < clampE ? e2 : clampE];
        uint2 k2 = *(const uint2*)(kv8 + (size_t)s2 * 128 + 8 * j);
        uint2 v2 = *(const uint2*)(kv8 + (size_t)s2 * 128 + 64 + 8 * j);

        f32x2 dp2 = q0 * f8pair<false>(k0.x);
        dp2 += q1 * f8pair<true >(k0.x);
        dp2 += q2 * f8pair<false>(k0.y);
        dp2 += q3 * f8pair<true >(k0.y);
        float dp = sum8(dp2.x + dp2.y);

        float w = 0.f;
        if (e0 < r1) {
            float sc = dp * SCLOG2E;
            if (sc <= m + 11.5f) { w = exp2f(sc - m); }
            else {
                float cc = exp2f(m - sc);
                se *= cc; a0 *= cc; a1 *= cc; a2 *= cc; a3 *= cc;
                m = sc; w = 1.f;
            }
        }
        se += w;
        a0 += f8pair<false>(v0.x) * w;
        a1 += f8pair<true >(v0.x) * w;
        a2 += f8pair<false>(v0.y) * w;
        a3 += f8pair<true >(v0.y) * w;

        e0 = e1; e1 = e2;
        k0 = k1; v0 = v1; k1 = k2; v1 = v2;
    }

    float M = fmaxf(m, __shfl_xor(m, 8));
    float cc = exp2f(m - M);
    se *= cc; a0 *= cc; a1 *= cc; a2 *= cc; a3 *= cc;
    se += __shfl_xor(se, 8);
    a0.x += __shfl_xor(a0.x, 8); a0.y += __shfl_xor(a0.y, 8);
    a1.x += __shfl_xor(a1.x, 8); a1.y += __shfl_xor(a1.y, 8);
    a2.x += __shfl_xor(a2.x, 8); a2.y += __shfl_xor(a2.y, 8);
    a3.x += __shfl_xor(a3.x, 8); a3.y += __shfl_xor(a3.y, 8);

    if (sub == 0) {
        float inv = 1.0f / (se + 1e-16f);
        u32x4 sk = *(const u32x4*)(skb + ((u32)nid << 6) + ((u32)j << 3));
        f32x2 o0 = a0 * inv + bfpair(sk.x);
        f32x2 o1 = a1 * inv + bfpair(sk.y);
        f32x2 o2 = a2 * inv + bfpair(sk.z);
        f32x2 o3 = a3 * inv + bfpair(sk.w);
        u32x4 pk;
        pk.x = cvtpk(fmaxf(o0.x, 0.f), fmaxf(o0.y, 0.f));
        pk.y = cvtpk(fmaxf(o1.x, 0.f), fmaxf(o1.y, 0.f));
        pk.z = cvtpk(fmaxf(o2.x, 0.f), fmaxf(o2.y, 0.f));
        pk.w = cvtpk(fmaxf(o3.x, 0.f), fmaxf(o3.y, 0.f));
        *(u32x4*)(hout + ((u32)nid << 6) + ((u32)j << 3)) = pk;
    }
}

// ---------------- global add pool ----------------

#define POOL_ROWS 128

__global__ __launch_bounds__(256) void pool_k(const ushort_t* __restrict__ h,
                                              const int* __restrict__ batch,
                                              float* __restrict__ pooled) {
    int i0 = blockIdx.x * POOL_ROWS;
    int i1 = i0 + POOL_ROWS; if (i1 > NN) i1 = NN;
    int lane = threadIdx.x & 63;
    int wv = threadIdx.x >> 6;
    float acc = 0.f;
    int gcur = -1;
    for (int i = i0 + wv; i < i1; i += 4) {
        int gi = batch[i];
        if (gi != gcur) {
            if (gcur >= 0) atomicAdd(&pooled[gcur * DD + lane], acc);
            gcur = gi; acc = 0.f;
        }
        unsigned u = ((unsigned)h[(size_t)i * DD + lane]) << 16;
        acc += __builtin_bit_cast(float, u);
    }
    if (gcur >= 0) atomicAdd(&pooled[gcur * DD + lane], acc);
}

// ---------------- head ----------------

__global__ __launch_bounds__(64) void head_k(const float* __restrict__ pooled2,
                                             const float* __restrict__ W1,
                                             const float* __restrict__ b1,
                                             const float* __restrict__ W2,
                                             const float* __restrict__ b2,
                                             float* __restrict__ out) {
    int g = blockIdx.x;
    int c = threadIdx.x;
    __shared__ float pg[64], p[64];
    pg[c] = pooled2[g * DD + c];
    __syncthreads();
    float a = b1[c];
#pragma unroll 8
    for (int kk = 0; kk < 64; kk++) a += pg[kk] * W1[kk * DD + c];
    p[c] = fmaxf(a, 0.f);
    __syncthreads();
    if (c < 10) {
        float o = b2[c];
#pragma unroll 8
        for (int kk = 0; kk < 64; kk++) o += p[kk] * W2[kk * 10 + c];
        out[g * 10 + c] = o;
    }
}

// ---------------- launch ----------------

extern "C" void kernel_launch(void* const* d_in, const int* in_sizes, int n_in,
                              void* d_out, int out_size, void* d_ws, size_t ws_size,
                              hipStream_t stream) {
    const float* x    = (const float*)d_in[0];
    const int*   ei   = (const int*)d_in[1];
    const int*   batch= (const int*)d_in[2];
    const float* Wq   = (const float*)d_in[3];
    const float* bq   = (const float*)d_in[4];
    const float* Wk   = (const float*)d_in[5];
    const float* bk   = (const float*)d_in[6];
    const float* Wv   = (const float*)d_in[7];
    const float* bv   = (const float*)d_in[8];
    const float* Wsp  = (const float*)d_in[9];
    const float* bsp  = (const float*)d_in[10];
    const float* W1   = (const float*)d_in[11];
    const float* b1   = (const float*)d_in[12];
    const float* W2   = (const float*)d_in[13];
    const float* b2   = (const float*)d_in[14];
    float* out = (float*)d_out;
    float* pooled = out + NG * 10;

    const int* srcv = ei;
    const int* dstv = ei + NE;

    const size_t NEL = (size_t)NN * DD;
    ushort_t* hbf = (ushort_t*)d_ws;                 // [NN][64] bf16
    ushort_t* qb  = hbf + NEL;
    ushort_t* skb = qb  + NEL;
    unsigned char* kv8 = (unsigned char*)(skb + NEL); // [NN][128] fp8 k|v
    u32* binbuf   = (u32*)(kv8 + (size_t)NN * 128);  // [NBUK*BCAP]
    int* gcur     = (int*)(binbuf + (size_t)NBUK * BCAP);
    int* gdh      = gcur + NBUK;                     // [NDC]
    int* gdcur    = gdh + NDC;                       // [NDC]
    int* rowstart = gdcur + NDC;                     // [NN+1]
    int* csr_src  = rowstart + (NN + 1);             // [NE]
    int* perm     = csr_src + NE;                    // [NN]
    ushort_t* wpack = (ushort_t*)(perm + NN);        // 12*4096 bf16

    int totOut = NG * 10 + NL * NG * DD;
    int cvtBlocks = (int)(NEL / 4 / 256);            // 6250 (exact)
    int zeroBlocks = (totOut + 255) / 256;           // 102

    zero_k<<<zeroBlocks, 256, 0, stream>>>(out, totOut, gcur, gdh);
    fused_k<<<cvtBlocks + NL * 4 + NBLK, 256, 0, stream>>>(
        x, hbf, Wq, Wk, Wv, Wsp, wpack, srcv, dstv, binbuf, gcur, cvtBlocks);
    csr_k<<<NBUK, 256, 0, stream>>>(binbuf, gcur, rowstart, csr_src, gdh);
    dscan_k<<<1, 64, 0, stream>>>(gdh, gdcur);
    dperm_k<<<(NN + 1023) / 1024, 256, 0, stream>>>(rowstart, gdcur, perm);

    int gtiles = (NN + 63) / 64;
    int poolblocks = (NN + POOL_ROWS - 1) / POOL_ROWS;
    for (int l = 0; l < NL; l++) {
        gemm4_k<<<gtiles, 256, 0, stream>>>(hbf, wpack + (size_t)l * 4 * 8 * 512,
                                            bq + l * DD, bk + l * DD, bv + l * DD, bsp + l * DD,
                                            qb, kv8, skb);
        agg_k<<<(NN + 15) / 16, 256, 0, stream>>>(qb, kv8, skb, rowstart, csr_src, perm, hbf);
        pool_k<<<poolblocks, 256, 0, stream>>>(hbf, batch, pooled + l * NG * DD);
    }
    head_k<<<NG, 64, 0, stream>>>(pooled + 2 * NG * DD, W1, b1, W2, b2, out);
}

// Round 13
// 243.945 us; speedup vs baseline: 1.3891x; 1.0373x over previous
//
#include <hip/hip_runtime.h>
#include <hip/hip_bf16.h>
#include <math.h>

#define NN 100000
#define NE 1000000
#define DD 64
#define NG 128
#define NL 3

#define NBUK 196          // dst >> 9 buckets (512 nodes each)
#define EPB 2048          // edges per bin block
#define NBLK ((NE + EPB - 1) / EPB)   // 489
#define BCAP 6144         // per-bucket capacity (mean 5120, ~14 sigma margin)
#define NDC 64            // degree classes for node sort

typedef unsigned short ushort_t;
typedef unsigned int u32;
typedef __attribute__((ext_vector_type(8))) short short8v;
typedef __attribute__((ext_vector_type(2))) float f32x2;
typedef __attribute__((ext_vector_type(4))) float f32x4;
typedef __attribute__((ext_vector_type(4))) unsigned int u32x4;

__device__ __forceinline__ ushort_t f2bf(float f) {
    __hip_bfloat16 h = __float2bfloat16(f);
    return *reinterpret_cast<ushort_t*>(&h);
}
__device__ __forceinline__ unsigned cvtpk(float lo, float hi) {
    unsigned r;
    asm("v_cvt_pk_bf16_f32 %0, %1, %2" : "=v"(r) : "v"(lo), "v"(hi));
    return r;
}
__device__ __forceinline__ f32x2 bfpair(u32 u) {
    f32x2 r;
    r.x = __builtin_bit_cast(float, u << 16);
    r.y = __builtin_bit_cast(float, u & 0xffff0000u);
    return r;
}
template <bool HI>
__device__ __forceinline__ f32x2 f8pair(u32 u) {
    return __builtin_amdgcn_cvt_pk_f32_fp8(u, HI);
}
// sum over each 8-lane group
__device__ __forceinline__ float sum8(float x) {
    int v = __builtin_bit_cast(int, x);
    x += __builtin_bit_cast(float, __builtin_amdgcn_update_dpp(0, v, 0xB1, 0xF, 0xF, true));
    v = __builtin_bit_cast(int, x);
    x += __builtin_bit_cast(float, __builtin_amdgcn_update_dpp(0, v, 0x4E, 0xF, 0xF, true));
    v = __builtin_bit_cast(int, x);
    x += __builtin_bit_cast(float, __builtin_amdgcn_update_dpp(0, v, 0x141, 0xF, 0xF, true));
    return x;
}

// ---------------- zero: out + gcur + gdh ----------------

__global__ __launch_bounds__(256) void zero_k(float* __restrict__ out, int totOut,
                                              int* __restrict__ gcur, int* __restrict__ gdh) {
    int i = blockIdx.x * 256 + threadIdx.x;
    if (i < totOut) out[i] = 0.f;
    if (blockIdx.x == 0 && threadIdx.x < NBUK) gcur[threadIdx.x] = 0;
    if (blockIdx.x == 1 && threadIdx.x < NDC) gdh[threadIdx.x] = 0;
}

// ---------------- fused: cvt + packw + bin ----------------

__global__ __launch_bounds__(256) void fused_k(const float* __restrict__ x, ushort_t* __restrict__ hbf,
                                               const float* __restrict__ Wq, const float* __restrict__ Wk,
                                               const float* __restrict__ Wv, const float* __restrict__ Ws_,
                                               ushort_t* __restrict__ wpack,
                                               const int* __restrict__ src, const int* __restrict__ dst,
                                               u32* __restrict__ binbuf, int* __restrict__ gcur,
                                               int cvtBlocks) {
    __shared__ int hist[NBUK];
    __shared__ int excl[NBUK];
    __shared__ int cur[NBUK];
    __shared__ int gbase[NBUK];
    __shared__ int tmp[256];
    __shared__ u32 pairs[EPB];
    __shared__ unsigned char bukid[EPB];

    int b = blockIdx.x, t = threadIdx.x;
    if (b < cvtBlocks) {
        int base = (b * 256 + t) * 4;
        float4 v = *(const float4*)&x[base];
        uint2 pk;
        pk.x = cvtpk(v.x, v.y);
        pk.y = cvtpk(v.z, v.w);
        *(uint2*)&hbf[base] = pk;
        return;
    }
    b -= cvtBlocks;
    if (b < NL * 4) {
        if (t < 64) {
            int mat = b & 3, layer = b >> 2;
            const float* W = ((mat == 0) ? Wq : (mat == 1) ? Wk : (mat == 2) ? Wv : Ws_) + layer * DD * DD;
#pragma unroll
            for (int ct = 0; ct < 4; ct++)
#pragma unroll
                for (int ks = 0; ks < 2; ks++)
#pragma unroll
                    for (int j = 0; j < 8; j++) {
                        float v = W[(ks * 32 + (t >> 4) * 8 + j) * DD + ct * 16 + (t & 15)];
                        wpack[((size_t)(b * 8 + ct * 2 + ks)) * 512 + t * 8 + j] = f2bf(v);
                    }
        }
        return;
    }
    b -= NL * 4;   // bin block index
    int e0 = b * EPB;
    int totvalid = NE - e0; if (totvalid > EPB) totvalid = EPB;

    for (int i = t; i < NBUK; i += 256) hist[i] = 0;
    __syncthreads();

    int mysrc[8], mydst[8];
#pragma unroll
    for (int i = 0; i < 8; i++) {
        int e = e0 + i * 256 + t;
        bool v = e < NE;
        mysrc[i] = v ? src[e] : -1;
        mydst[i] = v ? dst[e] : -1;
        if (v) atomicAdd(&hist[mydst[i] >> 9], 1);
    }
    __syncthreads();

    int v = (t < NBUK) ? hist[t] : 0;
    tmp[t] = v;
    __syncthreads();
#pragma unroll
    for (int off = 1; off < 256; off <<= 1) {
        int a = (t >= off) ? tmp[t - off] : 0;
        __syncthreads();
        tmp[t] += a;
        __syncthreads();
    }
    if (t < NBUK) { excl[t] = tmp[t] - v; cur[t] = tmp[t] - v; }
    __syncthreads();

#pragma unroll
    for (int i = 0; i < 8; i++) {
        if (mydst[i] >= 0) {
            int bb = mydst[i] >> 9;
            int p = atomicAdd(&cur[bb], 1);
            pairs[p] = ((u32)(mydst[i] & 511) << 17) | (u32)mysrc[i];
            bukid[p] = (unsigned char)bb;
        }
    }
    if (t < NBUK && v > 0) gbase[t] = atomicAdd(&gcur[t], v);
    __syncthreads();

    for (int i = t; i < totvalid; i += 256) {
        int bb = bukid[i];
        int idx = gbase[bb] + (i - excl[bb]);
        if (idx < BCAP) binbuf[(size_t)bb * BCAP + idx] = pairs[i];
    }
}

// ---------------- csr_k: CSR finalize + degree-class histogram ----------------

__global__ __launch_bounds__(256) void csr_k(const u32* __restrict__ binbuf,
                                             const int* __restrict__ gcur,
                                             int* __restrict__ rowstart,
                                             int* __restrict__ csr_src,
                                             int* __restrict__ gdh) {
    __shared__ u32 pairs[BCAP];
    __shared__ int csrb[BCAP];
    __shared__ int deg[512];
    __shared__ int excl[512];
    __shared__ int cur[512];
    __shared__ int tmp[512];
    __shared__ int bt[256];
    __shared__ int ch[NDC];
    int b = blockIdx.x;
    int t = threadIdx.x;

    int bv = 0;
    if (t < NBUK) { bv = gcur[t]; if (bv > BCAP) bv = BCAP; }
    bt[t] = bv;
    __syncthreads();
#pragma unroll
    for (int off = 1; off < 256; off <<= 1) {
        int a = (t >= off) ? bt[t - off] : 0;
        __syncthreads();
        bt[t] += a;
        __syncthreads();
    }
    int base = (b == 0) ? 0 : bt[b - 1];
    int T = bt[b] - base;
    if (b == 0 && t == 0) rowstart[NN] = bt[NBUK - 1];
    int nbase = b << 9;

    for (int i = t; i < 512; i += 256) deg[i] = 0;
    if (t < NDC) ch[t] = 0;
    for (int i = t; i < T; i += 256) pairs[i] = binbuf[(size_t)b * BCAP + i];
    __syncthreads();
    for (int i = t; i < T; i += 256) atomicAdd(&deg[pairs[i] >> 17], 1);
    __syncthreads();

    for (int i = t; i < 512; i += 256) {
        if (nbase + i < NN) {
            int d = deg[i]; if (d > NDC - 1) d = NDC - 1;
            atomicAdd(&ch[d], 1);
        }
    }

    int v0 = deg[t], v1 = deg[t + 256];
    tmp[t] = v0; tmp[t + 256] = v1;
    __syncthreads();
#pragma unroll
    for (int off = 1; off < 512; off <<= 1) {
        int a0 = (t >= off) ? tmp[t - off] : 0;
        int i1 = t + 256;
        int a1 = (i1 >= off) ? tmp[i1 - off] : 0;
        __syncthreads();
        tmp[t] += a0; tmp[i1] += a1;
        __syncthreads();
    }
    excl[t] = tmp[t] - v0; excl[t + 256] = tmp[t + 256] - v1;
    cur[t] = excl[t]; cur[t + 256] = excl[t + 256];
    if (t < NDC && ch[t]) atomicAdd(&gdh[t], ch[t]);
    __syncthreads();

    for (int i = t; i < 512; i += 256) {
        int n = nbase + i;
        if (n < NN) rowstart[n] = base + excl[i];
    }

    for (int i = t; i < T; i += 256) {
        u32 p = pairs[i];
        int pos = atomicAdd(&cur[p >> 17], 1);
        csrb[pos] = (int)(p & 0x1FFFFu);
    }
    __syncthreads();
    for (int i = t; i < T; i += 256) csr_src[base + i] = csrb[i];
}

// ---------------- degree sort: scan -> perm ----------------

__global__ __launch_bounds__(64) void dscan_k(const int* __restrict__ gdh,
                                              int* __restrict__ gdcur) {
    int t = threadIdx.x;
    int v = gdh[t];
    int inc = v;
#pragma unroll
    for (int off = 1; off < NDC; off <<= 1) {
        int u = __shfl_up(inc, off);
        if (t >= off) inc += u;
    }
    gdcur[t] = inc - v;
}

__global__ __launch_bounds__(256) void dperm_k(const int* __restrict__ rowstart,
                                               int* __restrict__ gdcur,
                                               int* __restrict__ perm) {
    __shared__ int h[NDC];
    __shared__ int cur[NDC];
    int t = threadIdx.x;
    if (t < NDC) h[t] = 0;
    __syncthreads();
    int n0 = blockIdx.x * 1024;
    int myd[4];
#pragma unroll
    for (int i = 0; i < 4; i++) {
        int n = n0 + i * 256 + t;
        myd[i] = -1;
        if (n < NN) {
            int d = rowstart[n + 1] - rowstart[n];
            if (d > NDC - 1) d = NDC - 1;
            myd[i] = d;
            atomicAdd(&h[d], 1);
        }
    }
    __syncthreads();
    if (t < NDC) cur[t] = h[t] ? atomicAdd(&gdcur[t], h[t]) : 0;
    __syncthreads();
#pragma unroll
    for (int i = 0; i < 4; i++) {
        if (myd[i] >= 0) {
            int pos = atomicAdd(&cur[myd[i]], 1);
            perm[pos] = n0 + i * 256 + t;
        }
    }
}

// ---------------- fused 4-matrix MFMA GEMM, swapped operands ----------------

__global__ __launch_bounds__(256) void gemm4_k(const ushort_t* __restrict__ hbf,
                                               const ushort_t* __restrict__ wpl,
                                               const float* __restrict__ bq_, const float* __restrict__ bk_,
                                               const float* __restrict__ bv_, const float* __restrict__ bs_,
                                               ushort_t* __restrict__ qo, unsigned char* __restrict__ kv8,
                                               ushort_t* __restrict__ so) {
    int t = threadIdx.x;
    int lane = t & 63, wv = t >> 6;
    int ln = lane & 15, lq = lane >> 4;
    int rowbase = blockIdx.x * 64;

    const float* bsel = (wv == 0) ? bq_ : (wv == 1) ? bk_ : (wv == 2) ? bv_ : bs_;
    ushort_t* osel    = (wv == 0) ? qo : so;
    int kvoff = (wv == 1) ? 0 : 64;

    short8v wfrag[4][2];
#pragma unroll
    for (int ct = 0; ct < 4; ct++)
#pragma unroll
        for (int ks = 0; ks < 2; ks++)
            wfrag[ct][ks] = *(const short8v*)&wpl[((size_t)(wv * 8 + ct * 2 + ks)) * 512 + lane * 8];

    float4 bias[4];
#pragma unroll
    for (int ct = 0; ct < 4; ct++) bias[ct] = *(const float4*)&bsel[ct * 16 + lq * 4];

#pragma unroll
    for (int rt = 0; rt < 4; rt++) {
        int grow = rowbase + rt * 16 + ln;
        bool rv = grow < NN;
        int gr = rv ? grow : NN - 1;
        short8v h0 = *(const short8v*)&hbf[(size_t)gr * DD + lq * 8];
        short8v h1 = *(const short8v*)&hbf[(size_t)gr * DD + 32 + lq * 8];
#pragma unroll
        for (int ct = 0; ct < 4; ct++) {
            f32x4 acc;
            acc[0] = bias[ct].x; acc[1] = bias[ct].y; acc[2] = bias[ct].z; acc[3] = bias[ct].w;
            acc = __builtin_amdgcn_mfma_f32_16x16x32_bf16(wfrag[ct][0], h0, acc, 0, 0, 0);
            acc = __builtin_amdgcn_mfma_f32_16x16x32_bf16(wfrag[ct][1], h1, acc, 0, 0, 0);
            if (rv) {
                if (wv == 1 || wv == 2) {
                    int pk8 = __builtin_amdgcn_cvt_pk_fp8_f32(acc[0], acc[1], 0, false);
                    pk8 = __builtin_amdgcn_cvt_pk_fp8_f32(acc[2], acc[3], pk8, true);
                    *(u32*)&kv8[(size_t)grow * 128 + kvoff + ct * 16 + lq * 4] = (u32)pk8;
                } else {
                    uint2 pk;
                    pk.x = cvtpk(acc[0], acc[1]);
                    pk.y = cvtpk(acc[2], acc[3]);
                    *(uint2*)&osel[(size_t)grow * DD + ct * 16 + lq * 4] = pk;
                }
            }
        }
    }
}

// ---------------- aggregate: two-level decoupled pipeline ----------------
// csr indices prefetched 4 iterations ahead (si queue); k/v gathers issued
// using an index that arrived 2 iterations ago; edge processed 2 iterations
// after its k/v issue. No same-iteration dependent load chains.

#define SCLOG2E 0.18033688011112042f  // 0.125 * log2(e)

__global__ __launch_bounds__(256) void agg_k(const ushort_t* __restrict__ qb,
                                             const unsigned char* __restrict__ kv8,
                                             const ushort_t* __restrict__ skb,
                                             const int* __restrict__ rowstart,
                                             const int* __restrict__ csr_src,
                                             const int* __restrict__ perm,
                                             ushort_t* __restrict__ hout) {
    int wv = threadIdx.x >> 6, lane = threadIdx.x & 63;
    int g = lane >> 3, j = lane & 7, sub = g & 1;
    int slot = blockIdx.x * 16 + wv * 4 + (g >> 1);
    if (slot >= NN) return;
    int nid = perm[(NN - 1) - slot];     // longest-first scheduling
    int r0 = rowstart[nid];
    int r1 = rowstart[nid + 1];

    u32x4 qa = *(const u32x4*)(qb + ((u32)nid << 6) + ((u32)j << 3));
    f32x2 q0 = bfpair(qa.x), q1 = bfpair(qa.y), q2 = bfpair(qa.z), q3 = bfpair(qa.w);

    float m = -1.0e38f, se = 0.f;
    f32x2 a0 = {0.f, 0.f}, a1 = {0.f, 0.f}, a2 = {0.f, 0.f}, a3 = {0.f, 0.f};

    int clampE = r1 - 1; if (clampE < 0) clampE = 0;
    int e = r0 + sub;
    // si queue: indices for edges e, e+2, e+4, e+6
    int si0 = csr_src[e     < clampE ? e     : clampE];
    int si1 = csr_src[e + 2 < clampE ? e + 2 : clampE];
    int si2 = csr_src[e + 4 < clampE ? e + 4 : clampE];
    int si3 = csr_src[e + 6 < clampE ? e + 6 : clampE];
    // kv queue: data for e (k0,v0) and e+2 (k1,v1)
    uint2 k0 = *(const uint2*)(kv8 + (size_t)si0 * 128 + 8 * j);
    uint2 v0 = *(const uint2*)(kv8 + (size_t)si0 * 128 + 64 + 8 * j);
    uint2 k1 = *(const uint2*)(kv8 + (size_t)si1 * 128 + 8 * j);
    uint2 v1 = *(const uint2*)(kv8 + (size_t)si1 * 128 + 64 + 8 * j);

    while (__ballot(e < r1)) {
        // issue csr for e+8 (independent)
        int e8 = e + 8;
        int sn = csr_src[e8 < clampE ? e8 : clampE];
        // issue kv for e+4 using si2 (arrived: loaded 2 iterations ago)
        uint2 k2 = *(const uint2*)(kv8 + (size_t)si2 * 128 + 8 * j);
        uint2 v2 = *(const uint2*)(kv8 + (size_t)si2 * 128 + 64 + 8 * j);

        // process edge e with k0/v0 (arrived: issued 2 iterations ago)
        f32x2 dp2 = q0 * f8pair<false>(k0.x);
        dp2 += q1 * f8pair<true >(k0.x);
        dp2 += q2 * f8pair<false>(k0.y);
        dp2 += q3 * f8pair<true >(k0.y);
        float dp = sum8(dp2.x + dp2.y);

        float w = 0.f;
        if (e < r1) {
            float sc = dp * SCLOG2E;
            if (sc <= m + 11.5f) { w = exp2f(sc - m); }
            else {
                float cc = exp2f(m - sc);
                se *= cc; a0 *= cc; a1 *= cc; a2 *= cc; a3 *= cc;
                m = sc; w = 1.f;
            }
        }
        se += w;
        a0 += f8pair<false>(v0.x) * w;
        a1 += f8pair<true >(v0.x) * w;
        a2 += f8pair<false>(v0.y) * w;
        a3 += f8pair<true >(v0.y) * w;

        e += 2;
        si0 = si1; si1 = si2; si2 = si3; si3 = sn;
        k0 = k1; v0 = v1; k1 = k2; v1 = v2;
    }

    float M = fmaxf(m, __shfl_xor(m, 8));
    float cc = exp2f(m - M);
    se *= cc; a0 *= cc; a1 *= cc; a2 *= cc; a3 *= cc;
    se += __shfl_xor(se, 8);
    a0.x += __shfl_xor(a0.x, 8); a0.y += __shfl_xor(a0.y, 8);
    a1.x += __shfl_xor(a1.x, 8); a1.y += __shfl_xor(a1.y, 8);
    a2.x += __shfl_xor(a2.x, 8); a2.y += __shfl_xor(a2.y, 8);
    a3.x += __shfl_xor(a3.x, 8); a3.y += __shfl_xor(a3.y, 8);

    if (sub == 0) {
        float inv = 1.0f / (se + 1e-16f);
        u32x4 sk = *(const u32x4*)(skb + ((u32)nid << 6) + ((u32)j << 3));
        f32x2 o0 = a0 * inv + bfpair(sk.x);
        f32x2 o1 = a1 * inv + bfpair(sk.y);
        f32x2 o2 = a2 * inv + bfpair(sk.z);
        f32x2 o3 = a3 * inv + bfpair(sk.w);
        u32x4 pk;
        pk.x = cvtpk(fmaxf(o0.x, 0.f), fmaxf(o0.y, 0.f));
        pk.y = cvtpk(fmaxf(o1.x, 0.f), fmaxf(o1.y, 0.f));
        pk.z = cvtpk(fmaxf(o2.x, 0.f), fmaxf(o2.y, 0.f));
        pk.w = cvtpk(fmaxf(o3.x, 0.f), fmaxf(o3.y, 0.f));
        *(u32x4*)(hout + ((u32)nid << 6) + ((u32)j << 3)) = pk;
    }
}

// ---------------- global add pool ----------------

#define POOL_ROWS 128

__global__ __launch_bounds__(256) void pool_k(const ushort_t* __restrict__ h,
                                              const int* __restrict__ batch,
                                              float* __restrict__ pooled) {
    int i0 = blockIdx.x * POOL_ROWS;
    int i1 = i0 + POOL_ROWS; if (i1 > NN) i1 = NN;
    int lane = threadIdx.x & 63;
    int wv = threadIdx.x >> 6;
    float acc = 0.f;
    int gcur = -1;
    for (int i = i0 + wv; i < i1; i += 4) {
        int gi = batch[i];
        if (gi != gcur) {
            if (gcur >= 0) atomicAdd(&pooled[gcur * DD + lane], acc);
            gcur = gi; acc = 0.f;
        }
        unsigned u = ((unsigned)h[(size_t)i * DD + lane]) << 16;
        acc += __builtin_bit_cast(float, u);
    }
    if (gcur >= 0) atomicAdd(&pooled[gcur * DD + lane], acc);
}

// ---------------- head ----------------

__global__ __launch_bounds__(64) void head_k(const float* __restrict__ pooled2,
                                             const float* __restrict__ W1,
                                             const float* __restrict__ b1,
                                             const float* __restrict__ W2,
                                             const float* __restrict__ b2,
                                             float* __restrict__ out) {
    int g = blockIdx.x;
    int c = threadIdx.x;
    __shared__ float pg[64], p[64];
    pg[c] = pooled2[g * DD + c];
    __syncthreads();
    float a = b1[c];
#pragma unroll 8
    for (int kk = 0; kk < 64; kk++) a += pg[kk] * W1[kk * DD + c];
    p[c] = fmaxf(a, 0.f);
    __syncthreads();
    if (c < 10) {
        float o = b2[c];
#pragma unroll 8
        for (int kk = 0; kk < 64; kk++) o += p[kk] * W2[kk * 10 + c];
        out[g * 10 + c] = o;
    }
}

// ---------------- launch ----------------

extern "C" void kernel_launch(void* const* d_in, const int* in_sizes, int n_in,
                              void* d_out, int out_size, void* d_ws, size_t ws_size,
                              hipStream_t stream) {
    const float* x    = (const float*)d_in[0];
    const int*   ei   = (const int*)d_in[1];
    const int*   batch= (const int*)d_in[2];
    const float* Wq   = (const float*)d_in[3];
    const float* bq   = (const float*)d_in[4];
    const float* Wk   = (const float*)d_in[5];
    const float* bk   = (const float*)d_in[6];
    const float* Wv   = (const float*)d_in[7];
    const float* bv   = (const float*)d_in[8];
    const float* Wsp  = (const float*)d_in[9];
    const float* bsp  = (const float*)d_in[10];
    const float* W1   = (const float*)d_in[11];
    const float* b1   = (const float*)d_in[12];
    const float* W2   = (const float*)d_in[13];
    const float* b2   = (const float*)d_in[14];
    float* out = (float*)d_out;
    float* pooled = out + NG * 10;

    const int* srcv = ei;
    const int* dstv = ei + NE;

    const size_t NEL = (size_t)NN * DD;
    ushort_t* hbf = (ushort_t*)d_ws;                 // [NN][64] bf16
    ushort_t* qb  = hbf + NEL;
    ushort_t* skb = qb  + NEL;
    unsigned char* kv8 = (unsigned char*)(skb + NEL); // [NN][128] fp8 k|v
    u32* binbuf   = (u32*)(kv8 + (size_t)NN * 128);  // [NBUK*BCAP]
    int* gcur     = (int*)(binbuf + (size_t)NBUK * BCAP);
    int* gdh      = gcur + NBUK;                     // [NDC]
    int* gdcur    = gdh + NDC;                       // [NDC]
    int* rowstart = gdcur + NDC;                     // [NN+1]
    int* csr_src  = rowstart + (NN + 1);             // [NE]
    int* perm     = csr_src + NE;                    // [NN]
    ushort_t* wpack = (ushort_t*)(perm + NN);        // 12*4096 bf16

    int totOut = NG * 10 + NL * NG * DD;
    int cvtBlocks = (int)(NEL / 4 / 256);            // 6250 (exact)
    int zeroBlocks = (totOut + 255) / 256;           // 102

    zero_k<<<zeroBlocks, 256, 0, stream>>>(out, totOut, gcur, gdh);
    fused_k<<<cvtBlocks + NL * 4 + NBLK, 256, 0, stream>>>(
        x, hbf, Wq, Wk, Wv, Wsp, wpack, srcv, dstv, binbuf, gcur, cvtBlocks);
    csr_k<<<NBUK, 256, 0, stream>>>(binbuf, gcur, rowstart, csr_src, gdh);
    dscan_k<<<1, 64, 0, stream>>>(gdh, gdcur);
    dperm_k<<<(NN + 1023) / 1024, 256, 0, stream>>>(rowstart, gdcur, perm);

    int gtiles = (NN + 63) / 64;
    int poolblocks = (NN + POOL_ROWS - 1) / POOL_ROWS;
    for (int l = 0; l < NL; l++) {
        gemm4_k<<<gtiles, 256, 0, stream>>>(hbf, wpack + (size_t)l * 4 * 8 * 512,
                                            bq + l * DD, bk + l * DD, bv + l * DD, bsp + l * DD,
                                            qb, kv8, skb);
        agg_k<<<(NN + 15) / 16, 256, 0, stream>>>(qb, kv8, skb, rowstart, csr_src, perm, hbf);
        pool_k<<<poolblocks, 256, 0, stream>>>(hbf, batch, pooled + l * NG * DD);
    }
    head_k<<<NG, 64, 0, stream>>>(pooled + 2 * NG * DD, W1, b1, W2, b2, out);
}

// Round 14
// 236.310 us; speedup vs baseline: 1.4340x; 1.0323x over previous
//
#include <hip/hip_runtime.h>
#include <hip/hip_bf16.h>
#include <math.h>

#define NN 100000
#define NE 1000000
#define DD 64
#define NG 128
#define NL 3

#define NBUK 196
#define EPB 2048
#define NBLK ((NE + EPB - 1) / EPB)
#define BCAP 6144
#define NDC 64
#define POOL_ROWS 128

typedef unsigned short ushort_t;
typedef unsigned int u32;
typedef __attribute__((ext_vector_type(8))) short short8v;
typedef __attribute__((ext_vector_type(2))) float f32x2;
typedef __attribute__((ext_vector_type(4))) float f32x4;
typedef __attribute__((ext_vector_type(4))) unsigned int u32x4;

__device__ __forceinline__ ushort_t f2bf(float f) {
    __hip_bfloat16 h = __float2bfloat16(f);
    return *reinterpret_cast<ushort_t*>(&h);
}
__device__ __forceinline__ unsigned cvtpk(float lo, float hi) {
    unsigned r;
    asm("v_cvt_pk_bf16_f32 %0, %1, %2" : "=v"(r) : "v"(lo), "v"(hi));
    return r;
}
__device__ __forceinline__ f32x2 bfpair(u32 u) {
    f32x2 r;
    r.x = __builtin_bit_cast(float, u << 16);
    r.y = __builtin_bit_cast(float, u & 0xffff0000u);
    return r;
}
template <bool HI>
__device__ __forceinline__ f32x2 f8pair(u32 u) {
    return __builtin_amdgcn_cvt_pk_f32_fp8(u, HI);
}
__device__ __forceinline__ float sum8(float x) {
    int v = __builtin_bit_cast(int, x);
    x += __builtin_bit_cast(float, __builtin_amdgcn_update_dpp(0, v, 0xB1, 0xF, 0xF, true));
    v = __builtin_bit_cast(int, x);
    x += __builtin_bit_cast(float, __builtin_amdgcn_update_dpp(0, v, 0x4E, 0xF, 0xF, true));
    v = __builtin_bit_cast(int, x);
    x += __builtin_bit_cast(float, __builtin_amdgcn_update_dpp(0, v, 0x141, 0xF, 0xF, true));
    return x;
}

// ---------------- zero: gcur + gdh (must precede fused_k) ----------------

__global__ __launch_bounds__(256) void zero_k(int* __restrict__ gcur, int* __restrict__ gdh) {
    if (blockIdx.x == 0 && threadIdx.x < NBUK) gcur[threadIdx.x] = 0;
    if (blockIdx.x == 1 && threadIdx.x < NDC) gdh[threadIdx.x] = 0;
}

// ---------------- fused: cvt + packw + bin + out-zero ----------------

__global__ __launch_bounds__(256) void fused_k(const float* __restrict__ x, ushort_t* __restrict__ hbf,
                                               const float* __restrict__ Wq, const float* __restrict__ Wk,
                                               const float* __restrict__ Wv, const float* __restrict__ Ws_,
                                               ushort_t* __restrict__ wpack,
                                               const int* __restrict__ src, const int* __restrict__ dst,
                                               u32* __restrict__ binbuf, int* __restrict__ gcur,
                                               float* __restrict__ out, int totOut,
                                               int cvtBlocks) {
    __shared__ int hist[NBUK];
    __shared__ int excl[NBUK];
    __shared__ int cur[NBUK];
    __shared__ int gbase[NBUK];
    __shared__ int tmp[256];
    __shared__ u32 pairs[EPB];
    __shared__ unsigned char bukid[EPB];

    int b = blockIdx.x, t = threadIdx.x;
    if (b < cvtBlocks) {
        int base = (b * 256 + t) * 4;
        float4 v = *(const float4*)&x[base];
        uint2 pk;
        pk.x = cvtpk(v.x, v.y);
        pk.y = cvtpk(v.z, v.w);
        *(uint2*)&hbf[base] = pk;
        return;
    }
    b -= cvtBlocks;
    if (b < NL * 4) {
        if (t < 64) {
            int mat = b & 3, layer = b >> 2;
            const float* W = ((mat == 0) ? Wq : (mat == 1) ? Wk : (mat == 2) ? Wv : Ws_) + layer * DD * DD;
#pragma unroll
            for (int ct = 0; ct < 4; ct++)
#pragma unroll
                for (int ks = 0; ks < 2; ks++)
#pragma unroll
                    for (int j = 0; j < 8; j++) {
                        float v = W[(ks * 32 + (t >> 4) * 8 + j) * DD + ct * 16 + (t & 15)];
                        wpack[((size_t)(b * 8 + ct * 2 + ks)) * 512 + t * 8 + j] = f2bf(v);
                    }
        }
        return;
    }
    b -= NL * 4;
    if (b >= NBLK) {            // out-zero blocks
        int i = (b - NBLK) * 256 + t;
        if (i < totOut) out[i] = 0.f;
        return;
    }
    // bin block
    int e0 = b * EPB;
    int totvalid = NE - e0; if (totvalid > EPB) totvalid = EPB;

    for (int i = t; i < NBUK; i += 256) hist[i] = 0;
    __syncthreads();

    int mysrc[8], mydst[8];
#pragma unroll
    for (int i = 0; i < 8; i++) {
        int e = e0 + i * 256 + t;
        bool v = e < NE;
        mysrc[i] = v ? src[e] : -1;
        mydst[i] = v ? dst[e] : -1;
        if (v) atomicAdd(&hist[mydst[i] >> 9], 1);
    }
    __syncthreads();

    int v = (t < NBUK) ? hist[t] : 0;
    tmp[t] = v;
    __syncthreads();
#pragma unroll
    for (int off = 1; off < 256; off <<= 1) {
        int a = (t >= off) ? tmp[t - off] : 0;
        __syncthreads();
        tmp[t] += a;
        __syncthreads();
    }
    if (t < NBUK) { excl[t] = tmp[t] - v; cur[t] = tmp[t] - v; }
    __syncthreads();

#pragma unroll
    for (int i = 0; i < 8; i++) {
        if (mydst[i] >= 0) {
            int bb = mydst[i] >> 9;
            int p = atomicAdd(&cur[bb], 1);
            pairs[p] = ((u32)(mydst[i] & 511) << 17) | (u32)mysrc[i];
            bukid[p] = (unsigned char)bb;
        }
    }
    if (t < NBUK && v > 0) gbase[t] = atomicAdd(&gcur[t], v);
    __syncthreads();

    for (int i = t; i < totvalid; i += 256) {
        int bb = bukid[i];
        int idx = gbase[bb] + (i - excl[bb]);
        if (idx < BCAP) binbuf[(size_t)bb * BCAP + idx] = pairs[i];
    }
}

// ---------------- csr_k: CSR finalize + degree-class histogram ----------------

__global__ __launch_bounds__(256) void csr_k(const u32* __restrict__ binbuf,
                                             const int* __restrict__ gcur,
                                             int* __restrict__ rowstart,
                                             int* __restrict__ csr_src,
                                             int* __restrict__ gdh) {
    __shared__ u32 pairs[BCAP];
    __shared__ int csrb[BCAP];
    __shared__ int deg[512];
    __shared__ int excl[512];
    __shared__ int cur[512];
    __shared__ int tmp[512];
    __shared__ int bt[256];
    __shared__ int ch[NDC];
    int b = blockIdx.x;
    int t = threadIdx.x;

    int bv = 0;
    if (t < NBUK) { bv = gcur[t]; if (bv > BCAP) bv = BCAP; }
    bt[t] = bv;
    __syncthreads();
#pragma unroll
    for (int off = 1; off < 256; off <<= 1) {
        int a = (t >= off) ? bt[t - off] : 0;
        __syncthreads();
        bt[t] += a;
        __syncthreads();
    }
    int base = (b == 0) ? 0 : bt[b - 1];
    int T = bt[b] - base;
    if (b == 0 && t == 0) rowstart[NN] = bt[NBUK - 1];
    int nbase = b << 9;

    for (int i = t; i < 512; i += 256) deg[i] = 0;
    if (t < NDC) ch[t] = 0;
    for (int i = t; i < T; i += 256) pairs[i] = binbuf[(size_t)b * BCAP + i];
    __syncthreads();
    for (int i = t; i < T; i += 256) atomicAdd(&deg[pairs[i] >> 17], 1);
    __syncthreads();

    for (int i = t; i < 512; i += 256) {
        if (nbase + i < NN) {
            int d = deg[i]; if (d > NDC - 1) d = NDC - 1;
            atomicAdd(&ch[d], 1);
        }
    }

    int v0 = deg[t], v1 = deg[t + 256];
    tmp[t] = v0; tmp[t + 256] = v1;
    __syncthreads();
#pragma unroll
    for (int off = 1; off < 512; off <<= 1) {
        int a0 = (t >= off) ? tmp[t - off] : 0;
        int i1 = t + 256;
        int a1 = (i1 >= off) ? tmp[i1 - off] : 0;
        __syncthreads();
        tmp[t] += a0; tmp[i1] += a1;
        __syncthreads();
    }
    excl[t] = tmp[t] - v0; excl[t + 256] = tmp[t + 256] - v1;
    cur[t] = excl[t]; cur[t + 256] = excl[t + 256];
    if (t < NDC && ch[t]) atomicAdd(&gdh[t], ch[t]);
    __syncthreads();

    for (int i = t; i < 512; i += 256) {
        int n = nbase + i;
        if (n < NN) rowstart[n] = base + excl[i];
    }

    for (int i = t; i < T; i += 256) {
        u32 p = pairs[i];
        int pos = atomicAdd(&cur[p >> 17], 1);
        csrb[pos] = (int)(p & 0x1FFFFu);
    }
    __syncthreads();
    for (int i = t; i < T; i += 256) csr_src[base + i] = csrb[i];
}

// ---------------- degree sort: scan -> perm ----------------

__global__ __launch_bounds__(64) void dscan_k(const int* __restrict__ gdh,
                                              int* __restrict__ gdcur) {
    int t = threadIdx.x;
    int v = gdh[t];
    int inc = v;
#pragma unroll
    for (int off = 1; off < NDC; off <<= 1) {
        int u = __shfl_up(inc, off);
        if (t >= off) inc += u;
    }
    gdcur[t] = inc - v;
}

__global__ __launch_bounds__(256) void dperm_k(const int* __restrict__ rowstart,
                                               int* __restrict__ gdcur,
                                               int* __restrict__ perm) {
    __shared__ int h[NDC];
    __shared__ int cur[NDC];
    int t = threadIdx.x;
    if (t < NDC) h[t] = 0;
    __syncthreads();
    int n0 = blockIdx.x * 1024;
    int myd[4];
#pragma unroll
    for (int i = 0; i < 4; i++) {
        int n = n0 + i * 256 + t;
        myd[i] = -1;
        if (n < NN) {
            int d = rowstart[n + 1] - rowstart[n];
            if (d > NDC - 1) d = NDC - 1;
            myd[i] = d;
            atomicAdd(&h[d], 1);
        }
    }
    __syncthreads();
    if (t < NDC) cur[t] = h[t] ? atomicAdd(&gdcur[t], h[t]) : 0;
    __syncthreads();
#pragma unroll
    for (int i = 0; i < 4; i++) {
        if (myd[i] >= 0) {
            int pos = atomicAdd(&cur[myd[i]], 1);
            perm[pos] = n0 + i * 256 + t;
        }
    }
}

// ---------------- pool body (shared by fused gemm+pool and tail pool) ----------------

__device__ __forceinline__ void pool_body(const ushort_t* __restrict__ h,
                                          const int* __restrict__ batch,
                                          float* __restrict__ pooled, int pb) {
    int i0 = pb * POOL_ROWS;
    int i1 = i0 + POOL_ROWS; if (i1 > NN) i1 = NN;
    int lane = threadIdx.x & 63;
    int wv = threadIdx.x >> 6;
    float acc = 0.f;
    int gc = -1;
    for (int i = i0 + wv; i < i1; i += 4) {
        int gi = batch[i];
        if (gi != gc) {
            if (gc >= 0) atomicAdd(&pooled[gc * DD + lane], acc);
            gc = gi; acc = 0.f;
        }
        unsigned u = ((unsigned)h[(size_t)i * DD + lane]) << 16;
        acc += __builtin_bit_cast(float, u);
    }
    if (gc >= 0) atomicAdd(&pooled[gc * DD + lane], acc);
}

// ---------------- fused 4-matrix MFMA GEMM (+ previous layer pool) ----------------

__global__ __launch_bounds__(256) void gemm4pool_k(const ushort_t* __restrict__ hbf,
                                                   const ushort_t* __restrict__ wpl,
                                                   const float* __restrict__ bq_, const float* __restrict__ bk_,
                                                   const float* __restrict__ bv_, const float* __restrict__ bs_,
                                                   ushort_t* __restrict__ qo, unsigned char* __restrict__ kv8,
                                                   ushort_t* __restrict__ so,
                                                   const int* __restrict__ batch,
                                                   float* __restrict__ pooledPrev, int gtiles) {
    int blk = blockIdx.x;
    if (blk >= gtiles) {
        pool_body(hbf, batch, pooledPrev, blk - gtiles);
        return;
    }
    int t = threadIdx.x;
    int lane = t & 63, wv = t >> 6;
    int ln = lane & 15, lq = lane >> 4;
    int rowbase = blk * 64;

    const float* bsel = (wv == 0) ? bq_ : (wv == 1) ? bk_ : (wv == 2) ? bv_ : bs_;
    ushort_t* osel    = (wv == 0) ? qo : so;
    int kvoff = (wv == 1) ? 0 : 64;

    short8v wfrag[4][2];
#pragma unroll
    for (int ct = 0; ct < 4; ct++)
#pragma unroll
        for (int ks = 0; ks < 2; ks++)
            wfrag[ct][ks] = *(const short8v*)&wpl[((size_t)(wv * 8 + ct * 2 + ks)) * 512 + lane * 8];

    float4 bias[4];
#pragma unroll
    for (int ct = 0; ct < 4; ct++) bias[ct] = *(const float4*)&bsel[ct * 16 + lq * 4];

#pragma unroll
    for (int rt = 0; rt < 4; rt++) {
        int grow = rowbase + rt * 16 + ln;
        bool rv = grow < NN;
        int gr = rv ? grow : NN - 1;
        short8v h0 = *(const short8v*)&hbf[(size_t)gr * DD + lq * 8];
        short8v h1 = *(const short8v*)&hbf[(size_t)gr * DD + 32 + lq * 8];
#pragma unroll
        for (int ct = 0; ct < 4; ct++) {
            f32x4 acc;
            acc[0] = bias[ct].x; acc[1] = bias[ct].y; acc[2] = bias[ct].z; acc[3] = bias[ct].w;
            acc = __builtin_amdgcn_mfma_f32_16x16x32_bf16(wfrag[ct][0], h0, acc, 0, 0, 0);
            acc = __builtin_amdgcn_mfma_f32_16x16x32_bf16(wfrag[ct][1], h1, acc, 0, 0, 0);
            if (rv) {
                if (wv == 1 || wv == 2) {
                    int pk8 = __builtin_amdgcn_cvt_pk_fp8_f32(acc[0], acc[1], 0, false);
                    pk8 = __builtin_amdgcn_cvt_pk_fp8_f32(acc[2], acc[3], pk8, true);
                    *(u32*)&kv8[(size_t)grow * 128 + kvoff + ct * 16 + lq * 4] = (u32)pk8;
                } else {
                    uint2 pk;
                    pk.x = cvtpk(acc[0], acc[1]);
                    pk.y = cvtpk(acc[2], acc[3]);
                    *(uint2*)&osel[(size_t)grow * DD + ct * 16 + lq * 4] = pk;
                }
            }
        }
    }
}

// ---------------- aggregate: 2-edge pairs per group, decoupled pipeline ----------------
// Group sub processes edge pair (e, e+1), stride 4. si pairs loaded 2 iters
// ahead; kv pairs issued 2 iters ahead using arrived indices.

#define SCLOG2E 0.18033688011112042f  // 0.125 * log2(e)

__global__ __launch_bounds__(256) void agg_k(const ushort_t* __restrict__ qb,
                                             const unsigned char* __restrict__ kv8,
                                             const ushort_t* __restrict__ skb,
                                             const int* __restrict__ rowstart,
                                             const int* __restrict__ csr_src,
                                             const int* __restrict__ perm,
                                             ushort_t* __restrict__ hout) {
    int wv = threadIdx.x >> 6, lane = threadIdx.x & 63;
    int g = lane >> 3, j = lane & 7, sub = g & 1;
    int slot = blockIdx.x * 16 + wv * 4 + (g >> 1);
    if (slot >= NN) return;
    int nid = perm[(NN - 1) - slot];     // longest-first
    int r0 = rowstart[nid];
    int r1 = rowstart[nid + 1];

    u32x4 qa = *(const u32x4*)(qb + ((u32)nid << 6) + ((u32)j << 3));
    f32x2 q0 = bfpair(qa.x), q1 = bfpair(qa.y), q2 = bfpair(qa.z), q3 = bfpair(qa.w);

    float m = -1.0e38f, se = 0.f;
    f32x2 a0 = {0.f, 0.f}, a1 = {0.f, 0.f}, a2 = {0.f, 0.f}, a3 = {0.f, 0.f};

    int clampE = r1 - 1; if (clampE < 0) clampE = 0;
    int e = r0 + sub * 2;
    // si pairs for kv-issue: sC (pair e+8, use this iter), sD (pair e+12, in flight)
    int sA0 = csr_src[e     < clampE ? e     : clampE];
    int sA1 = csr_src[e + 1 < clampE ? e + 1 : clampE];
    int sB0 = csr_src[e + 4 < clampE ? e + 4 : clampE];
    int sB1 = csr_src[e + 5 < clampE ? e + 5 : clampE];
    int sC0 = csr_src[e + 8 < clampE ? e + 8 : clampE];
    int sC1 = csr_src[e + 9 < clampE ? e + 9 : clampE];
    int sD0 = csr_src[e + 12 < clampE ? e + 12 : clampE];
    int sD1 = csr_src[e + 13 < clampE ? e + 13 : clampE];
    // kv for pairs A (process now+2) and B
    uint2 kA0 = *(const uint2*)(kv8 + (size_t)sA0 * 128 + 8 * j);
    uint2 vA0 = *(const uint2*)(kv8 + (size_t)sA0 * 128 + 64 + 8 * j);
    uint2 kA1 = *(const uint2*)(kv8 + (size_t)sA1 * 128 + 8 * j);
    uint2 vA1 = *(const uint2*)(kv8 + (size_t)sA1 * 128 + 64 + 8 * j);
    uint2 kB0 = *(const uint2*)(kv8 + (size_t)sB0 * 128 + 8 * j);
    uint2 vB0 = *(const uint2*)(kv8 + (size_t)sB0 * 128 + 64 + 8 * j);
    uint2 kB1 = *(const uint2*)(kv8 + (size_t)sB1 * 128 + 8 * j);
    uint2 vB1 = *(const uint2*)(kv8 + (size_t)sB1 * 128 + 64 + 8 * j);

    while (__ballot(e < r1)) {
        // csr for pair e+16 (independent)
        int e16 = e + 16;
        int sE0 = csr_src[e16     < clampE ? e16     : clampE];
        int sE1 = csr_src[e16 + 1 < clampE ? e16 + 1 : clampE];
        // kv for pair C (indices arrived 2 iters ago)
        uint2 kC0 = *(const uint2*)(kv8 + (size_t)sC0 * 128 + 8 * j);
        uint2 vC0 = *(const uint2*)(kv8 + (size_t)sC0 * 128 + 64 + 8 * j);
        uint2 kC1 = *(const uint2*)(kv8 + (size_t)sC1 * 128 + 8 * j);
        uint2 vC1 = *(const uint2*)(kv8 + (size_t)sC1 * 128 + 64 + 8 * j);

        // process pair A: edges e, e+1 (two independent dot/reduce chains)
        f32x2 d0 = q0 * f8pair<false>(kA0.x);
        d0 += q1 * f8pair<true >(kA0.x);
        d0 += q2 * f8pair<false>(kA0.y);
        d0 += q3 * f8pair<true >(kA0.y);
        f32x2 d1 = q0 * f8pair<false>(kA1.x);
        d1 += q1 * f8pair<true >(kA1.x);
        d1 += q2 * f8pair<false>(kA1.y);
        d1 += q3 * f8pair<true >(kA1.y);
        float dp0 = sum8(d0.x + d0.y);
        float dp1 = sum8(d1.x + d1.y);

        bool act0 = e < r1, act1 = e + 1 < r1;
        float sc0 = dp0 * SCLOG2E, sc1 = dp1 * SCLOG2E;
        float s0a = act0 ? sc0 : -1.0e38f;
        float s1a = act1 ? sc1 : -1.0e38f;
        float pm = fmaxf(s0a, s1a);
        float w0 = 0.f, w1 = 0.f;
        if (pm > -1.0e37f) {
            if (pm <= m + 11.5f) {
                if (act0) w0 = exp2f(sc0 - m);
                if (act1) w1 = exp2f(sc1 - m);
            } else {
                float cc = exp2f(m - pm);
                se *= cc; a0 *= cc; a1 *= cc; a2 *= cc; a3 *= cc;
                m = pm;
                if (act0) w0 = exp2f(sc0 - pm);
                if (act1) w1 = exp2f(sc1 - pm);
            }
        }
        se += w0 + w1;
        a0 += f8pair<false>(vA0.x) * w0 + f8pair<false>(vA1.x) * w1;
        a1 += f8pair<true >(vA0.x) * w0 + f8pair<true >(vA1.x) * w1;
        a2 += f8pair<false>(vA0.y) * w0 + f8pair<false>(vA1.y) * w1;
        a3 += f8pair<true >(vA0.y) * w0 + f8pair<true >(vA1.y) * w1;

        e += 4;
        sC0 = sD0; sC1 = sD1; sD0 = sE0; sD1 = sE1;
        kA0 = kB0; vA0 = vB0; kA1 = kB1; vA1 = vB1;
        kB0 = kC0; vB0 = vC0; kB1 = kC1; vB1 = vC1;
    }

    // combine the node's two groups (xor8)
    float M = fmaxf(m, __shfl_xor(m, 8));
    float cc = exp2f(m - M);
    se *= cc; a0 *= cc; a1 *= cc; a2 *= cc; a3 *= cc;
    se += __shfl_xor(se, 8);
    a0.x += __shfl_xor(a0.x, 8); a0.y += __shfl_xor(a0.y, 8);
    a1.x += __shfl_xor(a1.x, 8); a1.y += __shfl_xor(a1.y, 8);
    a2.x += __shfl_xor(a2.x, 8); a2.y += __shfl_xor(a2.y, 8);
    a3.x += __shfl_xor(a3.x, 8); a3.y += __shfl_xor(a3.y, 8);

    if (sub == 0) {
        float inv = 1.0f / (se + 1e-16f);
        u32x4 sk = *(const u32x4*)(skb + ((u32)nid << 6) + ((u32)j << 3));
        f32x2 o0 = a0 * inv + bfpair(sk.x);
        f32x2 o1 = a1 * inv + bfpair(sk.y);
        f32x2 o2 = a2 * inv + bfpair(sk.z);
        f32x2 o3 = a3 * inv + bfpair(sk.w);
        u32x4 pk;
        pk.x = cvtpk(fmaxf(o0.x, 0.f), fmaxf(o0.y, 0.f));
        pk.y = cvtpk(fmaxf(o1.x, 0.f), fmaxf(o1.y, 0.f));
        pk.z = cvtpk(fmaxf(o2.x, 0.f), fmaxf(o2.y, 0.f));
        pk.w = cvtpk(fmaxf(o3.x, 0.f), fmaxf(o3.y, 0.f));
        *(u32x4*)(hout + ((u32)nid << 6) + ((u32)j << 3)) = pk;
    }
}

// ---------------- standalone pool (last layer) ----------------

__global__ __launch_bounds__(256) void pool_k(const ushort_t* __restrict__ h,
                                              const int* __restrict__ batch,
                                              float* __restrict__ pooled) {
    pool_body(h, batch, pooled, blockIdx.x);
}

// ---------------- head ----------------

__global__ __launch_bounds__(64) void head_k(const float* __restrict__ pooled2,
                                             const float* __restrict__ W1,
                                             const float* __restrict__ b1,
                                             const float* __restrict__ W2,
                                             const float* __restrict__ b2,
                                             float* __restrict__ out) {
    int g = blockIdx.x;
    int c = threadIdx.x;
    __shared__ float pg[64], p[64];
    pg[c] = pooled2[g * DD + c];
    __syncthreads();
    float a = b1[c];
#pragma unroll 8
    for (int kk = 0; kk < 64; kk++) a += pg[kk] * W1[kk * DD + c];
    p[c] = fmaxf(a, 0.f);
    __syncthreads();
    if (c < 10) {
        float o = b2[c];
#pragma unroll 8
        for (int kk = 0; kk < 64; kk++) o += p[kk] * W2[kk * 10 + c];
        out[g * 10 + c] = o;
    }
}

// ---------------- launch ----------------

extern "C" void kernel_launch(void* const* d_in, const int* in_sizes, int n_in,
                              void* d_out, int out_size, void* d_ws, size_t ws_size,
                              hipStream_t stream) {
    const float* x    = (const float*)d_in[0];
    const int*   ei   = (const int*)d_in[1];
    const int*   batch= (const int*)d_in[2];
    const float* Wq   = (const float*)d_in[3];
    const float* bq   = (const float*)d_in[4];
    const float* Wk   = (const float*)d_in[5];
    const float* bk   = (const float*)d_in[6];
    const float* Wv   = (const float*)d_in[7];
    const float* bv   = (const float*)d_in[8];
    const float* Wsp  = (const float*)d_in[9];
    const float* bsp  = (const float*)d_in[10];
    const float* W1   = (const float*)d_in[11];
    const float* b1   = (const float*)d_in[12];
    const float* W2   = (const float*)d_in[13];
    const float* b2   = (const float*)d_in[14];
    float* out = (float*)d_out;
    float* pooled = out + NG * 10;

    const int* srcv = ei;
    const int* dstv = ei + NE;

    const size_t NEL = (size_t)NN * DD;
    ushort_t* hbf = (ushort_t*)d_ws;                 // [NN][64] bf16
    ushort_t* qb  = hbf + NEL;
    ushort_t* skb = qb  + NEL;
    unsigned char* kv8 = (unsigned char*)(skb + NEL); // [NN][128] fp8 k|v
    u32* binbuf   = (u32*)(kv8 + (size_t)NN * 128);  // [NBUK*BCAP]
    int* gcur     = (int*)(binbuf + (size_t)NBUK * BCAP);
    int* gdh      = gcur + NBUK;                     // [NDC]
    int* gdcur    = gdh + NDC;                       // [NDC]
    int* rowstart = gdcur + NDC;                     // [NN+1]
    int* csr_src  = rowstart + (NN + 1);             // [NE]
    int* perm     = csr_src + NE;                    // [NN]
    ushort_t* wpack = (ushort_t*)(perm + NN);        // 12*4096 bf16

    int totOut = NG * 10 + NL * NG * DD;
    int cvtBlocks = (int)(NEL / 4 / 256);            // 6250 (exact)
    int zeroBlocks = (totOut + 255) / 256;           // 102

    zero_k<<<2, 256, 0, stream>>>(gcur, gdh);
    fused_k<<<cvtBlocks + NL * 4 + NBLK + zeroBlocks, 256, 0, stream>>>(
        x, hbf, Wq, Wk, Wv, Wsp, wpack, srcv, dstv, binbuf, gcur, out, totOut, cvtBlocks);
    csr_k<<<NBUK, 256, 0, stream>>>(binbuf, gcur, rowstart, csr_src, gdh);
    dscan_k<<<1, 64, 0, stream>>>(gdh, gdcur);
    dperm_k<<<(NN + 1023) / 1024, 256, 0, stream>>>(rowstart, gdcur, perm);

    int gtiles = (NN + 63) / 64;
    int poolblocks = (NN + POOL_ROWS - 1) / POOL_ROWS;
    for (int l = 0; l < NL; l++) {
        int extra = (l > 0) ? poolblocks : 0;
        gemm4pool_k<<<gtiles + extra, 256, 0, stream>>>(
            hbf, wpack + (size_t)l * 4 * 8 * 512,
            bq + l * DD, bk + l * DD, bv + l * DD, bsp + l * DD,
            qb, kv8, skb, batch,
            (l > 0) ? (pooled + (l - 1) * NG * DD) : nullptr, gtiles);
        agg_k<<<(NN + 15) / 16, 256, 0, stream>>>(qb, kv8, skb, rowstart, csr_src, perm, hbf);
    }
    pool_k<<<poolblocks, 256, 0, stream>>>(hbf, batch, pooled + 2 * NG * DD);
    head_k<<<NG, 64, 0, stream>>>(pooled + 2 * NG * DD, W1, b1, W2, b2, out);
}

// Round 15
// 214.835 us; speedup vs baseline: 1.5773x; 1.1000x over previous
//
#include <hip/hip_runtime.h>
#include <hip/hip_bf16.h>
#include <math.h>

#define NN 100000
#define NE 1000000
#define DD 64
#define NG 128
#define NL 3

#define NBUK 196
#define EPB 2048
#define NBLK ((NE + EPB - 1) / EPB)
#define BCAP 6144
#define NDC 64
#define POOL_ROWS 128

typedef unsigned short ushort_t;
typedef unsigned int u32;
typedef __attribute__((ext_vector_type(8))) short short8v;
typedef __attribute__((ext_vector_type(2))) float f32x2;
typedef __attribute__((ext_vector_type(4))) float f32x4;
typedef __attribute__((ext_vector_type(4))) unsigned int u32x4;

__device__ __forceinline__ ushort_t f2bf(float f) {
    __hip_bfloat16 h = __float2bfloat16(f);
    return *reinterpret_cast<ushort_t*>(&h);
}
__device__ __forceinline__ unsigned cvtpk(float lo, float hi) {
    unsigned r;
    asm("v_cvt_pk_bf16_f32 %0, %1, %2" : "=v"(r) : "v"(lo), "v"(hi));
    return r;
}
__device__ __forceinline__ f32x2 bfpair(u32 u) {
    f32x2 r;
    r.x = __builtin_bit_cast(float, u << 16);
    r.y = __builtin_bit_cast(float, u & 0xffff0000u);
    return r;
}
template <bool HI>
__device__ __forceinline__ f32x2 f8pair(u32 u) {
    return __builtin_amdgcn_cvt_pk_f32_fp8(u, HI);
}
__device__ __forceinline__ float sum8(float x) {
    int v = __builtin_bit_cast(int, x);
    x += __builtin_bit_cast(float, __builtin_amdgcn_update_dpp(0, v, 0xB1, 0xF, 0xF, true));
    v = __builtin_bit_cast(int, x);
    x += __builtin_bit_cast(float, __builtin_amdgcn_update_dpp(0, v, 0x4E, 0xF, 0xF, true));
    v = __builtin_bit_cast(int, x);
    x += __builtin_bit_cast(float, __builtin_amdgcn_update_dpp(0, v, 0x141, 0xF, 0xF, true));
    return x;
}

// ---------------- zero: gcur + gdh ----------------

__global__ __launch_bounds__(256) void zero_k(int* __restrict__ gcur, int* __restrict__ gdh) {
    if (blockIdx.x == 0 && threadIdx.x < NBUK) gcur[threadIdx.x] = 0;
    if (blockIdx.x == 1 && threadIdx.x < NDC) gdh[threadIdx.x] = 0;
}

// ---------------- fused: cvt + packw + bin + out-zero ----------------

__global__ __launch_bounds__(256) void fused_k(const float* __restrict__ x, ushort_t* __restrict__ hbf,
                                               const float* __restrict__ Wq, const float* __restrict__ Wk,
                                               const float* __restrict__ Wv, const float* __restrict__ Ws_,
                                               ushort_t* __restrict__ wpack,
                                               const int* __restrict__ src, const int* __restrict__ dst,
                                               u32* __restrict__ binbuf, int* __restrict__ gcur,
                                               float* __restrict__ out, int totOut,
                                               int cvtBlocks) {
    __shared__ int hist[NBUK];
    __shared__ int excl[NBUK];
    __shared__ int cur[NBUK];
    __shared__ int gbase[NBUK];
    __shared__ int tmp[256];
    __shared__ u32 pairs[EPB];
    __shared__ unsigned char bukid[EPB];

    int b = blockIdx.x, t = threadIdx.x;
    if (b < cvtBlocks) {
        int base = (b * 256 + t) * 4;
        float4 v = *(const float4*)&x[base];
        uint2 pk;
        pk.x = cvtpk(v.x, v.y);
        pk.y = cvtpk(v.z, v.w);
        *(uint2*)&hbf[base] = pk;
        return;
    }
    b -= cvtBlocks;
    if (b < NL * 4) {
        if (t < 64) {
            int mat = b & 3, layer = b >> 2;
            const float* W = ((mat == 0) ? Wq : (mat == 1) ? Wk : (mat == 2) ? Wv : Ws_) + layer * DD * DD;
#pragma unroll
            for (int ct = 0; ct < 4; ct++)
#pragma unroll
                for (int ks = 0; ks < 2; ks++)
#pragma unroll
                    for (int j = 0; j < 8; j++) {
                        float v = W[(ks * 32 + (t >> 4) * 8 + j) * DD + ct * 16 + (t & 15)];
                        wpack[((size_t)(b * 8 + ct * 2 + ks)) * 512 + t * 8 + j] = f2bf(v);
                    }
        }
        return;
    }
    b -= NL * 4;
    if (b >= NBLK) {
        int i = (b - NBLK) * 256 + t;
        if (i < totOut) out[i] = 0.f;
        return;
    }
    int e0 = b * EPB;
    int totvalid = NE - e0; if (totvalid > EPB) totvalid = EPB;

    for (int i = t; i < NBUK; i += 256) hist[i] = 0;
    __syncthreads();

    int mysrc[8], mydst[8];
#pragma unroll
    for (int i = 0; i < 8; i++) {
        int e = e0 + i * 256 + t;
        bool v = e < NE;
        mysrc[i] = v ? src[e] : -1;
        mydst[i] = v ? dst[e] : -1;
        if (v) atomicAdd(&hist[mydst[i] >> 9], 1);
    }
    __syncthreads();

    int v = (t < NBUK) ? hist[t] : 0;
    tmp[t] = v;
    __syncthreads();
#pragma unroll
    for (int off = 1; off < 256; off <<= 1) {
        int a = (t >= off) ? tmp[t - off] : 0;
        __syncthreads();
        tmp[t] += a;
        __syncthreads();
    }
    if (t < NBUK) { excl[t] = tmp[t] - v; cur[t] = tmp[t] - v; }
    __syncthreads();

#pragma unroll
    for (int i = 0; i < 8; i++) {
        if (mydst[i] >= 0) {
            int bb = mydst[i] >> 9;
            int p = atomicAdd(&cur[bb], 1);
            pairs[p] = ((u32)(mydst[i] & 511) << 17) | (u32)mysrc[i];
            bukid[p] = (unsigned char)bb;
        }
    }
    if (t < NBUK && v > 0) gbase[t] = atomicAdd(&gcur[t], v);
    __syncthreads();

    for (int i = t; i < totvalid; i += 256) {
        int bb = bukid[i];
        int idx = gbase[bb] + (i - excl[bb]);
        if (idx < BCAP) binbuf[(size_t)bb * BCAP + idx] = pairs[i];
    }
}

// ---------------- csr_k: CSR finalize + degree-class histogram ----------------

__global__ __launch_bounds__(256) void csr_k(const u32* __restrict__ binbuf,
                                             const int* __restrict__ gcur,
                                             int* __restrict__ rowstart,
                                             int* __restrict__ csr_src,
                                             int* __restrict__ gdh) {
    __shared__ u32 pairs[BCAP];
    __shared__ int csrb[BCAP];
    __shared__ int deg[512];
    __shared__ int excl[512];
    __shared__ int cur[512];
    __shared__ int tmp[512];
    __shared__ int bt[256];
    __shared__ int ch[NDC];
    int b = blockIdx.x;
    int t = threadIdx.x;

    int bv = 0;
    if (t < NBUK) { bv = gcur[t]; if (bv > BCAP) bv = BCAP; }
    bt[t] = bv;
    __syncthreads();
#pragma unroll
    for (int off = 1; off < 256; off <<= 1) {
        int a = (t >= off) ? bt[t - off] : 0;
        __syncthreads();
        bt[t] += a;
        __syncthreads();
    }
    int base = (b == 0) ? 0 : bt[b - 1];
    int T = bt[b] - base;
    if (b == 0 && t == 0) rowstart[NN] = bt[NBUK - 1];
    int nbase = b << 9;

    for (int i = t; i < 512; i += 256) deg[i] = 0;
    if (t < NDC) ch[t] = 0;
    for (int i = t; i < T; i += 256) pairs[i] = binbuf[(size_t)b * BCAP + i];
    __syncthreads();
    for (int i = t; i < T; i += 256) atomicAdd(&deg[pairs[i] >> 17], 1);
    __syncthreads();

    for (int i = t; i < 512; i += 256) {
        if (nbase + i < NN) {
            int d = deg[i]; if (d > NDC - 1) d = NDC - 1;
            atomicAdd(&ch[d], 1);
        }
    }

    int v0 = deg[t], v1 = deg[t + 256];
    tmp[t] = v0; tmp[t + 256] = v1;
    __syncthreads();
#pragma unroll
    for (int off = 1; off < 512; off <<= 1) {
        int a0 = (t >= off) ? tmp[t - off] : 0;
        int i1 = t + 256;
        int a1 = (i1 >= off) ? tmp[i1 - off] : 0;
        __syncthreads();
        tmp[t] += a0; tmp[i1] += a1;
        __syncthreads();
    }
    excl[t] = tmp[t] - v0; excl[t + 256] = tmp[t + 256] - v1;
    cur[t] = excl[t]; cur[t + 256] = excl[t + 256];
    if (t < NDC && ch[t]) atomicAdd(&gdh[t], ch[t]);
    __syncthreads();

    for (int i = t; i < 512; i += 256) {
        int n = nbase + i;
        if (n < NN) rowstart[n] = base + excl[i];
    }

    for (int i = t; i < T; i += 256) {
        u32 p = pairs[i];
        int pos = atomicAdd(&cur[p >> 17], 1);
        csrb[pos] = (int)(p & 0x1FFFFu);
    }
    __syncthreads();
    for (int i = t; i < T; i += 256) csr_src[base + i] = csrb[i];
}

// ---------------- degree sort: scan -> perm ----------------

__global__ __launch_bounds__(64) void dscan_k(const int* __restrict__ gdh,
                                              int* __restrict__ gdcur) {
    int t = threadIdx.x;
    int v = gdh[t];
    int inc = v;
#pragma unroll
    for (int off = 1; off < NDC; off <<= 1) {
        int u = __shfl_up(inc, off);
        if (t >= off) inc += u;
    }
    gdcur[t] = inc - v;
}

__global__ __launch_bounds__(256) void dperm_k(const int* __restrict__ rowstart,
                                               int* __restrict__ gdcur,
                                               int* __restrict__ perm) {
    __shared__ int h[NDC];
    __shared__ int cur[NDC];
    int t = threadIdx.x;
    if (t < NDC) h[t] = 0;
    __syncthreads();
    int n0 = blockIdx.x * 1024;
    int myd[4];
#pragma unroll
    for (int i = 0; i < 4; i++) {
        int n = n0 + i * 256 + t;
        myd[i] = -1;
        if (n < NN) {
            int d = rowstart[n + 1] - rowstart[n];
            if (d > NDC - 1) d = NDC - 1;
            myd[i] = d;
            atomicAdd(&h[d], 1);
        }
    }
    __syncthreads();
    if (t < NDC) cur[t] = h[t] ? atomicAdd(&gdcur[t], h[t]) : 0;
    __syncthreads();
#pragma unroll
    for (int i = 0; i < 4; i++) {
        if (myd[i] >= 0) {
            int pos = atomicAdd(&cur[myd[i]], 1);
            perm[pos] = n0 + i * 256 + t;
        }
    }
}

// ---------------- pool body ----------------

__device__ __forceinline__ void pool_body(const ushort_t* __restrict__ h,
                                          const int* __restrict__ batch,
                                          float* __restrict__ pooled, int pb) {
    int i0 = pb * POOL_ROWS;
    int i1 = i0 + POOL_ROWS; if (i1 > NN) i1 = NN;
    int lane = threadIdx.x & 63;
    int wv = threadIdx.x >> 6;
    float acc = 0.f;
    int gc = -1;
    for (int i = i0 + wv; i < i1; i += 4) {
        int gi = batch[i];
        if (gi != gc) {
            if (gc >= 0) atomicAdd(&pooled[gc * DD + lane], acc);
            gc = gi; acc = 0.f;
        }
        unsigned u = ((unsigned)h[(size_t)i * DD + lane]) << 16;
        acc += __builtin_bit_cast(float, u);
    }
    if (gc >= 0) atomicAdd(&pooled[gc * DD + lane], acc);
}

// ---------------- fused 4-matrix MFMA GEMM (+ prev layer pool) ----------------
// LDS-staged outputs: per-wave tile staging -> full-row coalesced stores.
// bf16 tile: [16][72] ushorts (144B row stride, 16B-aligned);
// fp8 tile: [16][80] bytes (80B row stride, 16B-aligned).

__global__ __launch_bounds__(256) void gemm4pool_k(const ushort_t* __restrict__ hbf,
                                                   const ushort_t* __restrict__ wpl,
                                                   const float* __restrict__ bq_, const float* __restrict__ bk_,
                                                   const float* __restrict__ bv_, const float* __restrict__ bs_,
                                                   ushort_t* __restrict__ qo, unsigned char* __restrict__ kv8,
                                                   ushort_t* __restrict__ so,
                                                   const int* __restrict__ batch,
                                                   float* __restrict__ pooledPrev, int gtiles) {
    __shared__ char stage[4][2304];
    int blk = blockIdx.x;
    if (blk >= gtiles) {
        pool_body(hbf, batch, pooledPrev, blk - gtiles);
        return;
    }
    int t = threadIdx.x;
    int lane = t & 63, wv = t >> 6;
    int ln = lane & 15, lq = lane >> 4;
    int rowbase = blk * 64;
    char* st = stage[wv];
    bool isbf = (wv == 0) || (wv == 3);      // q / skip emit bf16; k/v emit fp8
    int kvoff = (wv == 1) ? 0 : 64;

    const float* bsel = (wv == 0) ? bq_ : (wv == 1) ? bk_ : (wv == 2) ? bv_ : bs_;
    ushort_t* osel    = (wv == 0) ? qo : so;

    short8v wfrag[4][2];
#pragma unroll
    for (int ct = 0; ct < 4; ct++)
#pragma unroll
        for (int ks = 0; ks < 2; ks++)
            wfrag[ct][ks] = *(const short8v*)&wpl[((size_t)(wv * 8 + ct * 2 + ks)) * 512 + lane * 8];

    float4 bias[4];
#pragma unroll
    for (int ct = 0; ct < 4; ct++) bias[ct] = *(const float4*)&bsel[ct * 16 + lq * 4];

#pragma unroll
    for (int rt = 0; rt < 4; rt++) {
        int grow0 = rowbase + rt * 16 + ln;
        int gr = grow0 < NN ? grow0 : NN - 1;
        short8v h0 = *(const short8v*)&hbf[(size_t)gr * DD + lq * 8];
        short8v h1 = *(const short8v*)&hbf[(size_t)gr * DD + 32 + lq * 8];
#pragma unroll
        for (int ct = 0; ct < 4; ct++) {
            f32x4 acc;
            acc[0] = bias[ct].x; acc[1] = bias[ct].y; acc[2] = bias[ct].z; acc[3] = bias[ct].w;
            acc = __builtin_amdgcn_mfma_f32_16x16x32_bf16(wfrag[ct][0], h0, acc, 0, 0, 0);
            acc = __builtin_amdgcn_mfma_f32_16x16x32_bf16(wfrag[ct][1], h1, acc, 0, 0, 0);
            if (isbf) {
                uint2 pk;
                pk.x = cvtpk(acc[0], acc[1]);
                pk.y = cvtpk(acc[2], acc[3]);
                *(uint2*)(st + ln * 144 + ct * 32 + lq * 8) = pk;
            } else {
                int pk8 = __builtin_amdgcn_cvt_pk_fp8_f32(acc[0], acc[1], 0, false);
                pk8 = __builtin_amdgcn_cvt_pk_fp8_f32(acc[2], acc[3], pk8, true);
                *(u32*)(st + ln * 80 + ct * 16 + lq * 4) = (u32)pk8;
            }
        }
        // readback + coalesced store (compiler inserts lgkmcnt waits for LDS deps)
        if (isbf) {
#pragma unroll
            for (int hh = 0; hh < 2; hh++) {
                int r = (lane >> 3) + 8 * hh;     // 0..15
                int c = lane & 7;                 // 16B chunk within 128B row
                u32x4 d = *(const u32x4*)(st + r * 144 + c * 16);
                int grow = rowbase + rt * 16 + r;
                if (grow < NN) *(u32x4*)&osel[(size_t)grow * DD + c * 8] = d;
            }
        } else {
            int r = lane >> 2;                    // 0..15
            int c = lane & 3;                     // 16B chunk within 64B half-row
            u32x4 d = *(const u32x4*)(st + r * 80 + c * 16);
            int grow = rowbase + rt * 16 + r;
            if (grow < NN) *(u32x4*)(kv8 + (size_t)grow * 128 + kvoff + c * 16) = d;
        }
    }
}

// ---------------- aggregate: 2-edge pairs per group, decoupled pipeline ----------------

#define SCLOG2E 0.18033688011112042f  // 0.125 * log2(e)

__global__ __launch_bounds__(256) void agg_k(const ushort_t* __restrict__ qb,
                                             const unsigned char* __restrict__ kv8,
                                             const ushort_t* __restrict__ skb,
                                             const int* __restrict__ rowstart,
                                             const int* __restrict__ csr_src,
                                             const int* __restrict__ perm,
                                             ushort_t* __restrict__ hout) {
    int wv = threadIdx.x >> 6, lane = threadIdx.x & 63;
    int g = lane >> 3, j = lane & 7, sub = g & 1;
    int slot = blockIdx.x * 16 + wv * 4 + (g >> 1);
    if (slot >= NN) return;
    int nid = perm[(NN - 1) - slot];     // longest-first
    int r0 = rowstart[nid];
    int r1 = rowstart[nid + 1];

    u32x4 qa = *(const u32x4*)(qb + ((u32)nid << 6) + ((u32)j << 3));
    f32x2 q0 = bfpair(qa.x), q1 = bfpair(qa.y), q2 = bfpair(qa.z), q3 = bfpair(qa.w);

    float m = -1.0e38f, se = 0.f;
    f32x2 a0 = {0.f, 0.f}, a1 = {0.f, 0.f}, a2 = {0.f, 0.f}, a3 = {0.f, 0.f};

    int clampE = r1 - 1; if (clampE < 0) clampE = 0;
    int e = r0 + sub * 2;
    int sA0 = csr_src[e     < clampE ? e     : clampE];
    int sA1 = csr_src[e + 1 < clampE ? e + 1 : clampE];
    int sB0 = csr_src[e + 4 < clampE ? e + 4 : clampE];
    int sB1 = csr_src[e + 5 < clampE ? e + 5 : clampE];
    int sC0 = csr_src[e + 8 < clampE ? e + 8 : clampE];
    int sC1 = csr_src[e + 9 < clampE ? e + 9 : clampE];
    int sD0 = csr_src[e + 12 < clampE ? e + 12 : clampE];
    int sD1 = csr_src[e + 13 < clampE ? e + 13 : clampE];
    uint2 kA0 = *(const uint2*)(kv8 + (size_t)sA0 * 128 + 8 * j);
    uint2 vA0 = *(const uint2*)(kv8 + (size_t)sA0 * 128 + 64 + 8 * j);
    uint2 kA1 = *(const uint2*)(kv8 + (size_t)sA1 * 128 + 8 * j);
    uint2 vA1 = *(const uint2*)(kv8 + (size_t)sA1 * 128 + 64 + 8 * j);
    uint2 kB0 = *(const uint2*)(kv8 + (size_t)sB0 * 128 + 8 * j);
    uint2 vB0 = *(const uint2*)(kv8 + (size_t)sB0 * 128 + 64 + 8 * j);
    uint2 kB1 = *(const uint2*)(kv8 + (size_t)sB1 * 128 + 8 * j);
    uint2 vB1 = *(const uint2*)(kv8 + (size_t)sB1 * 128 + 64 + 8 * j);

    while (__ballot(e < r1)) {
        int e16 = e + 16;
        int sE0 = csr_src[e16     < clampE ? e16     : clampE];
        int sE1 = csr_src[e16 + 1 < clampE ? e16 + 1 : clampE];
        uint2 kC0 = *(const uint2*)(kv8 + (size_t)sC0 * 128 + 8 * j);
        uint2 vC0 = *(const uint2*)(kv8 + (size_t)sC0 * 128 + 64 + 8 * j);
        uint2 kC1 = *(const uint2*)(kv8 + (size_t)sC1 * 128 + 8 * j);
        uint2 vC1 = *(const uint2*)(kv8 + (size_t)sC1 * 128 + 64 + 8 * j);

        f32x2 d0 = q0 * f8pair<false>(kA0.x);
        d0 += q1 * f8pair<true >(kA0.x);
        d0 += q2 * f8pair<false>(kA0.y);
        d0 += q3 * f8pair<true >(kA0.y);
        f32x2 d1 = q0 * f8pair<false>(kA1.x);
        d1 += q1 * f8pair<true >(kA1.x);
        d1 += q2 * f8pair<false>(kA1.y);
        d1 += q3 * f8pair<true >(kA1.y);
        float dp0 = sum8(d0.x + d0.y);
        float dp1 = sum8(d1.x + d1.y);

        bool act0 = e < r1, act1 = e + 1 < r1;
        float sc0 = dp0 * SCLOG2E, sc1 = dp1 * SCLOG2E;
        float s0a = act0 ? sc0 : -1.0e38f;
        float s1a = act1 ? sc1 : -1.0e38f;
        float pm = fmaxf(s0a, s1a);
        float w0 = 0.f, w1 = 0.f;
        if (pm > -1.0e37f) {
            if (pm <= m + 11.5f) {
                if (act0) w0 = exp2f(sc0 - m);
                if (act1) w1 = exp2f(sc1 - m);
            } else {
                float cc = exp2f(m - pm);
                se *= cc; a0 *= cc; a1 *= cc; a2 *= cc; a3 *= cc;
                m = pm;
                if (act0) w0 = exp2f(sc0 - pm);
                if (act1) w1 = exp2f(sc1 - pm);
            }
        }
        se += w0 + w1;
        a0 += f8pair<false>(vA0.x) * w0 + f8pair<false>(vA1.x) * w1;
        a1 += f8pair<true >(vA0.x) * w0 + f8pair<true >(vA1.x) * w1;
        a2 += f8pair<false>(vA0.y) * w0 + f8pair<false>(vA1.y) * w1;
        a3 += f8pair<true >(vA0.y) * w0 + f8pair<true >(vA1.y) * w1;

        e += 4;
        sC0 = sD0; sC1 = sD1; sD0 = sE0; sD1 = sE1;
        kA0 = kB0; vA0 = vB0; kA1 = kB1; vA1 = vB1;
        kB0 = kC0; vB0 = vC0; kB1 = kC1; vB1 = vC1;
    }

    float M = fmaxf(m, __shfl_xor(m, 8));
    float cc = exp2f(m - M);
    se *= cc; a0 *= cc; a1 *= cc; a2 *= cc; a3 *= cc;
    se += __shfl_xor(se, 8);
    a0.x += __shfl_xor(a0.x, 8); a0.y += __shfl_xor(a0.y, 8);
    a1.x += __shfl_xor(a1.x, 8); a1.y += __shfl_xor(a1.y, 8);
    a2.x += __shfl_xor(a2.x, 8); a2.y += __shfl_xor(a2.y, 8);
    a3.x += __shfl_xor(a3.x, 8); a3.y += __shfl_xor(a3.y, 8);

    if (sub == 0) {
        float inv = 1.0f / (se + 1e-16f);
        u32x4 sk = *(const u32x4*)(skb + ((u32)nid << 6) + ((u32)j << 3));
        f32x2 o0 = a0 * inv + bfpair(sk.x);
        f32x2 o1 = a1 * inv + bfpair(sk.y);
        f32x2 o2 = a2 * inv + bfpair(sk.z);
        f32x2 o3 = a3 * inv + bfpair(sk.w);
        u32x4 pk;
        pk.x = cvtpk(fmaxf(o0.x, 0.f), fmaxf(o0.y, 0.f));
        pk.y = cvtpk(fmaxf(o1.x, 0.f), fmaxf(o1.y, 0.f));
        pk.z = cvtpk(fmaxf(o2.x, 0.f), fmaxf(o2.y, 0.f));
        pk.w = cvtpk(fmaxf(o3.x, 0.f), fmaxf(o3.y, 0.f));
        *(u32x4*)(hout + ((u32)nid << 6) + ((u32)j << 3)) = pk;
    }
}

// ---------------- standalone pool (last layer) ----------------

__global__ __launch_bounds__(256) void pool_k(const ushort_t* __restrict__ h,
                                              const int* __restrict__ batch,
                                              float* __restrict__ pooled) {
    pool_body(h, batch, pooled, blockIdx.x);
}

// ---------------- head ----------------

__global__ __launch_bounds__(64) void head_k(const float* __restrict__ pooled2,
                                             const float* __restrict__ W1,
                                             const float* __restrict__ b1,
                                             const float* __restrict__ W2,
                                             const float* __restrict__ b2,
                                             float* __restrict__ out) {
    int g = blockIdx.x;
    int c = threadIdx.x;
    __shared__ float pg[64], p[64];
    pg[c] = pooled2[g * DD + c];
    __syncthreads();
    float a = b1[c];
#pragma unroll 8
    for (int kk = 0; kk < 64; kk++) a += pg[kk] * W1[kk * DD + c];
    p[c] = fmaxf(a, 0.f);
    __syncthreads();
    if (c < 10) {
        float o = b2[c];
#pragma unroll 8
        for (int kk = 0; kk < 64; kk++) o += p[kk] * W2[kk * 10 + c];
        out[g * 10 + c] = o;
    }
}

// ---------------- launch ----------------

extern "C" void kernel_launch(void* const* d_in, const int* in_sizes, int n_in,
                              void* d_out, int out_size, void* d_ws, size_t ws_size,
                              hipStream_t stream) {
    const float* x    = (const float*)d_in[0];
    const int*   ei   = (const int*)d_in[1];
    const int*   batch= (const int*)d_in[2];
    const float* Wq   = (const float*)d_in[3];
    const float* bq   = (const float*)d_in[4];
    const float* Wk   = (const float*)d_in[5];
    const float* bk   = (const float*)d_in[6];
    const float* Wv   = (const float*)d_in[7];
    const float* bv   = (const float*)d_in[8];
    const float* Wsp  = (const float*)d_in[9];
    const float* bsp  = (const float*)d_in[10];
    const float* W1   = (const float*)d_in[11];
    const float* b1   = (const float*)d_in[12];
    const float* W2   = (const float*)d_in[13];
    const float* b2   = (const float*)d_in[14];
    float* out = (float*)d_out;
    float* pooled = out + NG * 10;

    const int* srcv = ei;
    const int* dstv = ei + NE;

    const size_t NEL = (size_t)NN * DD;
    ushort_t* hbf = (ushort_t*)d_ws;
    ushort_t* qb  = hbf + NEL;
    ushort_t* skb = qb  + NEL;
    unsigned char* kv8 = (unsigned char*)(skb + NEL);
    u32* binbuf   = (u32*)(kv8 + (size_t)NN * 128);
    int* gcur     = (int*)(binbuf + (size_t)NBUK * BCAP);
    int* gdh      = gcur + NBUK;
    int* gdcur    = gdh + NDC;
    int* rowstart = gdcur + NDC;
    int* csr_src  = rowstart + (NN + 1);
    int* perm     = csr_src + NE;
    ushort_t* wpack = (ushort_t*)(perm + NN);

    int totOut = NG * 10 + NL * NG * DD;
    int cvtBlocks = (int)(NEL / 4 / 256);
    int zeroBlocks = (totOut + 255) / 256;

    zero_k<<<2, 256, 0, stream>>>(gcur, gdh);
    fused_k<<<cvtBlocks + NL * 4 + NBLK + zeroBlocks, 256, 0, stream>>>(
        x, hbf, Wq, Wk, Wv, Wsp, wpack, srcv, dstv, binbuf, gcur, out, totOut, cvtBlocks);
    csr_k<<<NBUK, 256, 0, stream>>>(binbuf, gcur, rowstart, csr_src, gdh);
    dscan_k<<<1, 64, 0, stream>>>(gdh, gdcur);
    dperm_k<<<(NN + 1023) / 1024, 256, 0, stream>>>(rowstart, gdcur, perm);

    int gtiles = (NN + 63) / 64;
    int poolblocks = (NN + POOL_ROWS - 1) / POOL_ROWS;
    for (int l = 0; l < NL; l++) {
        int extra = (l > 0) ? poolblocks : 0;
        gemm4pool_k<<<gtiles + extra, 256, 0, stream>>>(
            hbf, wpack + (size_t)l * 4 * 8 * 512,
            bq + l * DD, bk + l * DD, bv + l * DD, bsp + l * DD,
            qb, kv8, skb, batch,
            (l > 0) ? (pooled + (l - 1) * NG * DD) : nullptr, gtiles);
        agg_k<<<(NN + 15) / 16, 256, 0, stream>>>(qb, kv8, skb, rowstart, csr_src, perm, hbf);
    }
    pool_k<<<poolblocks, 256, 0, stream>>>(hbf, batch, pooled + 2 * NG * DD);
    head_k<<<NG, 64, 0, stream>>>(pooled + 2 * NG * DD, W1, b1, W2, b2, out);
}

// Round 16
// 205.638 us; speedup vs baseline: 1.6479x; 1.0447x over previous
//
#include <hip/hip_runtime.h>
#include <hip/hip_bf16.h>
#include <math.h>

#define NN 100000
#define NE 1000000
#define DD 64
#define NG 128
#define NL 3

#define NBUK 196
#define EPB 2048
#define NBLK ((NE + EPB - 1) / EPB)
#define BCAP 6144
#define NDC 64
#define POOL_ROWS 128
#define DPERM_BLOCKS ((NN + 1023) / 1024)

typedef unsigned short ushort_t;
typedef unsigned int u32;
typedef __attribute__((ext_vector_type(8))) short short8v;
typedef __attribute__((ext_vector_type(2))) float f32x2;
typedef __attribute__((ext_vector_type(4))) float f32x4;
typedef __attribute__((ext_vector_type(4))) unsigned int u32x4;

__device__ __forceinline__ ushort_t f2bf(float f) {
    __hip_bfloat16 h = __float2bfloat16(f);
    return *reinterpret_cast<ushort_t*>(&h);
}
__device__ __forceinline__ unsigned cvtpk(float lo, float hi) {
    unsigned r;
    asm("v_cvt_pk_bf16_f32 %0, %1, %2" : "=v"(r) : "v"(lo), "v"(hi));
    return r;
}
__device__ __forceinline__ f32x2 bfpair(u32 u) {
    f32x2 r;
    r.x = __builtin_bit_cast(float, u << 16);
    r.y = __builtin_bit_cast(float, u & 0xffff0000u);
    return r;
}
template <bool HI>
__device__ __forceinline__ f32x2 f8pair(u32 u) {
    return __builtin_amdgcn_cvt_pk_f32_fp8(u, HI);
}
__device__ __forceinline__ float sum8(float x) {
    int v = __builtin_bit_cast(int, x);
    x += __builtin_bit_cast(float, __builtin_amdgcn_update_dpp(0, v, 0xB1, 0xF, 0xF, true));
    v = __builtin_bit_cast(int, x);
    x += __builtin_bit_cast(float, __builtin_amdgcn_update_dpp(0, v, 0x4E, 0xF, 0xF, true));
    v = __builtin_bit_cast(int, x);
    x += __builtin_bit_cast(float, __builtin_amdgcn_update_dpp(0, v, 0x141, 0xF, 0xF, true));
    return x;
}

// ---------------- zero: gcur + gdh + gdcur ----------------

__global__ __launch_bounds__(256) void zero_k(int* __restrict__ gcur, int* __restrict__ gdh,
                                              int* __restrict__ gdcur) {
    if (blockIdx.x == 0 && threadIdx.x < NBUK) gcur[threadIdx.x] = 0;
    if (blockIdx.x == 1 && threadIdx.x < NDC) { gdh[threadIdx.x] = 0; gdcur[threadIdx.x] = 0; }
}

// ---------------- fused: packw + bin + out-zero ----------------

__global__ __launch_bounds__(256) void fused_k(const float* __restrict__ Wq, const float* __restrict__ Wk,
                                               const float* __restrict__ Wv, const float* __restrict__ Ws_,
                                               ushort_t* __restrict__ wpack,
                                               const int* __restrict__ src, const int* __restrict__ dst,
                                               u32* __restrict__ binbuf, int* __restrict__ gcur,
                                               float* __restrict__ out, int totOut) {
    __shared__ int hist[NBUK];
    __shared__ int excl[NBUK];
    __shared__ int cur[NBUK];
    __shared__ int gbase[NBUK];
    __shared__ int tmp[256];
    __shared__ u32 pairs[EPB];
    __shared__ unsigned char bukid[EPB];

    int b = blockIdx.x, t = threadIdx.x;
    if (b < NL * 4) {
        if (t < 64) {
            int mat = b & 3, layer = b >> 2;
            const float* W = ((mat == 0) ? Wq : (mat == 1) ? Wk : (mat == 2) ? Wv : Ws_) + layer * DD * DD;
#pragma unroll
            for (int ct = 0; ct < 4; ct++)
#pragma unroll
                for (int ks = 0; ks < 2; ks++)
#pragma unroll
                    for (int j = 0; j < 8; j++) {
                        float v = W[(ks * 32 + (t >> 4) * 8 + j) * DD + ct * 16 + (t & 15)];
                        wpack[((size_t)(b * 8 + ct * 2 + ks)) * 512 + t * 8 + j] = f2bf(v);
                    }
        }
        return;
    }
    b -= NL * 4;
    if (b >= NBLK) {
        int i = (b - NBLK) * 256 + t;
        if (i < totOut) out[i] = 0.f;
        return;
    }
    int e0 = b * EPB;
    int totvalid = NE - e0; if (totvalid > EPB) totvalid = EPB;

    for (int i = t; i < NBUK; i += 256) hist[i] = 0;
    __syncthreads();

    int mysrc[8], mydst[8];
#pragma unroll
    for (int i = 0; i < 8; i++) {
        int e = e0 + i * 256 + t;
        bool v = e < NE;
        mysrc[i] = v ? src[e] : -1;
        mydst[i] = v ? dst[e] : -1;
        if (v) atomicAdd(&hist[mydst[i] >> 9], 1);
    }
    __syncthreads();

    int v = (t < NBUK) ? hist[t] : 0;
    tmp[t] = v;
    __syncthreads();
#pragma unroll
    for (int off = 1; off < 256; off <<= 1) {
        int a = (t >= off) ? tmp[t - off] : 0;
        __syncthreads();
        tmp[t] += a;
        __syncthreads();
    }
    if (t < NBUK) { excl[t] = tmp[t] - v; cur[t] = tmp[t] - v; }
    __syncthreads();

#pragma unroll
    for (int i = 0; i < 8; i++) {
        if (mydst[i] >= 0) {
            int bb = mydst[i] >> 9;
            int p = atomicAdd(&cur[bb], 1);
            pairs[p] = ((u32)(mydst[i] & 511) << 17) | (u32)mysrc[i];
            bukid[p] = (unsigned char)bb;
        }
    }
    if (t < NBUK && v > 0) gbase[t] = atomicAdd(&gcur[t], v);
    __syncthreads();

    for (int i = t; i < totvalid; i += 256) {
        int bb = bukid[i];
        int idx = gbase[bb] + (i - excl[bb]);
        if (idx < BCAP) binbuf[(size_t)bb * BCAP + idx] = pairs[i];
    }
}

// ---------------- csr_k: CSR finalize + degree-class histogram ----------------

__global__ __launch_bounds__(256) void csr_k(const u32* __restrict__ binbuf,
                                             const int* __restrict__ gcur,
                                             int* __restrict__ rowstart,
                                             int* __restrict__ csr_src,
                                             int* __restrict__ gdh) {
    __shared__ u32 pairs[BCAP];
    __shared__ int csrb[BCAP];
    __shared__ int deg[512];
    __shared__ int excl[512];
    __shared__ int cur[512];
    __shared__ int tmp[512];
    __shared__ int bt[256];
    __shared__ int ch[NDC];
    int b = blockIdx.x;
    int t = threadIdx.x;

    int bv = 0;
    if (t < NBUK) { bv = gcur[t]; if (bv > BCAP) bv = BCAP; }
    bt[t] = bv;
    __syncthreads();
#pragma unroll
    for (int off = 1; off < 256; off <<= 1) {
        int a = (t >= off) ? bt[t - off] : 0;
        __syncthreads();
        bt[t] += a;
        __syncthreads();
    }
    int base = (b == 0) ? 0 : bt[b - 1];
    int T = bt[b] - base;
    if (b == 0 && t == 0) rowstart[NN] = bt[NBUK - 1];
    int nbase = b << 9;

    for (int i = t; i < 512; i += 256) deg[i] = 0;
    if (t < NDC) ch[t] = 0;
    for (int i = t; i < T; i += 256) pairs[i] = binbuf[(size_t)b * BCAP + i];
    __syncthreads();
    for (int i = t; i < T; i += 256) atomicAdd(&deg[pairs[i] >> 17], 1);
    __syncthreads();

    for (int i = t; i < 512; i += 256) {
        if (nbase + i < NN) {
            int d = deg[i]; if (d > NDC - 1) d = NDC - 1;
            atomicAdd(&ch[d], 1);
        }
    }

    int v0 = deg[t], v1 = deg[t + 256];
    tmp[t] = v0; tmp[t + 256] = v1;
    __syncthreads();
#pragma unroll
    for (int off = 1; off < 512; off <<= 1) {
        int a0 = (t >= off) ? tmp[t - off] : 0;
        int i1 = t + 256;
        int a1 = (i1 >= off) ? tmp[i1 - off] : 0;
        __syncthreads();
        tmp[t] += a0; tmp[i1] += a1;
        __syncthreads();
    }
    excl[t] = tmp[t] - v0; excl[t + 256] = tmp[t + 256] - v1;
    cur[t] = excl[t]; cur[t + 256] = excl[t + 256];
    if (t < NDC && ch[t]) atomicAdd(&gdh[t], ch[t]);
    __syncthreads();

    for (int i = t; i < 512; i += 256) {
        int n = nbase + i;
        if (n < NN) rowstart[n] = base + excl[i];
    }

    for (int i = t; i < T; i += 256) {
        u32 p = pairs[i];
        int pos = atomicAdd(&cur[p >> 17], 1);
        csrb[pos] = (int)(p & 0x1FFFFu);
    }
    __syncthreads();
    for (int i = t; i < T; i += 256) csr_src[base + i] = csrb[i];
}

// ---------------- dperm body: self-sufficient (local rescan of gdh) ----------------

__device__ __forceinline__ void dperm_body(const int* __restrict__ rowstart,
                                           const int* __restrict__ gdh,
                                           int* __restrict__ gdcur,
                                           int* __restrict__ perm, int pb) {
    __shared__ int h[NDC];
    __shared__ int cur[NDC];
    __shared__ int cbase[NDC];
    int t = threadIdx.x;
    if (t < NDC) {
        h[t] = 0;
        int v = gdh[t];
        int inc = v;
#pragma unroll
        for (int off = 1; off < NDC; off <<= 1) {
            int u = __shfl_up(inc, off);
            if (t >= off) inc += u;
        }
        cbase[t] = inc - v;
    }
    __syncthreads();
    int n0 = pb * 1024;
    int myd[4];
#pragma unroll
    for (int i = 0; i < 4; i++) {
        int n = n0 + i * 256 + t;
        myd[i] = -1;
        if (n < NN) {
            int d = rowstart[n + 1] - rowstart[n];
            if (d > NDC - 1) d = NDC - 1;
            myd[i] = d;
            atomicAdd(&h[d], 1);
        }
    }
    __syncthreads();
    if (t < NDC) cur[t] = h[t] ? (cbase[t] + atomicAdd(&gdcur[t], h[t])) : 0;
    __syncthreads();
#pragma unroll
    for (int i = 0; i < 4; i++) {
        if (myd[i] >= 0) {
            int pos = atomicAdd(&cur[myd[i]], 1);
            perm[pos] = n0 + i * 256 + t;
        }
    }
}

// ---------------- pool body ----------------

__device__ __forceinline__ void pool_body(const ushort_t* __restrict__ h,
                                          const int* __restrict__ batch,
                                          float* __restrict__ pooled, int pb) {
    int i0 = pb * POOL_ROWS;
    int i1 = i0 + POOL_ROWS; if (i1 > NN) i1 = NN;
    int lane = threadIdx.x & 63;
    int wv = threadIdx.x >> 6;
    float acc = 0.f;
    int gc = -1;
    for (int i = i0 + wv; i < i1; i += 4) {
        int gi = batch[i];
        if (gi != gc) {
            if (gc >= 0) atomicAdd(&pooled[gc * DD + lane], acc);
            gc = gi; acc = 0.f;
        }
        unsigned u = ((unsigned)h[(size_t)i * DD + lane]) << 16;
        acc += __builtin_bit_cast(float, u);
    }
    if (gc >= 0) atomicAdd(&pooled[gc * DD + lane], acc);
}

// ---------------- fused 4-matrix MFMA GEMM (+ tail: pool OR dperm) ----------------
// Layer 0 reads x directly as f32 (in-register cvtpk); layers 1,2 read bf16 hbf.

__global__ __launch_bounds__(256) void gemm4pool_k(const ushort_t* __restrict__ hbf,
                                                   const float* __restrict__ xf32,
                                                   const ushort_t* __restrict__ wpl,
                                                   const float* __restrict__ bq_, const float* __restrict__ bk_,
                                                   const float* __restrict__ bv_, const float* __restrict__ bs_,
                                                   ushort_t* __restrict__ qo, unsigned char* __restrict__ kv8,
                                                   ushort_t* __restrict__ so,
                                                   const int* __restrict__ batch,
                                                   float* __restrict__ pooledPrev, int gtiles, int tailMode,
                                                   const int* __restrict__ rowstart,
                                                   const int* __restrict__ gdh,
                                                   int* __restrict__ gdcur,
                                                   int* __restrict__ perm) {
    __shared__ char stage[4][2304];
    int blk = blockIdx.x;
    if (blk >= gtiles) {
        if (tailMode == 1) pool_body(hbf, batch, pooledPrev, blk - gtiles);
        else dperm_body(rowstart, gdh, gdcur, perm, blk - gtiles);
        return;
    }
    int t = threadIdx.x;
    int lane = t & 63, wv = t >> 6;
    int ln = lane & 15, lq = lane >> 4;
    int rowbase = blk * 64;
    char* st = stage[wv];
    bool isbf = (wv == 0) || (wv == 3);
    int kvoff = (wv == 1) ? 0 : 64;

    const float* bsel = (wv == 0) ? bq_ : (wv == 1) ? bk_ : (wv == 2) ? bv_ : bs_;
    ushort_t* osel    = (wv == 0) ? qo : so;

    short8v wfrag[4][2];
#pragma unroll
    for (int ct = 0; ct < 4; ct++)
#pragma unroll
        for (int ks = 0; ks < 2; ks++)
            wfrag[ct][ks] = *(const short8v*)&wpl[((size_t)(wv * 8 + ct * 2 + ks)) * 512 + lane * 8];

    float4 bias[4];
#pragma unroll
    for (int ct = 0; ct < 4; ct++) bias[ct] = *(const float4*)&bsel[ct * 16 + lq * 4];

#pragma unroll
    for (int rt = 0; rt < 4; rt++) {
        int grow0 = rowbase + rt * 16 + ln;
        int gr = grow0 < NN ? grow0 : NN - 1;
        short8v h0, h1;
        if (xf32) {
            float4 f0 = *(const float4*)&xf32[(size_t)gr * DD + lq * 8];
            float4 f1 = *(const float4*)&xf32[(size_t)gr * DD + lq * 8 + 4];
            float4 f2 = *(const float4*)&xf32[(size_t)gr * DD + 32 + lq * 8];
            float4 f3 = *(const float4*)&xf32[(size_t)gr * DD + 32 + lq * 8 + 4];
            u32x4 p0, p1;
            p0[0] = cvtpk(f0.x, f0.y); p0[1] = cvtpk(f0.z, f0.w);
            p0[2] = cvtpk(f1.x, f1.y); p0[3] = cvtpk(f1.z, f1.w);
            p1[0] = cvtpk(f2.x, f2.y); p1[1] = cvtpk(f2.z, f2.w);
            p1[2] = cvtpk(f3.x, f3.y); p1[3] = cvtpk(f3.z, f3.w);
            h0 = __builtin_bit_cast(short8v, p0);
            h1 = __builtin_bit_cast(short8v, p1);
        } else {
            h0 = *(const short8v*)&hbf[(size_t)gr * DD + lq * 8];
            h1 = *(const short8v*)&hbf[(size_t)gr * DD + 32 + lq * 8];
        }
#pragma unroll
        for (int ct = 0; ct < 4; ct++) {
            f32x4 acc;
            acc[0] = bias[ct].x; acc[1] = bias[ct].y; acc[2] = bias[ct].z; acc[3] = bias[ct].w;
            acc = __builtin_amdgcn_mfma_f32_16x16x32_bf16(wfrag[ct][0], h0, acc, 0, 0, 0);
            acc = __builtin_amdgcn_mfma_f32_16x16x32_bf16(wfrag[ct][1], h1, acc, 0, 0, 0);
            if (isbf) {
                uint2 pk;
                pk.x = cvtpk(acc[0], acc[1]);
                pk.y = cvtpk(acc[2], acc[3]);
                *(uint2*)(st + ln * 144 + ct * 32 + lq * 8) = pk;
            } else {
                int pk8 = __builtin_amdgcn_cvt_pk_fp8_f32(acc[0], acc[1], 0, false);
                pk8 = __builtin_amdgcn_cvt_pk_fp8_f32(acc[2], acc[3], pk8, true);
                *(u32*)(st + ln * 80 + ct * 16 + lq * 4) = (u32)pk8;
            }
        }
        if (isbf) {
#pragma unroll
            for (int hh = 0; hh < 2; hh++) {
                int r = (lane >> 3) + 8 * hh;
                int c = lane & 7;
                u32x4 d = *(const u32x4*)(st + r * 144 + c * 16);
                int grow = rowbase + rt * 16 + r;
                if (grow < NN) *(u32x4*)&osel[(size_t)grow * DD + c * 8] = d;
            }
        } else {
            int r = lane >> 2;
            int c = lane & 3;
            u32x4 d = *(const u32x4*)(st + r * 80 + c * 16);
            int grow = rowbase + rt * 16 + r;
            if (grow < NN) *(u32x4*)(kv8 + (size_t)grow * 128 + kvoff + c * 16) = d;
        }
    }
}

// ---------------- aggregate: 8 nodes/wave, 1 group/node, pair pipeline ----------------

#define SCLOG2E 0.18033688011112042f  // 0.125 * log2(e)

__global__ __launch_bounds__(256) void agg_k(const ushort_t* __restrict__ qb,
                                             const unsigned char* __restrict__ kv8,
                                             const ushort_t* __restrict__ skb,
                                             const int* __restrict__ rowstart,
                                             const int* __restrict__ csr_src,
                                             const int* __restrict__ perm,
                                             ushort_t* __restrict__ hout) {
    int wv = threadIdx.x >> 6, lane = threadIdx.x & 63;
    int g = lane >> 3, j = lane & 7;
    int slot = blockIdx.x * 32 + wv * 8 + g;
    if (slot >= NN) return;
    int nid = perm[(NN - 1) - slot];     // longest-first
    int r0 = rowstart[nid];
    int r1 = rowstart[nid + 1];

    u32x4 qa = *(const u32x4*)(qb + ((u32)nid << 6) + ((u32)j << 3));
    f32x2 q0 = bfpair(qa.x), q1 = bfpair(qa.y), q2 = bfpair(qa.z), q3 = bfpair(qa.w);

    float m = -1.0e38f, se = 0.f;
    f32x2 a0 = {0.f, 0.f}, a1 = {0.f, 0.f}, a2 = {0.f, 0.f}, a3 = {0.f, 0.f};

    int clampE = r1 - 1; if (clampE < 0) clampE = 0;
    int e = r0;
    int sA0 = csr_src[e     < clampE ? e     : clampE];
    int sA1 = csr_src[e + 1 < clampE ? e + 1 : clampE];
    int sB0 = csr_src[e + 2 < clampE ? e + 2 : clampE];
    int sB1 = csr_src[e + 3 < clampE ? e + 3 : clampE];
    int sC0 = csr_src[e + 4 < clampE ? e + 4 : clampE];
    int sC1 = csr_src[e + 5 < clampE ? e + 5 : clampE];
    int sD0 = csr_src[e + 6 < clampE ? e + 6 : clampE];
    int sD1 = csr_src[e + 7 < clampE ? e + 7 : clampE];
    uint2 kA0 = *(const uint2*)(kv8 + (size_t)sA0 * 128 + 8 * j);
    uint2 vA0 = *(const uint2*)(kv8 + (size_t)sA0 * 128 + 64 + 8 * j);
    uint2 kA1 = *(const uint2*)(kv8 + (size_t)sA1 * 128 + 8 * j);
    uint2 vA1 = *(const uint2*)(kv8 + (size_t)sA1 * 128 + 64 + 8 * j);
    uint2 kB0 = *(const uint2*)(kv8 + (size_t)sB0 * 128 + 8 * j);
    uint2 vB0 = *(const uint2*)(kv8 + (size_t)sB0 * 128 + 64 + 8 * j);
    uint2 kB1 = *(const uint2*)(kv8 + (size_t)sB1 * 128 + 8 * j);
    uint2 vB1 = *(const uint2*)(kv8 + (size_t)sB1 * 128 + 64 + 8 * j);

    while (__ballot(e < r1)) {
        int e8 = e + 8;
        int sE0 = csr_src[e8     < clampE ? e8     : clampE];
        int sE1 = csr_src[e8 + 1 < clampE ? e8 + 1 : clampE];
        uint2 kC0 = *(const uint2*)(kv8 + (size_t)sC0 * 128 + 8 * j);
        uint2 vC0 = *(const uint2*)(kv8 + (size_t)sC0 * 128 + 64 + 8 * j);
        uint2 kC1 = *(const uint2*)(kv8 + (size_t)sC1 * 128 + 8 * j);
        uint2 vC1 = *(const uint2*)(kv8 + (size_t)sC1 * 128 + 64 + 8 * j);

        f32x2 d0 = q0 * f8pair<false>(kA0.x);
        d0 += q1 * f8pair<true >(kA0.x);
        d0 += q2 * f8pair<false>(kA0.y);
        d0 += q3 * f8pair<true >(kA0.y);
        f32x2 d1 = q0 * f8pair<false>(kA1.x);
        d1 += q1 * f8pair<true >(kA1.x);
        d1 += q2 * f8pair<false>(kA1.y);
        d1 += q3 * f8pair<true >(kA1.y);
        float dp0 = sum8(d0.x + d0.y);
        float dp1 = sum8(d1.x + d1.y);

        bool act0 = e < r1, act1 = e + 1 < r1;
        float sc0 = dp0 * SCLOG2E, sc1 = dp1 * SCLOG2E;
        float s0a = act0 ? sc0 : -1.0e38f;
        float s1a = act1 ? sc1 : -1.0e38f;
        float pm = fmaxf(s0a, s1a);
        float w0 = 0.f, w1 = 0.f;
        if (pm > -1.0e37f) {
            if (pm <= m + 11.5f) {
                if (act0) w0 = exp2f(sc0 - m);
                if (act1) w1 = exp2f(sc1 - m);
            } else {
                float cc = exp2f(m - pm);
                se *= cc; a0 *= cc; a1 *= cc; a2 *= cc; a3 *= cc;
                m = pm;
                if (act0) w0 = exp2f(sc0 - pm);
                if (act1) w1 = exp2f(sc1 - pm);
            }
        }
        se += w0 + w1;
        a0 += f8pair<false>(vA0.x) * w0 + f8pair<false>(vA1.x) * w1;
        a1 += f8pair<true >(vA0.x) * w0 + f8pair<true >(vA1.x) * w1;
        a2 += f8pair<false>(vA0.y) * w0 + f8pair<false>(vA1.y) * w1;
        a3 += f8pair<true >(vA0.y) * w0 + f8pair<true >(vA1.y) * w1;

        e += 2;
        sC0 = sD0; sC1 = sD1; sD0 = sE0; sD1 = sE1;
        kA0 = kB0; vA0 = vB0; kA1 = kB1; vA1 = vB1;
        kB0 = kC0; vB0 = vC0; kB1 = kC1; vB1 = vC1;
    }

    // no cross-group combine: group == node
    float inv = 1.0f / (se + 1e-16f);
    u32x4 sk = *(const u32x4*)(skb + ((u32)nid << 6) + ((u32)j << 3));
    f32x2 o0 = a0 * inv + bfpair(sk.x);
    f32x2 o1 = a1 * inv + bfpair(sk.y);
    f32x2 o2 = a2 * inv + bfpair(sk.z);
    f32x2 o3 = a3 * inv + bfpair(sk.w);
    u32x4 pk;
    pk.x = cvtpk(fmaxf(o0.x, 0.f), fmaxf(o0.y, 0.f));
    pk.y = cvtpk(fmaxf(o1.x, 0.f), fmaxf(o1.y, 0.f));
    pk.z = cvtpk(fmaxf(o2.x, 0.f), fmaxf(o2.y, 0.f));
    pk.w = cvtpk(fmaxf(o3.x, 0.f), fmaxf(o3.y, 0.f));
    *(u32x4*)(hout + ((u32)nid << 6) + ((u32)j << 3)) = pk;
}

// ---------------- standalone pool (last layer) ----------------

__global__ __launch_bounds__(256) void pool_k(const ushort_t* __restrict__ h,
                                              const int* __restrict__ batch,
                                              float* __restrict__ pooled) {
    pool_body(h, batch, pooled, blockIdx.x);
}

// ---------------- head ----------------

__global__ __launch_bounds__(64) void head_k(const float* __restrict__ pooled2,
                                             const float* __restrict__ W1,
                                             const float* __restrict__ b1,
                                             const float* __restrict__ W2,
                                             const float* __restrict__ b2,
                                             float* __restrict__ out) {
    int g = blockIdx.x;
    int c = threadIdx.x;
    __shared__ float pg[64], p[64];
    pg[c] = pooled2[g * DD + c];
    __syncthreads();
    float a = b1[c];
#pragma unroll 8
    for (int kk = 0; kk < 64; kk++) a += pg[kk] * W1[kk * DD + c];
    p[c] = fmaxf(a, 0.f);
    __syncthreads();
    if (c < 10) {
        float o = b2[c];
#pragma unroll 8
        for (int kk = 0; kk < 64; kk++) o += p[kk] * W2[kk * 10 + c];
        out[g * 10 + c] = o;
    }
}

// ---------------- launch ----------------

extern "C" void kernel_launch(void* const* d_in, const int* in_sizes, int n_in,
                              void* d_out, int out_size, void* d_ws, size_t ws_size,
                              hipStream_t stream) {
    const float* x    = (const float*)d_in[0];
    const int*   ei   = (const int*)d_in[1];
    const int*   batch= (const int*)d_in[2];
    const float* Wq   = (const float*)d_in[3];
    const float* bq   = (const float*)d_in[4];
    const float* Wk   = (const float*)d_in[5];
    const float* bk   = (const float*)d_in[6];
    const float* Wv   = (const float*)d_in[7];
    const float* bv   = (const float*)d_in[8];
    const float* Wsp  = (const float*)d_in[9];
    const float* bsp  = (const float*)d_in[10];
    const float* W1   = (const float*)d_in[11];
    const float* b1   = (const float*)d_in[12];
    const float* W2   = (const float*)d_in[13];
    const float* b2   = (const float*)d_in[14];
    float* out = (float*)d_out;
    float* pooled = out + NG * 10;

    const int* srcv = ei;
    const int* dstv = ei + NE;

    const size_t NEL = (size_t)NN * DD;
    ushort_t* hbf = (ushort_t*)d_ws;                 // [NN][64] bf16 (written by agg)
    ushort_t* qb  = hbf + NEL;
    ushort_t* skb = qb  + NEL;
    unsigned char* kv8 = (unsigned char*)(skb + NEL);
    u32* binbuf   = (u32*)(kv8 + (size_t)NN * 128);
    int* gcur     = (int*)(binbuf + (size_t)NBUK * BCAP);
    int* gdh      = gcur + NBUK;
    int* gdcur    = gdh + NDC;
    int* rowstart = gdcur + NDC;
    int* csr_src  = rowstart + (NN + 1);
    int* perm     = csr_src + NE;
    ushort_t* wpack = (ushort_t*)(perm + NN);

    int totOut = NG * 10 + NL * NG * DD;
    int zeroBlocks = (totOut + 255) / 256;

    zero_k<<<2, 256, 0, stream>>>(gcur, gdh, gdcur);
    fused_k<<<NL * 4 + NBLK + zeroBlocks, 256, 0, stream>>>(
        Wq, Wk, Wv, Wsp, wpack, srcv, dstv, binbuf, gcur, out, totOut);
    csr_k<<<NBUK, 256, 0, stream>>>(binbuf, gcur, rowstart, csr_src, gdh);

    int gtiles = (NN + 63) / 64;
    int poolblocks = (NN + POOL_ROWS - 1) / POOL_ROWS;
    for (int l = 0; l < NL; l++) {
        int tailMode = (l == 0) ? 2 : 1;
        int extra = (l == 0) ? DPERM_BLOCKS : poolblocks;
        gemm4pool_k<<<gtiles + extra, 256, 0, stream>>>(
            hbf, (l == 0) ? x : nullptr, wpack + (size_t)l * 4 * 8 * 512,
            bq + l * DD, bk + l * DD, bv + l * DD, bsp + l * DD,
            qb, kv8, skb, batch,
            (l > 0) ? (pooled + (l - 1) * NG * DD) : nullptr, gtiles, tailMode,
            rowstart, gdh, gdcur, perm);
        agg_k<<<(NN + 31) / 32, 256, 0, stream>>>(qb, kv8, skb, rowstart, csr_src, perm, hbf);
    }
    pool_k<<<poolblocks, 256, 0, stream>>>(hbf, batch, pooled + 2 * NG * DD);
    head_k<<<NG, 64, 0, stream>>>(pooled + 2 * NG * DD, W1, b1, W2, b2, out);
}